// Round 6
// baseline (4686.364 us; speedup 1.0000x reference)
//
#include <hip/hip_runtime.h>

// ---------------------------------------------------------------------------
// TeacherModel: small U-Net + pose heads. B=8, H=W=384, fp32 NCHW.
// Round 6: register-pressure discipline. gfx950 allocator spills rather than
// exceed its occupancy-target VGPR bucket (~85 = 6 waves/EU), so every hot
// kernel keeps peak live < ~82:
//  - u2seg: 32 cos x 2 px, SINGLE pass over ci (no chunk re-reads), per-ky
//    window (live = 64 acc + 4 win + 2 seg ~ 78). R5: VGPR=76 w/ spill, 647MB
//    FETCH, 42ms scratch-init dispatch.
//  - conv3x3_x8: per-ky window v[10] instead of v[3][10] (live ~78).
// Accumulation order per output unchanged (ci -> ky -> px) => absmax stable.
// ---------------------------------------------------------------------------

#define BS 256

// 3x3 stride-1 SAME conv, TCO cos x 8 px per thread, per-ky window.
// Input = concat([maybe-up2(inA) (Ca ch), inB (Cb ch)]).
// UPA: 1 = inA full-res; 2 = inA half-res nearest-up2.
template <int UPA, int TCO>
__global__ __launch_bounds__(BS, 2) void conv3x3_x8_kernel(
    const float* __restrict__ inA, int Ca,
    const float* __restrict__ inB, int Cb,
    const float* __restrict__ w, const float* __restrict__ b,
    float* __restrict__ out,
    int N, int H, int W, int Cout, int do_relu)
{
    const int W8 = W >> 3;
    int idx = blockIdx.x * BS + threadIdx.x;
    int total = N * H * W8;
    if (idx >= total) return;
    int x8 = idx % W8;
    int t  = idx / W8;
    int y  = t % H;
    int n  = t / H;
    int x0 = x8 << 3;
    const int co0 = blockIdx.y * TCO;       // wave-uniform
    const bool left_ok  = (x0 > 0);
    const bool right_ok = (x0 + 8 < W);
    const int Cin = Ca + Cb;

    float acc[TCO][8];
#pragma unroll
    for (int j = 0; j < TCO; ++j) {
        float bv = b[co0 + j];
#pragma unroll
        for (int p = 0; p < 8; ++p) acc[j][p] = bv;
    }

    for (int ci = 0; ci < Cin; ++ci) {
#pragma unroll
        for (int ky = 0; ky < 3; ++ky) {
            int iy = y + ky - 1;
            float v[10];                    // input x0-1 .. x0+8 (per-ky: low live)
            if (iy < 0 || iy >= H) {
#pragma unroll
                for (int p = 0; p < 10; ++p) v[p] = 0.f;
            } else if (UPA == 2 && ci < Ca) {
                const float* r = inA + ((size_t)(n * Ca + ci) * (H >> 1) + (iy >> 1)) * (W >> 1);
                int xh = x0 >> 1;                    // multiple of 4
                float sm = left_ok  ? r[xh - 1] : 0.f;
                float4 q = *(const float4*)(r + xh);
                float s4 = right_ok ? r[xh + 4] : 0.f;
                v[0] = sm;
                v[1] = q.x; v[2] = q.x;
                v[3] = q.y; v[4] = q.y;
                v[5] = q.z; v[6] = q.z;
                v[7] = q.w; v[8] = q.w;
                v[9] = s4;
            } else {
                const float* r = (ci < Ca)
                    ? inA + ((size_t)(n * Ca + ci) * H + iy) * W
                    : inB + ((size_t)(n * Cb + (ci - Ca)) * H + iy) * W;
                v[0] = left_ok ? r[x0 - 1] : 0.f;
                float4 q0 = *(const float4*)(r + x0);
                float4 q1 = *(const float4*)(r + x0 + 4);
                v[1] = q0.x; v[2] = q0.y; v[3] = q0.z; v[4] = q0.w;
                v[5] = q1.x; v[6] = q1.y; v[7] = q1.z; v[8] = q1.w;
                v[9] = right_ok ? r[x0 + 8] : 0.f;
            }
#pragma unroll
            for (int j = 0; j < TCO; ++j) {
                const float* wp = w + ((size_t)(co0 + j) * Cin + ci) * 9 + ky * 3;  // uniform
                float w0 = wp[0], w1 = wp[1], w2 = wp[2];
#pragma unroll
                for (int p = 0; p < 8; ++p)
                    acc[j][p] += w0 * v[p] + w1 * v[p + 1] + w2 * v[p + 2];
            }
        }
    }

#pragma unroll
    for (int j = 0; j < TCO; ++j) {
#pragma unroll
        for (int p = 0; p < 8; ++p)
            if (do_relu) acc[j][p] = fmaxf(acc[j][p], 0.f);
        float* o = out + ((size_t)(n * Cout + co0 + j) * H + y) * W + x0;
        float4 q0; q0.x = acc[j][0]; q0.y = acc[j][1]; q0.z = acc[j][2]; q0.w = acc[j][3];
        float4 q1; q1.x = acc[j][4]; q1.y = acc[j][5]; q1.z = acc[j][6]; q1.w = acc[j][7];
        *(float4*)o = q0;
        *(float4*)(o + 4) = q1;
    }
}

// 3x3 stride-2 SAME conv (pad_lo=0, pad_hi=1), TCO cos x 4 out-px, per-ky window.
template <int TCO>
__global__ __launch_bounds__(BS, 2) void conv3x3_s2_co_kernel(
    const float* __restrict__ inA, int Ca,
    const float* __restrict__ inB, int Cb,
    const float* __restrict__ w, const float* __restrict__ b,
    float* __restrict__ out,
    int N, int Hi, int Wi, int Cout, int do_relu)
{
    const int Ho = Hi >> 1, Wo = Wi >> 1, Woq = Wo >> 2;
    int idx = blockIdx.x * BS + threadIdx.x;
    int total = N * Ho * Woq;
    if (idx >= total) return;
    int q  = idx % Woq;
    int t  = idx / Woq;
    int oy = t % Ho;
    int n  = t / Ho;
    int ox0 = q << 2;
    int ix0 = ox0 << 1;                       // input x start (pad_lo = 0)
    const int co0 = blockIdx.y * TCO;
    const bool right_ok = (ix0 + 8 < Wi);
    const int Cin = Ca + Cb;

    float acc[TCO][4];
#pragma unroll
    for (int j = 0; j < TCO; ++j) {
        float bv = b[co0 + j];
        acc[j][0] = bv; acc[j][1] = bv; acc[j][2] = bv; acc[j][3] = bv;
    }

    for (int ci = 0; ci < Cin; ++ci) {
        const float* base = (ci < Ca)
            ? inA + (size_t)(n * Ca + ci) * Hi * Wi
            : inB + (size_t)(n * Cb + (ci - Ca)) * Hi * Wi;
#pragma unroll
        for (int ky = 0; ky < 3; ++ky) {
            int iy = 2 * oy + ky;
            float v[9];
            if (iy >= Hi) {
#pragma unroll
                for (int p = 0; p < 9; ++p) v[p] = 0.f;
            } else {
                const float* r = base + (size_t)iy * Wi + ix0;
                float4 a = *(const float4*)r;
                float4 c = *(const float4*)(r + 4);
                v[0] = a.x; v[1] = a.y; v[2] = a.z; v[3] = a.w;
                v[4] = c.x; v[5] = c.y; v[6] = c.z; v[7] = c.w;
                v[8] = right_ok ? r[8] : 0.f;
            }
#pragma unroll
            for (int j = 0; j < TCO; ++j) {
                const float* wp = w + ((size_t)(co0 + j) * Cin + ci) * 9 + ky * 3;  // uniform
                float w0 = wp[0], w1 = wp[1], w2 = wp[2];
#pragma unroll
                for (int p = 0; p < 4; ++p)
                    acc[j][p] += w0 * v[2 * p] + w1 * v[2 * p + 1] + w2 * v[2 * p + 2];
            }
        }
    }

#pragma unroll
    for (int j = 0; j < TCO; ++j) {
        float4 o;
        o.x = acc[j][0]; o.y = acc[j][1]; o.z = acc[j][2]; o.w = acc[j][3];
        if (do_relu) {
            o.x = fmaxf(o.x, 0.f); o.y = fmaxf(o.y, 0.f);
            o.z = fmaxf(o.z, 0.f); o.w = fmaxf(o.w, 0.f);
        }
        *(float4*)(out + ((size_t)(n * Cout + co0 + j) * Ho + oy) * Wo + ox0) = o;
    }
}

// Fused: u2 = relu(conv3x3(concat(up2(u1), d1); 96->32)); seg = conv1x1(u2; 32->1)
// 2 px per thread, ALL 32 cos in regs, single pass over ci (inputs read once).
// Peak live: acc 64 + v 4 + sa 2 + addr ~ 78 regs -> no spill.
__global__ __launch_bounds__(BS, 2) void u2seg_kernel(
    const float* __restrict__ u1,    // [N,64,H/2,W/2]
    const float* __restrict__ d1,    // [N,32,H,W]
    const float* __restrict__ w_u2,  // [32,96,3,3]
    const float* __restrict__ b_u2,  // [32]
    const float* __restrict__ w_seg, // [32]
    const float* __restrict__ b_seg, // [1]
    float* __restrict__ seg,         // [N,1,H,W]
    int N, int H, int W)
{
    const int Wh = W >> 1;
    int idx = blockIdx.x * BS + threadIdx.x;
    int total = N * H * Wh;
    if (idx >= total) return;
    int xp = idx % Wh;
    int t  = idx / Wh;
    int y  = t % H;
    int n  = t / H;
    int x0 = xp << 1;
    const bool left_ok  = (x0 > 0);
    const bool right_ok = (x0 + 2 < W);
    const int H2 = H >> 1, W2 = W >> 1;

    float acc[32][2];
#pragma unroll
    for (int co = 0; co < 32; ++co) {
        float bv = b_u2[co];
        acc[co][0] = bv; acc[co][1] = bv;
    }

    for (int ci = 0; ci < 96; ++ci) {
#pragma unroll
        for (int ky = 0; ky < 3; ++ky) {
            int iy = y + ky - 1;
            float v[4];                  // input x0-1 .. x0+2
            if (iy < 0 || iy >= H) {
                v[0] = v[1] = v[2] = v[3] = 0.f;
            } else if (ci < 64) {
                const float* r = u1 + ((size_t)(n * 64 + ci) * H2 + (iy >> 1)) * W2;
                int xh = x0 >> 1;
                float sm = left_ok  ? r[xh - 1] : 0.f;
                float s0 = r[xh];
                float s1 = right_ok ? r[xh + 1] : 0.f;
                v[0] = sm; v[1] = s0; v[2] = s0; v[3] = s1;
            } else {
                const float* r = d1 + ((size_t)(n * 32 + (ci - 64)) * H + iy) * W;
                v[0] = left_ok ? r[x0 - 1] : 0.f;
                float2 qd = *(const float2*)(r + x0);
                v[1] = qd.x; v[2] = qd.y;
                v[3] = right_ok ? r[x0 + 2] : 0.f;
            }
#pragma unroll
            for (int co = 0; co < 32; ++co) {
                const float* wp = w_u2 + ((size_t)co * 96 + ci) * 9 + ky * 3;  // uniform
                float w0 = wp[0], w1 = wp[1], w2 = wp[2];
                acc[co][0] += w0 * v[0] + w1 * v[1] + w2 * v[2];
                acc[co][1] += w0 * v[1] + w1 * v[2] + w2 * v[3];
            }
        }
    }

    float s0 = b_seg[0], s1 = s0;
#pragma unroll
    for (int co = 0; co < 32; ++co) {
        float wv = w_seg[co];
        s0 += wv * fmaxf(acc[co][0], 0.f);
        s1 += wv * fmaxf(acc[co][1], 0.f);
    }
    float2 o; o.x = s0; o.y = s1;
    *(float2*)(seg + ((size_t)n * H + y) * W + x0) = o;
}

// 2x2 maxpool stride 2, float4-vectorized output
__global__ __launch_bounds__(BS) void maxpool2_kernel(
    const float* __restrict__ in, float* __restrict__ out, int NC, int H, int W)
{
    int Ho = H >> 1, Wo = W >> 1, Woq = Wo >> 2;
    int idx = blockIdx.x * BS + threadIdx.x;
    int total = NC * Ho * Woq;
    if (idx >= total) return;
    int x4 = idx % Woq;
    int t  = idx / Woq;
    int y  = t % Ho;
    int c  = t / Ho;
    const float* r0 = in + ((size_t)c * H + 2 * y) * W + 8 * x4;
    const float* r1 = r0 + W;
    float4 a0 = *(const float4*)r0;
    float4 a1 = *(const float4*)(r0 + 4);
    float4 b0 = *(const float4*)r1;
    float4 b1 = *(const float4*)(r1 + 4);
    float4 o;
    o.x = fmaxf(fmaxf(a0.x, a0.y), fmaxf(b0.x, b0.y));
    o.y = fmaxf(fmaxf(a0.z, a0.w), fmaxf(b0.z, b0.w));
    o.z = fmaxf(fmaxf(a1.x, a1.y), fmaxf(b1.x, b1.y));
    o.w = fmaxf(fmaxf(a1.z, a1.w), fmaxf(b1.z, b1.w));
    *(float4*)(out + ((size_t)c * Ho + y) * Wo + 4 * x4) = o;
}

// 1x1 conv, 4 pixels per thread
__global__ __launch_bounds__(BS) void conv1x1_kernel(
    const float* __restrict__ in, const float* __restrict__ w,
    const float* __restrict__ b, float* __restrict__ out,
    int N, int Cin, int HW, int Cout, int do_relu)
{
    int HWq = HW >> 2;
    int idx = blockIdx.x * BS + threadIdx.x;
    int total = N * Cout * HWq;
    if (idx >= total) return;
    int q  = idx % HWq;
    int t  = idx / HWq;
    int co = t % Cout;
    int n  = t / Cout;
    float bias = b[co];
    float a0 = bias, a1 = bias, a2 = bias, a3 = bias;
    const float* wc = w + (size_t)co * Cin;
    const float* base = in + (size_t)n * Cin * HW + 4 * q;
    for (int ci = 0; ci < Cin; ++ci) {
        float4 v = *(const float4*)(base + (size_t)ci * HW);
        float wv = wc[ci];
        a0 += wv * v.x; a1 += wv * v.y; a2 += wv * v.z; a3 += wv * v.w;
    }
    if (do_relu) {
        a0 = fmaxf(a0, 0.f); a1 = fmaxf(a1, 0.f);
        a2 = fmaxf(a2, 0.f); a3 = fmaxf(a3, 0.f);
    }
    float4 o; o.x = a0; o.y = a1; o.z = a2; o.w = a3;
    *(float4*)(out + ((size_t)(n * Cout + co)) * HW + 4 * q) = o;
}

// local-max peaks mask
__global__ __launch_bounds__(BS) void peaks_kernel(
    const float* __restrict__ hm, float* __restrict__ out,
    int NC, int H, int W, float thresh)
{
    int idx = blockIdx.x * BS + threadIdx.x;
    int total = NC * H * W;
    if (idx >= total) return;
    int x = idx % W;
    int t = idx / W;
    int y = t % H;
    int c = t / H;
    float r = 0.f;
    if (x >= 1 && x < W - 1 && y >= 1 && y < H - 1) {
        const float* base = hm + (size_t)c * H * W;
        float cv = base[y * W + x];
        if (cv > thresh &&
            cv >= base[(y - 1) * W + x] &&
            cv >= base[(y + 1) * W + x] &&
            cv >= base[y * W + (x - 1)] &&
            cv >= base[y * W + (x + 1)])
            r = 1.f;
    }
    out[idx] = r;
}

static inline int nblk(long n) { return (int)((n + BS - 1) / BS); }

extern "C" void kernel_launch(void* const* d_in, const int* in_sizes, int n_in,
                              void* d_out, int out_size, void* d_ws, size_t ws_size,
                              hipStream_t stream)
{
    const float* x     = (const float*)d_in[0];
    const float* w_d1  = (const float*)d_in[1];  const float* b_d1  = (const float*)d_in[2];
    const float* w_d2  = (const float*)d_in[3];  const float* b_d2  = (const float*)d_in[4];
    const float* w_bn  = (const float*)d_in[5];  const float* b_bn  = (const float*)d_in[6];
    const float* w_u1  = (const float*)d_in[7];  const float* b_u1  = (const float*)d_in[8];
    const float* w_u2  = (const float*)d_in[9];  const float* b_u2  = (const float*)d_in[10];
    const float* w_seg = (const float*)d_in[11]; const float* b_seg = (const float*)d_in[12];
    const float* w_p1  = (const float*)d_in[13]; const float* b_p1  = (const float*)d_in[14];
    const float* w_p2  = (const float*)d_in[15]; const float* b_p2  = (const float*)d_in[16];
    const float* w_hm  = (const float*)d_in[17]; const float* b_hm  = (const float*)d_in[18];
    const float* w_paf = (const float*)d_in[19]; const float* b_paf = (const float*)d_in[20];

    const int N = 8, H = 384, W = 384;
    const int H2 = 192, W2 = 192, H4 = 96, W4 = 96;

    float* ws = (float*)d_ws;
    // Workspace extent = 56,623,104 floats = 216 MiB (see R2 lifetime map).
    float* u1  = ws;                   // 8*64*192*192 = 18874368
    float* d1  = ws + 18874368;        // 8*32*384*384 = 37748736 (also d1' recompute)
    float* d2  = ws + 18874368;        // 8*64*192*192 = 18874368
    float* bn  = ws + 37748736;        // 8*128*96*96  = 9437184
    float* pd1 = ws;                   // 8*32*192*192 = 9437184
    float* pd2 = ws + 47185920;        // 8*64*96*96   = 4718592
    float* p1  = ws;                   // 8*64*192*192 = 18874368
    float* p2  = ws + 18874368;        // 8*128*96*96  = 9437184

    float* out_seg   = (float*)d_out;                 // 8*1*384*384   = 1179648
    float* out_hm    = out_seg + 1179648;             // 8*17*96*96    = 1253376
    float* out_paf   = out_hm + 1253376;              // 8*32*96*96    = 2359296
    float* out_peaks = out_paf + 2359296;             // 8*17*96*96    = 1253376

    // 1. d1 = relu(conv3x3(x; 3->32)) @384
    {
        dim3 g(nblk((long)N * H * (W / 8)), 32 / 8);
        conv3x3_x8_kernel<1, 8><<<g, BS, 0, stream>>>(
            x, 3, nullptr, 0, w_d1, b_d1, d1, N, H, W, 32, 1);
    }
    // 2. pd1 = maxpool(d1) @192
    maxpool2_kernel<<<nblk((long)N * 32 * H2 * (W2 / 4)), BS, 0, stream>>>(d1, pd1, N * 32, H, W);
    // 3. d2 = relu(conv3x3(pd1; 32->64)) @192
    {
        dim3 g(nblk((long)N * H2 * (W2 / 8)), 64 / 8);
        conv3x3_x8_kernel<1, 8><<<g, BS, 0, stream>>>(
            pd1, 32, nullptr, 0, w_d2, b_d2, d2, N, H2, W2, 64, 1);
    }
    // 4. pd2 = maxpool(d2) @96
    maxpool2_kernel<<<nblk((long)N * 64 * H4 * (W4 / 4)), BS, 0, stream>>>(d2, pd2, N * 64, H2, W2);
    // 5. bn = relu(conv3x3(pd2; 64->128)) @96
    {
        dim3 g(nblk((long)N * H4 * (W4 / 8)), 128 / 8);
        conv3x3_x8_kernel<1, 8><<<g, BS, 0, stream>>>(
            pd2, 64, nullptr, 0, w_bn, b_bn, bn, N, H4, W4, 128, 1);
    }
    // 6. u1 = relu(conv3x3(concat(up2(bn), d2); 192->64)) @192
    {
        dim3 g(nblk((long)N * H2 * (W2 / 8)), 64 / 8);
        conv3x3_x8_kernel<2, 8><<<g, BS, 0, stream>>>(
            bn, 128, d2, 64, w_u1, b_u1, u1, N, H2, W2, 64, 1);
    }
    // 7. d1' = relu(conv3x3(x; 3->32)) @384  (recompute)
    {
        dim3 g(nblk((long)N * H * (W / 8)), 32 / 8);
        conv3x3_x8_kernel<1, 8><<<g, BS, 0, stream>>>(
            x, 3, nullptr, 0, w_d1, b_d1, d1, N, H, W, 32, 1);
    }
    // 8. seg = fused u2+seg (32 cos x 2 px, single pass)
    u2seg_kernel<<<nblk((long)N * H * (W / 2)), BS, 0, stream>>>(
        u1, d1, w_u2, b_u2, w_seg, b_seg, out_seg, N, H, W);
    // 9. p1 = relu(conv3x3_s2(concat(x, seg); 4->64)) @384->192
    {
        dim3 g(nblk((long)N * H2 * (W2 / 4)), 64 / 8);
        conv3x3_s2_co_kernel<8><<<g, BS, 0, stream>>>(
            x, 3, out_seg, 1, w_p1, b_p1, p1, N, H, W, 64, 1);
    }
    // 10. p2 = relu(conv3x3_s2(p1; 64->128)) @192->96
    {
        dim3 g(nblk((long)N * H4 * (W4 / 4)), 128 / 8);
        conv3x3_s2_co_kernel<8><<<g, BS, 0, stream>>>(
            p1, 64, nullptr, 0, w_p2, b_p2, p2, N, H2, W2, 128, 1);
    }
    // 11. hm = conv1x1(p2; 128->17) @96
    conv1x1_kernel<<<nblk((long)N * 17 * (H4 * W4 / 4)), BS, 0, stream>>>(
        p2, w_hm, b_hm, out_hm, N, 128, H4 * W4, 17, 0);
    // 12. paf = conv1x1(p2; 128->32) @96
    conv1x1_kernel<<<nblk((long)N * 32 * (H4 * W4 / 4)), BS, 0, stream>>>(
        p2, w_paf, b_paf, out_paf, N, 128, H4 * W4, 32, 0);
    // 13. peaks @96
    peaks_kernel<<<nblk((long)N * 17 * H4 * W4), BS, 0, stream>>>(
        out_hm, out_peaks, N * 17, H4, W4, 0.1f);
}

// Round 7
// 3265.434 us; speedup vs baseline: 1.4351x; 1.4351x over previous
//
#include <hip/hip_runtime.h>

// ---------------------------------------------------------------------------
// TeacherModel: small U-Net + pose heads. B=8, H=W=384, fp32 NCHW.
// Round 7: de-spill everything by cloning the ONE proven-no-spill shape.
// Evidence R3-R6: conv3x3_x8 (acc[8][8]+v[3][10], co-group in blockIdx.y,
// plain inner loops) never scratches; u2seg variants with serial chunk loops
// or TCO=32 weight streams (SGPR=112) always scratch (40ms first dispatch).
//  - u2seg => 4 co-group dispatches of the conv3x3_x8 shape, each writing an
//    8-px seg PARTIAL to the unused out_hm/out_paf region; tiny reduce sums.
//  - s2 convs: exact R4 form (never hot, no scratch).
//  - conv1x1 heads: TCO=8 co-blocking (p2 re-read 49x -> 7x).
// ---------------------------------------------------------------------------

#define BS 256

// 3x3 stride-1 SAME conv, TCO cos x 8 px per thread.
// Input = concat([maybe-up2(inA) (Ca ch), inB (Cb ch)]).
// UPA: 1 = inA full-res; 2 = inA half-res nearest-up2.
template <int UPA, int TCO>
__global__ __launch_bounds__(BS, 2) void conv3x3_x8_kernel(
    const float* __restrict__ inA, int Ca,
    const float* __restrict__ inB, int Cb,
    const float* __restrict__ w, const float* __restrict__ b,
    float* __restrict__ out,
    int N, int H, int W, int Cout, int do_relu)
{
    const int W8 = W >> 3;
    int idx = blockIdx.x * BS + threadIdx.x;
    int total = N * H * W8;
    if (idx >= total) return;
    int x8 = idx % W8;
    int t  = idx / W8;
    int y  = t % H;
    int n  = t / H;
    int x0 = x8 << 3;
    const int co0 = blockIdx.y * TCO;       // wave-uniform
    const bool left_ok  = (x0 > 0);
    const bool right_ok = (x0 + 8 < W);
    const int Cin = Ca + Cb;

    float acc[TCO][8];
#pragma unroll
    for (int j = 0; j < TCO; ++j) {
        float bv = b[co0 + j];
#pragma unroll
        for (int p = 0; p < 8; ++p) acc[j][p] = bv;
    }

    for (int ci = 0; ci < Cin; ++ci) {
        // window v[ky][0..9] = input x0-1 .. x0+8
        float v[3][10];
#pragma unroll
        for (int ky = 0; ky < 3; ++ky) {
            int iy = y + ky - 1;
            if (iy < 0 || iy >= H) {
#pragma unroll
                for (int p = 0; p < 10; ++p) v[ky][p] = 0.f;
                continue;
            }
            if (UPA == 2 && ci < Ca) {
                const float* r = inA + ((size_t)(n * Ca + ci) * (H >> 1) + (iy >> 1)) * (W >> 1);
                int xh = x0 >> 1;                    // multiple of 4
                float sm = left_ok  ? r[xh - 1] : 0.f;
                float4 q = *(const float4*)(r + xh);
                float s4 = right_ok ? r[xh + 4] : 0.f;
                v[ky][0] = sm;
                v[ky][1] = q.x; v[ky][2] = q.x;
                v[ky][3] = q.y; v[ky][4] = q.y;
                v[ky][5] = q.z; v[ky][6] = q.z;
                v[ky][7] = q.w; v[ky][8] = q.w;
                v[ky][9] = s4;
            } else {
                const float* r = (ci < Ca)
                    ? inA + ((size_t)(n * Ca + ci) * H + iy) * W
                    : inB + ((size_t)(n * Cb + (ci - Ca)) * H + iy) * W;
                v[ky][0] = left_ok ? r[x0 - 1] : 0.f;
                float4 q0 = *(const float4*)(r + x0);
                float4 q1 = *(const float4*)(r + x0 + 4);
                v[ky][1] = q0.x; v[ky][2] = q0.y; v[ky][3] = q0.z; v[ky][4] = q0.w;
                v[ky][5] = q1.x; v[ky][6] = q1.y; v[ky][7] = q1.z; v[ky][8] = q1.w;
                v[ky][9] = right_ok ? r[x0 + 8] : 0.f;
            }
        }
#pragma unroll
        for (int j = 0; j < TCO; ++j) {
            const float* wp = w + ((size_t)(co0 + j) * Cin + ci) * 9;  // uniform -> s_load
#pragma unroll
            for (int ky = 0; ky < 3; ++ky) {
                float w0 = wp[ky * 3 + 0], w1 = wp[ky * 3 + 1], w2 = wp[ky * 3 + 2];
#pragma unroll
                for (int p = 0; p < 8; ++p)
                    acc[j][p] += w0 * v[ky][p] + w1 * v[ky][p + 1] + w2 * v[ky][p + 2];
            }
        }
    }

#pragma unroll
    for (int j = 0; j < TCO; ++j) {
#pragma unroll
        for (int p = 0; p < 8; ++p)
            if (do_relu) acc[j][p] = fmaxf(acc[j][p], 0.f);
        float* o = out + ((size_t)(n * Cout + co0 + j) * H + y) * W + x0;
        float4 q0; q0.x = acc[j][0]; q0.y = acc[j][1]; q0.z = acc[j][2]; q0.w = acc[j][3];
        float4 q1; q1.x = acc[j][4]; q1.y = acc[j][5]; q1.z = acc[j][6]; q1.w = acc[j][7];
        *(float4*)o = q0;
        *(float4*)(o + 4) = q1;
    }
}

// u2+seg partial: identical shape to conv3x3_x8<2,8>, but instead of storing
// u2 channels, reduces its 8 cos into an 8-px seg partial for this co-group.
__global__ __launch_bounds__(BS, 2) void u2seg_part_kernel(
    const float* __restrict__ u1,    // [N,64,H/2,W/2]  (Ca=64, up2)
    const float* __restrict__ d1,    // [N,32,H,W]      (Cb=32)
    const float* __restrict__ w_u2,  // [32,96,3,3]
    const float* __restrict__ b_u2,  // [32]
    const float* __restrict__ w_seg, // [32]
    float* __restrict__ segpart,     // [4][N*H*W]
    int N, int H, int W)
{
    const int W8 = W >> 3;
    int idx = blockIdx.x * BS + threadIdx.x;
    int total = N * H * W8;
    if (idx >= total) return;
    int x8 = idx % W8;
    int t  = idx / W8;
    int y  = t % H;
    int n  = t / H;
    int x0 = x8 << 3;
    const int co0 = blockIdx.y * 8;          // wave-uniform co group
    const bool left_ok  = (x0 > 0);
    const bool right_ok = (x0 + 8 < W);
    const int H2 = H >> 1, W2 = W >> 1;

    float acc[8][8];
#pragma unroll
    for (int j = 0; j < 8; ++j) {
        float bv = b_u2[co0 + j];
#pragma unroll
        for (int p = 0; p < 8; ++p) acc[j][p] = bv;
    }

    for (int ci = 0; ci < 96; ++ci) {
        float v[3][10];
#pragma unroll
        for (int ky = 0; ky < 3; ++ky) {
            int iy = y + ky - 1;
            if (iy < 0 || iy >= H) {
#pragma unroll
                for (int p = 0; p < 10; ++p) v[ky][p] = 0.f;
                continue;
            }
            if (ci < 64) {
                const float* r = u1 + ((size_t)(n * 64 + ci) * H2 + (iy >> 1)) * W2;
                int xh = x0 >> 1;
                float sm = left_ok  ? r[xh - 1] : 0.f;
                float4 q = *(const float4*)(r + xh);
                float s4 = right_ok ? r[xh + 4] : 0.f;
                v[ky][0] = sm;
                v[ky][1] = q.x; v[ky][2] = q.x;
                v[ky][3] = q.y; v[ky][4] = q.y;
                v[ky][5] = q.z; v[ky][6] = q.z;
                v[ky][7] = q.w; v[ky][8] = q.w;
                v[ky][9] = s4;
            } else {
                const float* r = d1 + ((size_t)(n * 32 + (ci - 64)) * H + iy) * W;
                v[ky][0] = left_ok ? r[x0 - 1] : 0.f;
                float4 q0 = *(const float4*)(r + x0);
                float4 q1 = *(const float4*)(r + x0 + 4);
                v[ky][1] = q0.x; v[ky][2] = q0.y; v[ky][3] = q0.z; v[ky][4] = q0.w;
                v[ky][5] = q1.x; v[ky][6] = q1.y; v[ky][7] = q1.z; v[ky][8] = q1.w;
                v[ky][9] = right_ok ? r[x0 + 8] : 0.f;
            }
        }
#pragma unroll
        for (int j = 0; j < 8; ++j) {
            const float* wp = w_u2 + ((size_t)(co0 + j) * 96 + ci) * 9;  // uniform
#pragma unroll
            for (int ky = 0; ky < 3; ++ky) {
                float w0 = wp[ky * 3 + 0], w1 = wp[ky * 3 + 1], w2 = wp[ky * 3 + 2];
#pragma unroll
                for (int p = 0; p < 8; ++p)
                    acc[j][p] += w0 * v[ky][p] + w1 * v[ky][p + 1] + w2 * v[ky][p + 2];
            }
        }
    }

    // relu + 1x1 partial reduce over this group's 8 cos
    float s[8];
#pragma unroll
    for (int p = 0; p < 8; ++p) s[p] = 0.f;
#pragma unroll
    for (int j = 0; j < 8; ++j) {
        float wv = w_seg[co0 + j];
#pragma unroll
        for (int p = 0; p < 8; ++p)
            s[p] += wv * fmaxf(acc[j][p], 0.f);
    }
    float* o = segpart + (size_t)blockIdx.y * (N * H * W) + ((size_t)n * H + y) * W + x0;
    float4 q0; q0.x = s[0]; q0.y = s[1]; q0.z = s[2]; q0.w = s[3];
    float4 q1; q1.x = s[4]; q1.y = s[5]; q1.z = s[6]; q1.w = s[7];
    *(float4*)o = q0;
    *(float4*)(o + 4) = q1;
}

// out_seg = b_seg + sum of 4 partials
__global__ __launch_bounds__(BS) void seg_reduce_kernel(
    const float* __restrict__ segpart, const float* __restrict__ b_seg,
    float* __restrict__ seg, int total /* N*H*W */)
{
    int q = blockIdx.x * BS + threadIdx.x;
    if (q >= (total >> 2)) return;
    size_t off = (size_t)q << 2;
    float4 a = *(const float4*)(segpart + off);
    float4 b = *(const float4*)(segpart + (size_t)total + off);
    float4 c = *(const float4*)(segpart + 2 * (size_t)total + off);
    float4 d = *(const float4*)(segpart + 3 * (size_t)total + off);
    float bv = b_seg[0];
    float4 o;
    o.x = bv + a.x + b.x + c.x + d.x;
    o.y = bv + a.y + b.y + c.y + d.y;
    o.z = bv + a.z + b.z + c.z + d.z;
    o.w = bv + a.w + b.w + c.w + d.w;
    *(float4*)(seg + off) = o;
}

// 3x3 stride-2 SAME conv (pad_lo=0, pad_hi=1), TCO cos x 4 out-px per thread.
// Exact R4 form (no min-waves bound, whole-window regs) - never scratched.
template <int TCO>
__global__ __launch_bounds__(BS) void conv3x3_s2_co_kernel(
    const float* __restrict__ inA, int Ca,
    const float* __restrict__ inB, int Cb,
    const float* __restrict__ w, const float* __restrict__ b,
    float* __restrict__ out,
    int N, int Hi, int Wi, int Cout, int do_relu)
{
    const int Ho = Hi >> 1, Wo = Wi >> 1, Woq = Wo >> 2;
    int idx = blockIdx.x * BS + threadIdx.x;
    int total = N * Ho * Woq;
    if (idx >= total) return;
    int q  = idx % Woq;
    int t  = idx / Woq;
    int oy = t % Ho;
    int n  = t / Ho;
    int ox0 = q << 2;
    int ix0 = ox0 << 1;                       // input x start (pad_lo = 0)
    const int co0 = blockIdx.y * TCO;
    const bool right_ok = (ix0 + 8 < Wi);
    const int Cin = Ca + Cb;

    float acc[TCO][4];
#pragma unroll
    for (int j = 0; j < TCO; ++j) {
        float bv = b[co0 + j];
        acc[j][0] = bv; acc[j][1] = bv; acc[j][2] = bv; acc[j][3] = bv;
    }

    for (int ci = 0; ci < Cin; ++ci) {
        const float* base = (ci < Ca)
            ? inA + (size_t)(n * Ca + ci) * Hi * Wi
            : inB + (size_t)(n * Cb + (ci - Ca)) * Hi * Wi;
        float v[3][9];
#pragma unroll
        for (int ky = 0; ky < 3; ++ky) {
            int iy = 2 * oy + ky;
            if (iy >= Hi) {
#pragma unroll
                for (int p = 0; p < 9; ++p) v[ky][p] = 0.f;
                continue;
            }
            const float* r = base + (size_t)iy * Wi + ix0;
            float4 a = *(const float4*)r;
            float4 c = *(const float4*)(r + 4);
            v[ky][0] = a.x; v[ky][1] = a.y; v[ky][2] = a.z; v[ky][3] = a.w;
            v[ky][4] = c.x; v[ky][5] = c.y; v[ky][6] = c.z; v[ky][7] = c.w;
            v[ky][8] = right_ok ? r[8] : 0.f;
        }
#pragma unroll
        for (int j = 0; j < TCO; ++j) {
            const float* wp = w + ((size_t)(co0 + j) * Cin + ci) * 9;  // uniform
#pragma unroll
            for (int ky = 0; ky < 3; ++ky) {
                float w0 = wp[ky * 3 + 0], w1 = wp[ky * 3 + 1], w2 = wp[ky * 3 + 2];
#pragma unroll
                for (int p = 0; p < 4; ++p)
                    acc[j][p] += w0 * v[ky][2 * p] + w1 * v[ky][2 * p + 1] + w2 * v[ky][2 * p + 2];
            }
        }
    }

#pragma unroll
    for (int j = 0; j < TCO; ++j) {
        float4 o;
        o.x = acc[j][0]; o.y = acc[j][1]; o.z = acc[j][2]; o.w = acc[j][3];
        if (do_relu) {
            o.x = fmaxf(o.x, 0.f); o.y = fmaxf(o.y, 0.f);
            o.z = fmaxf(o.z, 0.f); o.w = fmaxf(o.w, 0.f);
        }
        *(float4*)(out + ((size_t)(n * Cout + co0 + j) * Ho + oy) * Wo + ox0) = o;
    }
}

// 2x2 maxpool stride 2, float4-vectorized output
__global__ __launch_bounds__(BS) void maxpool2_kernel(
    const float* __restrict__ in, float* __restrict__ out, int NC, int H, int W)
{
    int Ho = H >> 1, Wo = W >> 1, Woq = Wo >> 2;
    int idx = blockIdx.x * BS + threadIdx.x;
    int total = NC * Ho * Woq;
    if (idx >= total) return;
    int x4 = idx % Woq;
    int t  = idx / Woq;
    int y  = t % Ho;
    int c  = t / Ho;
    const float* r0 = in + ((size_t)c * H + 2 * y) * W + 8 * x4;
    const float* r1 = r0 + W;
    float4 a0 = *(const float4*)r0;
    float4 a1 = *(const float4*)(r0 + 4);
    float4 b0 = *(const float4*)r1;
    float4 b1 = *(const float4*)(r1 + 4);
    float4 o;
    o.x = fmaxf(fmaxf(a0.x, a0.y), fmaxf(b0.x, b0.y));
    o.y = fmaxf(fmaxf(a0.z, a0.w), fmaxf(b0.z, b0.w));
    o.z = fmaxf(fmaxf(a1.x, a1.y), fmaxf(b1.x, b1.y));
    o.w = fmaxf(fmaxf(a1.z, a1.w), fmaxf(b1.z, b1.w));
    *(float4*)(out + ((size_t)c * Ho + y) * Wo + 4 * x4) = o;
}

// 1x1 conv, TCO cos x 4 px per thread (co group in blockIdx.y; tail-clamped)
template <int TCO>
__global__ __launch_bounds__(BS) void conv1x1_co_kernel(
    const float* __restrict__ in, const float* __restrict__ w,
    const float* __restrict__ b, float* __restrict__ out,
    int N, int Cin, int HW, int Cout, int do_relu)
{
    int HWq = HW >> 2;
    int idx = blockIdx.x * BS + threadIdx.x;
    int total = N * HWq;
    if (idx >= total) return;
    int q = idx % HWq;
    int n = idx / HWq;
    const int co0 = blockIdx.y * TCO;

    float acc[TCO][4];
#pragma unroll
    for (int j = 0; j < TCO; ++j) {
        int co = min(co0 + j, Cout - 1);        // clamp tail (uniform)
        float bv = b[co];
        acc[j][0] = bv; acc[j][1] = bv; acc[j][2] = bv; acc[j][3] = bv;
    }
    const float* base = in + (size_t)n * Cin * HW + 4 * q;
    for (int ci = 0; ci < Cin; ++ci) {
        float4 v = *(const float4*)(base + (size_t)ci * HW);
#pragma unroll
        for (int j = 0; j < TCO; ++j) {
            int co = min(co0 + j, Cout - 1);
            float wv = w[(size_t)co * Cin + ci];  // uniform -> s_load
            acc[j][0] += wv * v.x; acc[j][1] += wv * v.y;
            acc[j][2] += wv * v.z; acc[j][3] += wv * v.w;
        }
    }
#pragma unroll
    for (int j = 0; j < TCO; ++j) {
        if (co0 + j >= Cout) break;
        float4 o;
        o.x = acc[j][0]; o.y = acc[j][1]; o.z = acc[j][2]; o.w = acc[j][3];
        if (do_relu) {
            o.x = fmaxf(o.x, 0.f); o.y = fmaxf(o.y, 0.f);
            o.z = fmaxf(o.z, 0.f); o.w = fmaxf(o.w, 0.f);
        }
        *(float4*)(out + ((size_t)(n * Cout + co0 + j)) * HW + 4 * q) = o;
    }
}

// local-max peaks mask
__global__ __launch_bounds__(BS) void peaks_kernel(
    const float* __restrict__ hm, float* __restrict__ out,
    int NC, int H, int W, float thresh)
{
    int idx = blockIdx.x * BS + threadIdx.x;
    int total = NC * H * W;
    if (idx >= total) return;
    int x = idx % W;
    int t = idx / W;
    int y = t % H;
    int c = t / H;
    float r = 0.f;
    if (x >= 1 && x < W - 1 && y >= 1 && y < H - 1) {
        const float* base = hm + (size_t)c * H * W;
        float cv = base[y * W + x];
        if (cv > thresh &&
            cv >= base[(y - 1) * W + x] &&
            cv >= base[(y + 1) * W + x] &&
            cv >= base[y * W + (x - 1)] &&
            cv >= base[y * W + (x + 1)])
            r = 1.f;
    }
    out[idx] = r;
}

static inline int nblk(long n) { return (int)((n + BS - 1) / BS); }

extern "C" void kernel_launch(void* const* d_in, const int* in_sizes, int n_in,
                              void* d_out, int out_size, void* d_ws, size_t ws_size,
                              hipStream_t stream)
{
    const float* x     = (const float*)d_in[0];
    const float* w_d1  = (const float*)d_in[1];  const float* b_d1  = (const float*)d_in[2];
    const float* w_d2  = (const float*)d_in[3];  const float* b_d2  = (const float*)d_in[4];
    const float* w_bn  = (const float*)d_in[5];  const float* b_bn  = (const float*)d_in[6];
    const float* w_u1  = (const float*)d_in[7];  const float* b_u1  = (const float*)d_in[8];
    const float* w_u2  = (const float*)d_in[9];  const float* b_u2  = (const float*)d_in[10];
    const float* w_seg = (const float*)d_in[11]; const float* b_seg = (const float*)d_in[12];
    const float* w_p1  = (const float*)d_in[13]; const float* b_p1  = (const float*)d_in[14];
    const float* w_p2  = (const float*)d_in[15]; const float* b_p2  = (const float*)d_in[16];
    const float* w_hm  = (const float*)d_in[17]; const float* b_hm  = (const float*)d_in[18];
    const float* w_paf = (const float*)d_in[19]; const float* b_paf = (const float*)d_in[20];

    const int N = 8, H = 384, W = 384;
    const int H2 = 192, W2 = 192, H4 = 96, W4 = 96;
    const int HW = H * W;                  // 147456

    float* ws = (float*)d_ws;
    // Workspace extent = 56,623,104 floats = 216 MiB (see R2 lifetime map).
    float* u1  = ws;                   // 8*64*192*192 = 18874368
    float* d1  = ws + 18874368;        // 8*32*384*384 = 37748736 (also d1' recompute)
    float* d2  = ws + 18874368;        // 8*64*192*192 = 18874368
    float* bn  = ws + 37748736;        // 8*128*96*96  = 9437184
    float* pd1 = ws;                   // 8*32*192*192 = 9437184
    float* pd2 = ws + 47185920;        // 8*64*96*96   = 4718592
    float* p1  = ws;                   // 8*64*192*192 = 18874368
    float* p2  = ws + 18874368;        // 8*128*96*96  = 9437184

    float* out_seg   = (float*)d_out;                 // 8*1*384*384   = 1179648
    float* out_hm    = out_seg + 1179648;             // 8*17*96*96    = 1253376
    float* out_paf   = out_hm + 1253376;              // 8*32*96*96    = 2359296
    float* out_peaks = out_paf + 2359296;             // 8*17*96*96    = 1253376
    // seg partials [4][N*H*W] live in the not-yet-written hm/paf/peaks region
    // (4*1179648 = 4718592 <= 1253376+2359296+1253376); overwritten at steps 11-13.
    float* segpart = out_hm;

    // 1. d1 = relu(conv3x3(x; 3->32)) @384
    {
        dim3 g(nblk((long)N * H * (W / 8)), 32 / 8);
        conv3x3_x8_kernel<1, 8><<<g, BS, 0, stream>>>(
            x, 3, nullptr, 0, w_d1, b_d1, d1, N, H, W, 32, 1);
    }
    // 2. pd1 = maxpool(d1) @192
    maxpool2_kernel<<<nblk((long)N * 32 * H2 * (W2 / 4)), BS, 0, stream>>>(d1, pd1, N * 32, H, W);
    // 3. d2 = relu(conv3x3(pd1; 32->64)) @192
    {
        dim3 g(nblk((long)N * H2 * (W2 / 8)), 64 / 8);
        conv3x3_x8_kernel<1, 8><<<g, BS, 0, stream>>>(
            pd1, 32, nullptr, 0, w_d2, b_d2, d2, N, H2, W2, 64, 1);
    }
    // 4. pd2 = maxpool(d2) @96
    maxpool2_kernel<<<nblk((long)N * 64 * H4 * (W4 / 4)), BS, 0, stream>>>(d2, pd2, N * 64, H2, W2);
    // 5. bn = relu(conv3x3(pd2; 64->128)) @96
    {
        dim3 g(nblk((long)N * H4 * (W4 / 8)), 128 / 8);
        conv3x3_x8_kernel<1, 8><<<g, BS, 0, stream>>>(
            pd2, 64, nullptr, 0, w_bn, b_bn, bn, N, H4, W4, 128, 1);
    }
    // 6. u1 = relu(conv3x3(concat(up2(bn), d2); 192->64)) @192
    {
        dim3 g(nblk((long)N * H2 * (W2 / 8)), 64 / 8);
        conv3x3_x8_kernel<2, 8><<<g, BS, 0, stream>>>(
            bn, 128, d2, 64, w_u1, b_u1, u1, N, H2, W2, 64, 1);
    }
    // 7. d1' = relu(conv3x3(x; 3->32)) @384  (recompute)
    {
        dim3 g(nblk((long)N * H * (W / 8)), 32 / 8);
        conv3x3_x8_kernel<1, 8><<<g, BS, 0, stream>>>(
            x, 3, nullptr, 0, w_d1, b_d1, d1, N, H, W, 32, 1);
    }
    // 8a. seg partials (4 co groups, conv3x3_x8-shaped)
    {
        dim3 g(nblk((long)N * H * (W / 8)), 4);
        u2seg_part_kernel<<<g, BS, 0, stream>>>(
            u1, d1, w_u2, b_u2, w_seg, segpart, N, H, W);
    }
    // 8b. seg = b_seg + sum partials
    seg_reduce_kernel<<<nblk((long)N * HW / 4), BS, 0, stream>>>(
        segpart, b_seg, out_seg, N * HW);
    // 9. p1 = relu(conv3x3_s2(concat(x, seg); 4->64)) @384->192
    {
        dim3 g(nblk((long)N * H2 * (W2 / 4)), 64 / 8);
        conv3x3_s2_co_kernel<8><<<g, BS, 0, stream>>>(
            x, 3, out_seg, 1, w_p1, b_p1, p1, N, H, W, 64, 1);
    }
    // 10. p2 = relu(conv3x3_s2(p1; 64->128)) @192->96
    {
        dim3 g(nblk((long)N * H4 * (W4 / 4)), 128 / 8);
        conv3x3_s2_co_kernel<8><<<g, BS, 0, stream>>>(
            p1, 64, nullptr, 0, w_p2, b_p2, p2, N, H2, W2, 128, 1);
    }
    // 11. hm = conv1x1(p2; 128->17) @96   (overwrites segpart region - safe now)
    {
        dim3 g(nblk((long)N * (H4 * W4 / 4)), 3);   // 3 groups of 8 cover 17
        conv1x1_co_kernel<8><<<g, BS, 0, stream>>>(
            p2, w_hm, b_hm, out_hm, N, 128, H4 * W4, 17, 0);
    }
    // 12. paf = conv1x1(p2; 128->32) @96
    {
        dim3 g(nblk((long)N * (H4 * W4 / 4)), 4);
        conv1x1_co_kernel<8><<<g, BS, 0, stream>>>(
            p2, w_paf, b_paf, out_paf, N, 128, H4 * W4, 32, 0);
    }
    // 13. peaks @96
    peaks_kernel<<<nblk((long)N * 17 * H4 * W4), BS, 0, stream>>>(
        out_hm, out_peaks, N * 17, H4, W4, 0.1f);
}

// Round 8
// 2446.483 us; speedup vs baseline: 1.9156x; 1.3347x over previous
//
#include <hip/hip_runtime.h>

// ---------------------------------------------------------------------------
// TeacherModel: small U-Net + pose heads. B=8, H=W=384, fp32 NCHW.
// Round 8: u1 conv -> implicit-GEMM MFMA with 3-term f16 split (a=ah+al,
// b=bh+bl; ah*bh+ah*bl+al*bh in mfma_f32_16x16x32_f16, fp32 acc) ~= fp32
// precision at ~790 TF useful vs 157 TF vector ceiling. R7 counters: u1 at
// 48 TF, VALUBusy 56%, MfmaUtil 0 - direct conv plateaued. Everything else
// unchanged from R7 (3265us, passing, absmax 7.8e-3).
// ---------------------------------------------------------------------------

#define BS 256

typedef _Float16 half8 __attribute__((ext_vector_type(8)));
typedef float floatx4 __attribute__((ext_vector_type(4)));

// ===========================================================================
// u1 MFMA path. GEMM view: M = px (8*192*192), N = 64 cos, K = ci per tap.
// Block = 256 thr = 4 waves; block covers 64 px of ONE row (W=192, 64|192).
// Wave w handles px [wv*16, wv*16+16) x all 4 N-tiles. K-loop: 6 ci-chunks of
// 32 (chunks 0..3 = bn half-res via up2, 4..5 = d2 full-res) x 9 taps.
// ===========================================================================

// Weight pre-pack: fragment-ready per-lane blobs.
// layout: [plane(hi/lo)][chunk(6)][tap(9)][ntile(4)][lane(64)][8 f16]
// element: ci = chunk*32 + (lane>>4)*8 + j ; co = ntile*16 + (lane&15)
__global__ __launch_bounds__(BS) void packw_u1_kernel(
    const float* __restrict__ w, _Float16* __restrict__ bp)
{
    int tid = blockIdx.x * BS + threadIdx.x;          // 6*9*4*64 = 13824
    if (tid >= 13824) return;
    int lane = tid & 63;
    int t = tid >> 6;
    int nt = t & 3; t >>= 2;
    int tap = t % 9;
    int chunk = t / 9;
    int q = lane >> 4, n = lane & 15;
    int co = nt * 16 + n;
    _Float16 hi[8], lo[8];
#pragma unroll
    for (int j = 0; j < 8; ++j) {
        int ci = chunk * 32 + q * 8 + j;
        float v = w[((size_t)co * 192 + ci) * 9 + tap];
        _Float16 h = (_Float16)v;
        hi[j] = h;
        lo[j] = (_Float16)(v - (float)h);
    }
    _Float16* ph = bp + (size_t)tid * 8;
    _Float16* pl = bp + 110592 + (size_t)tid * 8;     // lo plane offset 6*9*4*64*8
#pragma unroll
    for (int j = 0; j < 8; ++j) { ph[j] = hi[j]; pl[j] = lo[j]; }
}

#define LDSDW 20   // dwords per x position (16 f16-pairs used + 4 pad -> bank spread)
#define PLANE 4080 // 3*68*LDSDW dwords per plane

__global__ __launch_bounds__(BS) void u1_mfma_kernel(
    const float* __restrict__ bn_,   // [8,128,96,96]
    const float* __restrict__ d2_,   // [8,64,192,192]
    const _Float16* __restrict__ bp, // packed weights
    const float* __restrict__ b_u1,  // [64]
    float* __restrict__ out)         // [8,64,192,192]
{
    __shared__ unsigned int lds[2 * PLANE];           // 32640 B; reused for epilogue
    const int Ho = 192, Wo = 192;
    int pxbase = blockIdx.x * 64;
    int yy = pxbase / Wo;
    int x0 = pxbase % Wo;
    int n = yy / Ho;
    int y = yy % Ho;

    int tid = threadIdx.x;
    int lane = tid & 63, wv = tid >> 6;
    int m = lane & 15, q = lane >> 4;
    int wx = x0 + wv * 16;

    floatx4 acc[4];
#pragma unroll
    for (int nt = 0; nt < 4; ++nt) acc[nt] = (floatx4){0.f, 0.f, 0.f, 0.f};

    const int h0  = (y - 1) >> 1;     // half-res row base (arith shift: -1 ok)
    const int hx0 = (x0 - 1) >> 1;

    for (int chunk = 0; chunk < 6; ++chunk) {
        __syncthreads();
        // ---------------- stage chunk into LDS (f16 hi/lo planes) ----------
        if (chunk < 4) {
            // bn, half-res: rows h0,h0+1; x hx0..hx0+33; [row][xi][ci] xi<34
            for (int e = tid; e < 2 * 34 * 32; e += BS) {
                int xi = e % 34;
                int rest = e / 34;
                int ci = rest & 31;
                int row = rest >> 5;
                int hy = h0 + row, hx = hx0 + xi;
                float v = (hy >= 0 && hy < 96 && hx >= 0 && hx < 96)
                    ? bn_[((size_t)(n * 128 + chunk * 32 + ci) * 96 + hy) * 96 + hx] : 0.f;
                _Float16 h = (_Float16)v;
                _Float16 l = (_Float16)(v - (float)h);
                int base = (row * 68 + xi) * LDSDW + (ci >> 1);
                ((_Float16*)lds)[(size_t)base * 2 + (ci & 1)] = h;
                ((_Float16*)lds)[((size_t)PLANE + base) * 2 + (ci & 1)] = l;
            }
        } else {
            // d2, full-res: rows y-1..y+1; gx x0-1 .. x0+65 (67 vals, pad 68)
            for (int e = tid; e < 3 * 68 * 32; e += BS) {
                int xi = e % 68;
                int rest = e / 68;
                int ci = rest & 31;
                int row = rest >> 5;
                int iy = y - 1 + row, gx = x0 - 1 + xi;
                float v = (xi < 67 && iy >= 0 && iy < Ho && gx >= 0 && gx < Wo)
                    ? d2_[((size_t)(n * 64 + (chunk - 4) * 32 + ci) * Ho + iy) * Wo + gx] : 0.f;
                _Float16 h = (_Float16)v;
                _Float16 l = (_Float16)(v - (float)h);
                int base = (row * 68 + xi) * LDSDW + (ci >> 1);
                ((_Float16*)lds)[(size_t)base * 2 + (ci & 1)] = h;
                ((_Float16*)lds)[((size_t)PLANE + base) * 2 + (ci & 1)] = l;
            }
        }
        __syncthreads();
        // ---------------- 9 taps: A from LDS, B from packed global ---------
#pragma unroll
        for (int ky = 0; ky < 3; ++ky) {
#pragma unroll
            for (int kx = 0; kx < 3; ++kx) {
                int row, xi;
                if (chunk < 4) {
                    row = ((y + ky - 1) >> 1) - h0;               // 0 or 1
                    xi  = ((wx + m + kx - 1) >> 1) - hx0;
                } else {
                    row = ky;
                    xi  = (wx - x0) + m + kx;                     // 0..65
                }
                int adw = (row * 68 + xi) * LDSDW + q * 4;        // 16B aligned
                half8 ah = *(const half8*)((const char*)lds + (size_t)adw * 4);
                half8 al = *(const half8*)((const char*)lds + ((size_t)PLANE + adw) * 4);
                int tap = ky * 3 + kx;
                const _Float16* bpp = bp + ((size_t)(chunk * 9 + tap) * 4) * 64 * 8;
#pragma unroll
                for (int nt = 0; nt < 4; ++nt) {
                    half8 bh = *(const half8*)(bpp + ((size_t)nt * 64 + lane) * 8);
                    half8 bl = *(const half8*)(bpp + 110592 + ((size_t)nt * 64 + lane) * 8);
                    acc[nt] = __builtin_amdgcn_mfma_f32_16x16x32_f16(ah, bh, acc[nt], 0, 0, 0);
                    acc[nt] = __builtin_amdgcn_mfma_f32_16x16x32_f16(ah, bl, acc[nt], 0, 0, 0);
                    acc[nt] = __builtin_amdgcn_mfma_f32_16x16x32_f16(al, bh, acc[nt], 0, 0, 0);
                }
            }
        }
    }

    // ---------------- epilogue: LDS transpose, bias+relu, coalesced store --
    __syncthreads();
    // C/D layout: col(co within ntile) = lane&15, row(px within 16) = q*4+reg
#pragma unroll
    for (int nt = 0; nt < 4; ++nt) {
#pragma unroll
        for (int r = 0; r < 4; ++r) {
            int co = nt * 16 + m;
            int pxl = wv * 16 + q * 4 + r;
            ((float*)lds)[co * 64 + pxl] = acc[nt][r];
        }
    }
    __syncthreads();
    {
        int co = tid >> 2, g = tid & 3;
        float bb = b_u1[co];
        const float* lp = (const float*)lds + co * 64 + g * 16;
        float* op = out + ((size_t)(n * 64 + co) * Ho + y) * Wo + x0 + g * 16;
#pragma unroll
        for (int u = 0; u < 16; u += 4) {
            float4 vv = *(const float4*)(lp + u);
            vv.x = fmaxf(vv.x + bb, 0.f);
            vv.y = fmaxf(vv.y + bb, 0.f);
            vv.z = fmaxf(vv.z + bb, 0.f);
            vv.w = fmaxf(vv.w + bb, 0.f);
            *(float4*)(op + u) = vv;
        }
    }
}

// ===========================================================================
// R7 kernels below, unchanged.
// ===========================================================================

// 3x3 stride-1 SAME conv, TCO cos x 8 px per thread.
template <int UPA, int TCO>
__global__ __launch_bounds__(BS, 2) void conv3x3_x8_kernel(
    const float* __restrict__ inA, int Ca,
    const float* __restrict__ inB, int Cb,
    const float* __restrict__ w, const float* __restrict__ b,
    float* __restrict__ out,
    int N, int H, int W, int Cout, int do_relu)
{
    const int W8 = W >> 3;
    int idx = blockIdx.x * BS + threadIdx.x;
    int total = N * H * W8;
    if (idx >= total) return;
    int x8 = idx % W8;
    int t  = idx / W8;
    int y  = t % H;
    int n  = t / H;
    int x0 = x8 << 3;
    const int co0 = blockIdx.y * TCO;
    const bool left_ok  = (x0 > 0);
    const bool right_ok = (x0 + 8 < W);
    const int Cin = Ca + Cb;

    float acc[TCO][8];
#pragma unroll
    for (int j = 0; j < TCO; ++j) {
        float bv = b[co0 + j];
#pragma unroll
        for (int p = 0; p < 8; ++p) acc[j][p] = bv;
    }

    for (int ci = 0; ci < Cin; ++ci) {
        float v[3][10];
#pragma unroll
        for (int ky = 0; ky < 3; ++ky) {
            int iy = y + ky - 1;
            if (iy < 0 || iy >= H) {
#pragma unroll
                for (int p = 0; p < 10; ++p) v[ky][p] = 0.f;
                continue;
            }
            if (UPA == 2 && ci < Ca) {
                const float* r = inA + ((size_t)(n * Ca + ci) * (H >> 1) + (iy >> 1)) * (W >> 1);
                int xh = x0 >> 1;
                float sm = left_ok  ? r[xh - 1] : 0.f;
                float4 qq = *(const float4*)(r + xh);
                float s4 = right_ok ? r[xh + 4] : 0.f;
                v[ky][0] = sm;
                v[ky][1] = qq.x; v[ky][2] = qq.x;
                v[ky][3] = qq.y; v[ky][4] = qq.y;
                v[ky][5] = qq.z; v[ky][6] = qq.z;
                v[ky][7] = qq.w; v[ky][8] = qq.w;
                v[ky][9] = s4;
            } else {
                const float* r = (ci < Ca)
                    ? inA + ((size_t)(n * Ca + ci) * H + iy) * W
                    : inB + ((size_t)(n * Cb + (ci - Ca)) * H + iy) * W;
                v[ky][0] = left_ok ? r[x0 - 1] : 0.f;
                float4 q0 = *(const float4*)(r + x0);
                float4 q1 = *(const float4*)(r + x0 + 4);
                v[ky][1] = q0.x; v[ky][2] = q0.y; v[ky][3] = q0.z; v[ky][4] = q0.w;
                v[ky][5] = q1.x; v[ky][6] = q1.y; v[ky][7] = q1.z; v[ky][8] = q1.w;
                v[ky][9] = right_ok ? r[x0 + 8] : 0.f;
            }
        }
#pragma unroll
        for (int j = 0; j < TCO; ++j) {
            const float* wp = w + ((size_t)(co0 + j) * Cin + ci) * 9;
#pragma unroll
            for (int ky = 0; ky < 3; ++ky) {
                float w0 = wp[ky * 3 + 0], w1 = wp[ky * 3 + 1], w2 = wp[ky * 3 + 2];
#pragma unroll
                for (int p = 0; p < 8; ++p)
                    acc[j][p] += w0 * v[ky][p] + w1 * v[ky][p + 1] + w2 * v[ky][p + 2];
            }
        }
    }

#pragma unroll
    for (int j = 0; j < TCO; ++j) {
#pragma unroll
        for (int p = 0; p < 8; ++p)
            if (do_relu) acc[j][p] = fmaxf(acc[j][p], 0.f);
        float* o = out + ((size_t)(n * Cout + co0 + j) * H + y) * W + x0;
        float4 q0; q0.x = acc[j][0]; q0.y = acc[j][1]; q0.z = acc[j][2]; q0.w = acc[j][3];
        float4 q1; q1.x = acc[j][4]; q1.y = acc[j][5]; q1.z = acc[j][6]; q1.w = acc[j][7];
        *(float4*)o = q0;
        *(float4*)(o + 4) = q1;
    }
}

// u2+seg partial (conv3x3_x8<2,8>-shaped)
__global__ __launch_bounds__(BS, 2) void u2seg_part_kernel(
    const float* __restrict__ u1,
    const float* __restrict__ d1,
    const float* __restrict__ w_u2,
    const float* __restrict__ b_u2,
    const float* __restrict__ w_seg,
    float* __restrict__ segpart,
    int N, int H, int W)
{
    const int W8 = W >> 3;
    int idx = blockIdx.x * BS + threadIdx.x;
    int total = N * H * W8;
    if (idx >= total) return;
    int x8 = idx % W8;
    int t  = idx / W8;
    int y  = t % H;
    int n  = t / H;
    int x0 = x8 << 3;
    const int co0 = blockIdx.y * 8;
    const bool left_ok  = (x0 > 0);
    const bool right_ok = (x0 + 8 < W);
    const int H2 = H >> 1, W2 = W >> 1;

    float acc[8][8];
#pragma unroll
    for (int j = 0; j < 8; ++j) {
        float bv = b_u2[co0 + j];
#pragma unroll
        for (int p = 0; p < 8; ++p) acc[j][p] = bv;
    }

    for (int ci = 0; ci < 96; ++ci) {
        float v[3][10];
#pragma unroll
        for (int ky = 0; ky < 3; ++ky) {
            int iy = y + ky - 1;
            if (iy < 0 || iy >= H) {
#pragma unroll
                for (int p = 0; p < 10; ++p) v[ky][p] = 0.f;
                continue;
            }
            if (ci < 64) {
                const float* r = u1 + ((size_t)(n * 64 + ci) * H2 + (iy >> 1)) * W2;
                int xh = x0 >> 1;
                float sm = left_ok  ? r[xh - 1] : 0.f;
                float4 qq = *(const float4*)(r + xh);
                float s4 = right_ok ? r[xh + 4] : 0.f;
                v[ky][0] = sm;
                v[ky][1] = qq.x; v[ky][2] = qq.x;
                v[ky][3] = qq.y; v[ky][4] = qq.y;
                v[ky][5] = qq.z; v[ky][6] = qq.z;
                v[ky][7] = qq.w; v[ky][8] = qq.w;
                v[ky][9] = s4;
            } else {
                const float* r = d1 + ((size_t)(n * 32 + (ci - 64)) * H + iy) * W;
                v[ky][0] = left_ok ? r[x0 - 1] : 0.f;
                float4 q0 = *(const float4*)(r + x0);
                float4 q1 = *(const float4*)(r + x0 + 4);
                v[ky][1] = q0.x; v[ky][2] = q0.y; v[ky][3] = q0.z; v[ky][4] = q0.w;
                v[ky][5] = q1.x; v[ky][6] = q1.y; v[ky][7] = q1.z; v[ky][8] = q1.w;
                v[ky][9] = right_ok ? r[x0 + 8] : 0.f;
            }
        }
#pragma unroll
        for (int j = 0; j < 8; ++j) {
            const float* wp = w_u2 + ((size_t)(co0 + j) * 96 + ci) * 9;
#pragma unroll
            for (int ky = 0; ky < 3; ++ky) {
                float w0 = wp[ky * 3 + 0], w1 = wp[ky * 3 + 1], w2 = wp[ky * 3 + 2];
#pragma unroll
                for (int p = 0; p < 8; ++p)
                    acc[j][p] += w0 * v[ky][p] + w1 * v[ky][p + 1] + w2 * v[ky][p + 2];
            }
        }
    }

    float s[8];
#pragma unroll
    for (int p = 0; p < 8; ++p) s[p] = 0.f;
#pragma unroll
    for (int j = 0; j < 8; ++j) {
        float wv = w_seg[co0 + j];
#pragma unroll
        for (int p = 0; p < 8; ++p)
            s[p] += wv * fmaxf(acc[j][p], 0.f);
    }
    float* o = segpart + (size_t)blockIdx.y * (N * H * W) + ((size_t)n * H + y) * W + x0;
    float4 q0; q0.x = s[0]; q0.y = s[1]; q0.z = s[2]; q0.w = s[3];
    float4 q1; q1.x = s[4]; q1.y = s[5]; q1.z = s[6]; q1.w = s[7];
    *(float4*)o = q0;
    *(float4*)(o + 4) = q1;
}

__global__ __launch_bounds__(BS) void seg_reduce_kernel(
    const float* __restrict__ segpart, const float* __restrict__ b_seg,
    float* __restrict__ seg, int total)
{
    int q = blockIdx.x * BS + threadIdx.x;
    if (q >= (total >> 2)) return;
    size_t off = (size_t)q << 2;
    float4 a = *(const float4*)(segpart + off);
    float4 b = *(const float4*)(segpart + (size_t)total + off);
    float4 c = *(const float4*)(segpart + 2 * (size_t)total + off);
    float4 d = *(const float4*)(segpart + 3 * (size_t)total + off);
    float bv = b_seg[0];
    float4 o;
    o.x = bv + a.x + b.x + c.x + d.x;
    o.y = bv + a.y + b.y + c.y + d.y;
    o.z = bv + a.z + b.z + c.z + d.z;
    o.w = bv + a.w + b.w + c.w + d.w;
    *(float4*)(seg + off) = o;
}

template <int TCO>
__global__ __launch_bounds__(BS) void conv3x3_s2_co_kernel(
    const float* __restrict__ inA, int Ca,
    const float* __restrict__ inB, int Cb,
    const float* __restrict__ w, const float* __restrict__ b,
    float* __restrict__ out,
    int N, int Hi, int Wi, int Cout, int do_relu)
{
    const int Ho = Hi >> 1, Wo = Wi >> 1, Woq = Wo >> 2;
    int idx = blockIdx.x * BS + threadIdx.x;
    int total = N * Ho * Woq;
    if (idx >= total) return;
    int q  = idx % Woq;
    int t  = idx / Woq;
    int oy = t % Ho;
    int n  = t / Ho;
    int ox0 = q << 2;
    int ix0 = ox0 << 1;
    const int co0 = blockIdx.y * TCO;
    const bool right_ok = (ix0 + 8 < Wi);
    const int Cin = Ca + Cb;

    float acc[TCO][4];
#pragma unroll
    for (int j = 0; j < TCO; ++j) {
        float bv = b[co0 + j];
        acc[j][0] = bv; acc[j][1] = bv; acc[j][2] = bv; acc[j][3] = bv;
    }

    for (int ci = 0; ci < Cin; ++ci) {
        const float* base = (ci < Ca)
            ? inA + (size_t)(n * Ca + ci) * Hi * Wi
            : inB + (size_t)(n * Cb + (ci - Ca)) * Hi * Wi;
        float v[3][9];
#pragma unroll
        for (int ky = 0; ky < 3; ++ky) {
            int iy = 2 * oy + ky;
            if (iy >= Hi) {
#pragma unroll
                for (int p = 0; p < 9; ++p) v[ky][p] = 0.f;
                continue;
            }
            const float* r = base + (size_t)iy * Wi + ix0;
            float4 a = *(const float4*)r;
            float4 c = *(const float4*)(r + 4);
            v[ky][0] = a.x; v[ky][1] = a.y; v[ky][2] = a.z; v[ky][3] = a.w;
            v[ky][4] = c.x; v[ky][5] = c.y; v[ky][6] = c.z; v[ky][7] = c.w;
            v[ky][8] = right_ok ? r[8] : 0.f;
        }
#pragma unroll
        for (int j = 0; j < TCO; ++j) {
            const float* wp = w + ((size_t)(co0 + j) * Cin + ci) * 9;
#pragma unroll
            for (int ky = 0; ky < 3; ++ky) {
                float w0 = wp[ky * 3 + 0], w1 = wp[ky * 3 + 1], w2 = wp[ky * 3 + 2];
#pragma unroll
                for (int p = 0; p < 4; ++p)
                    acc[j][p] += w0 * v[ky][2 * p] + w1 * v[ky][2 * p + 1] + w2 * v[ky][2 * p + 2];
            }
        }
    }

#pragma unroll
    for (int j = 0; j < TCO; ++j) {
        float4 o;
        o.x = acc[j][0]; o.y = acc[j][1]; o.z = acc[j][2]; o.w = acc[j][3];
        if (do_relu) {
            o.x = fmaxf(o.x, 0.f); o.y = fmaxf(o.y, 0.f);
            o.z = fmaxf(o.z, 0.f); o.w = fmaxf(o.w, 0.f);
        }
        *(float4*)(out + ((size_t)(n * Cout + co0 + j) * Ho + oy) * Wo + ox0) = o;
    }
}

__global__ __launch_bounds__(BS) void maxpool2_kernel(
    const float* __restrict__ in, float* __restrict__ out, int NC, int H, int W)
{
    int Ho = H >> 1, Wo = W >> 1, Woq = Wo >> 2;
    int idx = blockIdx.x * BS + threadIdx.x;
    int total = NC * Ho * Woq;
    if (idx >= total) return;
    int x4 = idx % Woq;
    int t  = idx / Woq;
    int y  = t % Ho;
    int c  = t / Ho;
    const float* r0 = in + ((size_t)c * H + 2 * y) * W + 8 * x4;
    const float* r1 = r0 + W;
    float4 a0 = *(const float4*)r0;
    float4 a1 = *(const float4*)(r0 + 4);
    float4 b0 = *(const float4*)r1;
    float4 b1 = *(const float4*)(r1 + 4);
    float4 o;
    o.x = fmaxf(fmaxf(a0.x, a0.y), fmaxf(b0.x, b0.y));
    o.y = fmaxf(fmaxf(a0.z, a0.w), fmaxf(b0.z, b0.w));
    o.z = fmaxf(fmaxf(a1.x, a1.y), fmaxf(b1.x, b1.y));
    o.w = fmaxf(fmaxf(a1.z, a1.w), fmaxf(b1.z, b1.w));
    *(float4*)(out + ((size_t)c * Ho + y) * Wo + 4 * x4) = o;
}

template <int TCO>
__global__ __launch_bounds__(BS) void conv1x1_co_kernel(
    const float* __restrict__ in, const float* __restrict__ w,
    const float* __restrict__ b, float* __restrict__ out,
    int N, int Cin, int HW, int Cout, int do_relu)
{
    int HWq = HW >> 2;
    int idx = blockIdx.x * BS + threadIdx.x;
    int total = N * HWq;
    if (idx >= total) return;
    int q = idx % HWq;
    int n = idx / HWq;
    const int co0 = blockIdx.y * TCO;

    float acc[TCO][4];
#pragma unroll
    for (int j = 0; j < TCO; ++j) {
        int co = min(co0 + j, Cout - 1);
        float bv = b[co];
        acc[j][0] = bv; acc[j][1] = bv; acc[j][2] = bv; acc[j][3] = bv;
    }
    const float* base = in + (size_t)n * Cin * HW + 4 * q;
    for (int ci = 0; ci < Cin; ++ci) {
        float4 v = *(const float4*)(base + (size_t)ci * HW);
#pragma unroll
        for (int j = 0; j < TCO; ++j) {
            int co = min(co0 + j, Cout - 1);
            float wv = w[(size_t)co * Cin + ci];
            acc[j][0] += wv * v.x; acc[j][1] += wv * v.y;
            acc[j][2] += wv * v.z; acc[j][3] += wv * v.w;
        }
    }
#pragma unroll
    for (int j = 0; j < TCO; ++j) {
        if (co0 + j >= Cout) break;
        float4 o;
        o.x = acc[j][0]; o.y = acc[j][1]; o.z = acc[j][2]; o.w = acc[j][3];
        if (do_relu) {
            o.x = fmaxf(o.x, 0.f); o.y = fmaxf(o.y, 0.f);
            o.z = fmaxf(o.z, 0.f); o.w = fmaxf(o.w, 0.f);
        }
        *(float4*)(out + ((size_t)(n * Cout + co0 + j)) * HW + 4 * q) = o;
    }
}

__global__ __launch_bounds__(BS) void peaks_kernel(
    const float* __restrict__ hm, float* __restrict__ out,
    int NC, int H, int W, float thresh)
{
    int idx = blockIdx.x * BS + threadIdx.x;
    int total = NC * H * W;
    if (idx >= total) return;
    int x = idx % W;
    int t = idx / W;
    int y = t % H;
    int c = t / H;
    float r = 0.f;
    if (x >= 1 && x < W - 1 && y >= 1 && y < H - 1) {
        const float* base = hm + (size_t)c * H * W;
        float cv = base[y * W + x];
        if (cv > thresh &&
            cv >= base[(y - 1) * W + x] &&
            cv >= base[(y + 1) * W + x] &&
            cv >= base[y * W + (x - 1)] &&
            cv >= base[y * W + (x + 1)])
            r = 1.f;
    }
    out[idx] = r;
}

static inline int nblk(long n) { return (int)((n + BS - 1) / BS); }

extern "C" void kernel_launch(void* const* d_in, const int* in_sizes, int n_in,
                              void* d_out, int out_size, void* d_ws, size_t ws_size,
                              hipStream_t stream)
{
    const float* x     = (const float*)d_in[0];
    const float* w_d1  = (const float*)d_in[1];  const float* b_d1  = (const float*)d_in[2];
    const float* w_d2  = (const float*)d_in[3];  const float* b_d2  = (const float*)d_in[4];
    const float* w_bn  = (const float*)d_in[5];  const float* b_bn  = (const float*)d_in[6];
    const float* w_u1  = (const float*)d_in[7];  const float* b_u1  = (const float*)d_in[8];
    const float* w_u2  = (const float*)d_in[9];  const float* b_u2  = (const float*)d_in[10];
    const float* w_seg = (const float*)d_in[11]; const float* b_seg = (const float*)d_in[12];
    const float* w_p1  = (const float*)d_in[13]; const float* b_p1  = (const float*)d_in[14];
    const float* w_p2  = (const float*)d_in[15]; const float* b_p2  = (const float*)d_in[16];
    const float* w_hm  = (const float*)d_in[17]; const float* b_hm  = (const float*)d_in[18];
    const float* w_paf = (const float*)d_in[19]; const float* b_paf = (const float*)d_in[20];

    const int N = 8, H = 384, W = 384;
    const int H2 = 192, W2 = 192, H4 = 96, W4 = 96;
    const int HW = H * W;

    float* ws = (float*)d_ws;
    // Workspace extent = 56,623,104 floats = 216 MiB (R2 lifetime map).
    float* u1  = ws;                   // 8*64*192*192 = 18874368
    float* d1  = ws + 18874368;        // 8*32*384*384 = 37748736
    float* d2  = ws + 18874368;        // 8*64*192*192 = 18874368
    float* bn  = ws + 37748736;        // 8*128*96*96  = 9437184
    float* pd1 = ws;                   // 8*32*192*192 = 9437184
    float* pd2 = ws + 47185920;        // 8*64*96*96   = 4718592
    float* p1  = ws;                   // 8*64*192*192 = 18874368
    float* p2  = ws + 18874368;        // 8*128*96*96  = 9437184

    float* out_seg   = (float*)d_out;                 // 1179648
    float* out_hm    = out_seg + 1179648;             // 1253376
    float* out_paf   = out_hm + 1253376;              // 2359296
    float* out_peaks = out_paf + 2359296;             // 1253376
    float* segpart = out_hm;                          // [4][N*H*W] until step 11
    // packed u1 weights: d_out tail [5898240, 6045696) floats (after segpart's
    // 4*1179648 span, inside peaks region - overwritten by step 13 AFTER use).
    _Float16* bp_u1 = (_Float16*)(out_seg + 5898240); // 221184 f16 = 110592 fl

    // 0. pack u1 weights (fragment-ready f16 hi/lo)
    packw_u1_kernel<<<nblk(13824), BS, 0, stream>>>(w_u1, bp_u1);
    // 1. d1 = relu(conv3x3(x; 3->32)) @384
    {
        dim3 g(nblk((long)N * H * (W / 8)), 32 / 8);
        conv3x3_x8_kernel<1, 8><<<g, BS, 0, stream>>>(
            x, 3, nullptr, 0, w_d1, b_d1, d1, N, H, W, 32, 1);
    }
    // 2. pd1 = maxpool(d1) @192
    maxpool2_kernel<<<nblk((long)N * 32 * H2 * (W2 / 4)), BS, 0, stream>>>(d1, pd1, N * 32, H, W);
    // 3. d2 = relu(conv3x3(pd1; 32->64)) @192
    {
        dim3 g(nblk((long)N * H2 * (W2 / 8)), 64 / 8);
        conv3x3_x8_kernel<1, 8><<<g, BS, 0, stream>>>(
            pd1, 32, nullptr, 0, w_d2, b_d2, d2, N, H2, W2, 64, 1);
    }
    // 4. pd2 = maxpool(d2) @96
    maxpool2_kernel<<<nblk((long)N * 64 * H4 * (W4 / 4)), BS, 0, stream>>>(d2, pd2, N * 64, H2, W2);
    // 5. bn = relu(conv3x3(pd2; 64->128)) @96
    {
        dim3 g(nblk((long)N * H4 * (W4 / 8)), 128 / 8);
        conv3x3_x8_kernel<1, 8><<<g, BS, 0, stream>>>(
            pd2, 64, nullptr, 0, w_bn, b_bn, bn, N, H4, W4, 128, 1);
    }
    // 6. u1 = relu(conv3x3(concat(up2(bn), d2); 192->64)) @192  [MFMA f16x3]
    u1_mfma_kernel<<<4608, BS, 0, stream>>>(bn, d2, bp_u1, b_u1, u1);
    // 7. d1' = relu(conv3x3(x; 3->32)) @384  (recompute)
    {
        dim3 g(nblk((long)N * H * (W / 8)), 32 / 8);
        conv3x3_x8_kernel<1, 8><<<g, BS, 0, stream>>>(
            x, 3, nullptr, 0, w_d1, b_d1, d1, N, H, W, 32, 1);
    }
    // 8a. seg partials (4 co groups)
    {
        dim3 g(nblk((long)N * H * (W / 8)), 4);
        u2seg_part_kernel<<<g, BS, 0, stream>>>(
            u1, d1, w_u2, b_u2, w_seg, segpart, N, H, W);
    }
    // 8b. seg = b_seg + sum partials
    seg_reduce_kernel<<<nblk((long)N * HW / 4), BS, 0, stream>>>(
        segpart, b_seg, out_seg, N * HW);
    // 9. p1 = relu(conv3x3_s2(concat(x, seg); 4->64)) @384->192
    {
        dim3 g(nblk((long)N * H2 * (W2 / 4)), 64 / 8);
        conv3x3_s2_co_kernel<8><<<g, BS, 0, stream>>>(
            x, 3, out_seg, 1, w_p1, b_p1, p1, N, H, W, 64, 1);
    }
    // 10. p2 = relu(conv3x3_s2(p1; 64->128)) @192->96
    {
        dim3 g(nblk((long)N * H4 * (W4 / 4)), 128 / 8);
        conv3x3_s2_co_kernel<8><<<g, BS, 0, stream>>>(
            p1, 64, nullptr, 0, w_p2, b_p2, p2, N, H2, W2, 128, 1);
    }
    // 11. hm = conv1x1(p2; 128->17) @96
    {
        dim3 g(nblk((long)N * (H4 * W4 / 4)), 3);
        conv1x1_co_kernel<8><<<g, BS, 0, stream>>>(
            p2, w_hm, b_hm, out_hm, N, 128, H4 * W4, 17, 0);
    }
    // 12. paf = conv1x1(p2; 128->32) @96
    {
        dim3 g(nblk((long)N * (H4 * W4 / 4)), 4);
        conv1x1_co_kernel<8><<<g, BS, 0, stream>>>(
            p2, w_paf, b_paf, out_paf, N, 128, H4 * W4, 32, 0);
    }
    // 13. peaks @96  (overwrites bp_u1 region - safe, already consumed)
    peaks_kernel<<<nblk((long)N * 17 * H4 * W4), BS, 0, stream>>>(
        out_hm, out_peaks, N * 17, H4, W4, 0.1f);
}

// Round 9
// 2016.897 us; speedup vs baseline: 2.3236x; 1.2130x over previous
//
#include <hip/hip_runtime.h>

// ---------------------------------------------------------------------------
// TeacherModel: small U-Net + pose heads. B=8, H=W=384, fp32 NCHW.
// Round 9: u2+seg -> MFMA engine (same f16 hi/lo 3-term split validated in R8
// by u1: absmax unchanged). One block = 64 px x ALL 32 cos, so seg fuses
// in-register (shfl_xor reduce over 16 co-lanes) - no segpart, no seg_reduce,
// no 4x input re-read (R8: u2seg_part 1065us, VALU 75%, 644MB FETCH).
// ---------------------------------------------------------------------------

#define BS 256

typedef _Float16 half8 __attribute__((ext_vector_type(8)));
typedef float floatx4 __attribute__((ext_vector_type(4)));

#define LDSDW 20   // dwords per x position
#define PLANE 4080 // 3*68*LDSDW dwords per plane

// ===========================================================================
// Weight pre-pack (fragment-ready per-lane blobs), u1: 192 Cin -> 6 chunks.
// layout: [plane(hi/lo)][chunk][tap(9)][ntile][lane(64)][8 f16]
// element: ci = chunk*32 + (lane>>4)*8 + j ; co = ntile*16 + (lane&15)
// ===========================================================================
__global__ __launch_bounds__(BS) void packw_u1_kernel(
    const float* __restrict__ w, _Float16* __restrict__ bp)
{
    int tid = blockIdx.x * BS + threadIdx.x;          // 6*9*4*64 = 13824
    if (tid >= 13824) return;
    int lane = tid & 63;
    int t = tid >> 6;
    int nt = t & 3; t >>= 2;
    int tap = t % 9;
    int chunk = t / 9;
    int q = lane >> 4, n = lane & 15;
    int co = nt * 16 + n;
    _Float16* ph = bp + (size_t)tid * 8;
    _Float16* pl = bp + 110592 + (size_t)tid * 8;     // plane = 6*9*4*64*8
#pragma unroll
    for (int j = 0; j < 8; ++j) {
        int ci = chunk * 32 + q * 8 + j;
        float v = w[((size_t)co * 192 + ci) * 9 + tap];
        _Float16 h = (_Float16)v;
        ph[j] = h;
        pl[j] = (_Float16)(v - (float)h);
    }
}

// u2: [32,96,3,3] -> 3 chunks x 9 taps x 2 ntiles
__global__ __launch_bounds__(BS) void packw_u2_kernel(
    const float* __restrict__ w, _Float16* __restrict__ bp)
{
    int tid = blockIdx.x * BS + threadIdx.x;          // 3*9*2*64 = 3456
    if (tid >= 3456) return;
    int lane = tid & 63;
    int t = tid >> 6;
    int nt = t & 1; t >>= 1;
    int tap = t % 9;
    int chunk = t / 9;
    int q = lane >> 4, n = lane & 15;
    int co = nt * 16 + n;
    _Float16* ph = bp + (size_t)tid * 8;
    _Float16* pl = bp + 27648 + (size_t)tid * 8;      // plane = 3*9*2*64*8
#pragma unroll
    for (int j = 0; j < 8; ++j) {
        int ci = chunk * 32 + q * 8 + j;
        float v = w[((size_t)co * 96 + ci) * 9 + tap];
        _Float16 h = (_Float16)v;
        ph[j] = h;
        pl[j] = (_Float16)(v - (float)h);
    }
}

// ===========================================================================
// u1 = relu(conv3x3(concat(up2(bn), d2))) via MFMA, 64 px/block @192.
// ===========================================================================
__global__ __launch_bounds__(BS) void u1_mfma_kernel(
    const float* __restrict__ bn_,   // [8,128,96,96]
    const float* __restrict__ d2_,   // [8,64,192,192]
    const _Float16* __restrict__ bp, // packed weights
    const float* __restrict__ b_u1,  // [64]
    float* __restrict__ out)         // [8,64,192,192]
{
    __shared__ unsigned int lds[2 * PLANE];
    const int Ho = 192, Wo = 192;
    int pxbase = blockIdx.x * 64;
    int yy = pxbase / Wo;
    int x0 = pxbase % Wo;
    int n = yy / Ho;
    int y = yy % Ho;

    int tid = threadIdx.x;
    int lane = tid & 63, wv = tid >> 6;
    int m = lane & 15, q = lane >> 4;
    int wx = x0 + wv * 16;

    floatx4 acc[4];
#pragma unroll
    for (int nt = 0; nt < 4; ++nt) acc[nt] = (floatx4){0.f, 0.f, 0.f, 0.f};

    const int h0  = (y - 1) >> 1;
    const int hx0 = (x0 - 1) >> 1;

    for (int chunk = 0; chunk < 6; ++chunk) {
        __syncthreads();
        if (chunk < 4) {
            for (int e = tid; e < 2 * 34 * 32; e += BS) {
                int xi = e % 34;
                int rest = e / 34;
                int ci = rest & 31;
                int row = rest >> 5;
                int hy = h0 + row, hx = hx0 + xi;
                float v = (hy >= 0 && hy < 96 && hx >= 0 && hx < 96)
                    ? bn_[((size_t)(n * 128 + chunk * 32 + ci) * 96 + hy) * 96 + hx] : 0.f;
                _Float16 h = (_Float16)v;
                _Float16 l = (_Float16)(v - (float)h);
                int base = (row * 68 + xi) * LDSDW + (ci >> 1);
                ((_Float16*)lds)[(size_t)base * 2 + (ci & 1)] = h;
                ((_Float16*)lds)[((size_t)PLANE + base) * 2 + (ci & 1)] = l;
            }
        } else {
            for (int e = tid; e < 3 * 68 * 32; e += BS) {
                int xi = e % 68;
                int rest = e / 68;
                int ci = rest & 31;
                int row = rest >> 5;
                int iy = y - 1 + row, gx = x0 - 1 + xi;
                float v = (xi < 67 && iy >= 0 && iy < Ho && gx >= 0 && gx < Wo)
                    ? d2_[((size_t)(n * 64 + (chunk - 4) * 32 + ci) * Ho + iy) * Wo + gx] : 0.f;
                _Float16 h = (_Float16)v;
                _Float16 l = (_Float16)(v - (float)h);
                int base = (row * 68 + xi) * LDSDW + (ci >> 1);
                ((_Float16*)lds)[(size_t)base * 2 + (ci & 1)] = h;
                ((_Float16*)lds)[((size_t)PLANE + base) * 2 + (ci & 1)] = l;
            }
        }
        __syncthreads();
#pragma unroll
        for (int ky = 0; ky < 3; ++ky) {
#pragma unroll
            for (int kx = 0; kx < 3; ++kx) {
                int row, xi;
                if (chunk < 4) {
                    row = ((y + ky - 1) >> 1) - h0;
                    xi  = ((wx + m + kx - 1) >> 1) - hx0;
                } else {
                    row = ky;
                    xi  = (wx - x0) + m + kx;
                }
                int adw = (row * 68 + xi) * LDSDW + q * 4;
                half8 ah = *(const half8*)((const char*)lds + (size_t)adw * 4);
                half8 al = *(const half8*)((const char*)lds + ((size_t)PLANE + adw) * 4);
                int tap = ky * 3 + kx;
                const _Float16* bpp = bp + ((size_t)(chunk * 9 + tap) * 4) * 64 * 8;
#pragma unroll
                for (int nt = 0; nt < 4; ++nt) {
                    half8 bh = *(const half8*)(bpp + ((size_t)nt * 64 + lane) * 8);
                    half8 bl = *(const half8*)(bpp + 110592 + ((size_t)nt * 64 + lane) * 8);
                    acc[nt] = __builtin_amdgcn_mfma_f32_16x16x32_f16(ah, bh, acc[nt], 0, 0, 0);
                    acc[nt] = __builtin_amdgcn_mfma_f32_16x16x32_f16(ah, bl, acc[nt], 0, 0, 0);
                    acc[nt] = __builtin_amdgcn_mfma_f32_16x16x32_f16(al, bh, acc[nt], 0, 0, 0);
                }
            }
        }
    }

    __syncthreads();
#pragma unroll
    for (int nt = 0; nt < 4; ++nt) {
#pragma unroll
        for (int r = 0; r < 4; ++r) {
            int co = nt * 16 + m;
            int pxl = wv * 16 + q * 4 + r;
            ((float*)lds)[co * 64 + pxl] = acc[nt][r];
        }
    }
    __syncthreads();
    {
        int co = tid >> 2, g = tid & 3;
        float bb = b_u1[co];
        const float* lp = (const float*)lds + co * 64 + g * 16;
        float* op = out + ((size_t)(n * 64 + co) * Ho + y) * Wo + x0 + g * 16;
#pragma unroll
        for (int u = 0; u < 16; u += 4) {
            float4 vv = *(const float4*)(lp + u);
            vv.x = fmaxf(vv.x + bb, 0.f);
            vv.y = fmaxf(vv.y + bb, 0.f);
            vv.z = fmaxf(vv.z + bb, 0.f);
            vv.w = fmaxf(vv.w + bb, 0.f);
            *(float4*)(op + u) = vv;
        }
    }
}

// ===========================================================================
// seg = b_seg + sum_co w_seg[co]*relu(conv3x3(concat(up2(u1), d1))[co] + b_u2)
// via MFMA; 64 px/block @384; seg fused in-register (shfl_xor over co lanes).
// ===========================================================================
__global__ __launch_bounds__(BS) void u2seg_mfma_kernel(
    const float* __restrict__ u1_,   // [8,64,192,192]
    const float* __restrict__ d1_,   // [8,32,384,384]
    const _Float16* __restrict__ bp, // packed u2 weights
    const float* __restrict__ b_u2,  // [32]
    const float* __restrict__ w_seg, // [32]
    const float* __restrict__ b_seg, // [1]
    float* __restrict__ seg)         // [8,1,384,384]
{
    __shared__ unsigned int lds[2 * PLANE];
    const int Ho = 384, Wo = 384;
    int pxbase = blockIdx.x * 64;
    int yy = pxbase / Wo;
    int x0 = pxbase % Wo;
    int n = yy / Ho;
    int y = yy % Ho;

    int tid = threadIdx.x;
    int lane = tid & 63, wv = tid >> 6;
    int m = lane & 15, q = lane >> 4;
    int wx = x0 + wv * 16;

    floatx4 acc[2];
    acc[0] = (floatx4){0.f, 0.f, 0.f, 0.f};
    acc[1] = (floatx4){0.f, 0.f, 0.f, 0.f};

    const int h0  = (y - 1) >> 1;
    const int hx0 = (x0 - 1) >> 1;

    for (int chunk = 0; chunk < 3; ++chunk) {
        __syncthreads();
        if (chunk < 2) {
            // u1 half-res: rows h0,h0+1; x hx0..hx0+33
            for (int e = tid; e < 2 * 34 * 32; e += BS) {
                int xi = e % 34;
                int rest = e / 34;
                int ci = rest & 31;
                int row = rest >> 5;
                int hy = h0 + row, hx = hx0 + xi;
                float v = (hy >= 0 && hy < 192 && hx >= 0 && hx < 192)
                    ? u1_[((size_t)(n * 64 + chunk * 32 + ci) * 192 + hy) * 192 + hx] : 0.f;
                _Float16 h = (_Float16)v;
                _Float16 l = (_Float16)(v - (float)h);
                int base = (row * 68 + xi) * LDSDW + (ci >> 1);
                ((_Float16*)lds)[(size_t)base * 2 + (ci & 1)] = h;
                ((_Float16*)lds)[((size_t)PLANE + base) * 2 + (ci & 1)] = l;
            }
        } else {
            // d1 full-res: rows y-1..y+1; x x0-1..x0+65
            for (int e = tid; e < 3 * 68 * 32; e += BS) {
                int xi = e % 68;
                int rest = e / 68;
                int ci = rest & 31;
                int row = rest >> 5;
                int iy = y - 1 + row, gx = x0 - 1 + xi;
                float v = (xi < 67 && iy >= 0 && iy < Ho && gx >= 0 && gx < Wo)
                    ? d1_[((size_t)(n * 32 + ci) * Ho + iy) * Wo + gx] : 0.f;
                _Float16 h = (_Float16)v;
                _Float16 l = (_Float16)(v - (float)h);
                int base = (row * 68 + xi) * LDSDW + (ci >> 1);
                ((_Float16*)lds)[(size_t)base * 2 + (ci & 1)] = h;
                ((_Float16*)lds)[((size_t)PLANE + base) * 2 + (ci & 1)] = l;
            }
        }
        __syncthreads();
#pragma unroll
        for (int ky = 0; ky < 3; ++ky) {
#pragma unroll
            for (int kx = 0; kx < 3; ++kx) {
                int row, xi;
                if (chunk < 2) {
                    row = ((y + ky - 1) >> 1) - h0;
                    xi  = ((wx + m + kx - 1) >> 1) - hx0;
                } else {
                    row = ky;
                    xi  = (wx - x0) + m + kx;
                }
                int adw = (row * 68 + xi) * LDSDW + q * 4;
                half8 ah = *(const half8*)((const char*)lds + (size_t)adw * 4);
                half8 al = *(const half8*)((const char*)lds + ((size_t)PLANE + adw) * 4);
                int tap = ky * 3 + kx;
                const _Float16* bpp = bp + ((size_t)(chunk * 9 + tap) * 2) * 64 * 8;
#pragma unroll
                for (int nt = 0; nt < 2; ++nt) {
                    half8 bh = *(const half8*)(bpp + ((size_t)nt * 64 + lane) * 8);
                    half8 bl = *(const half8*)(bpp + 27648 + ((size_t)nt * 64 + lane) * 8);
                    acc[nt] = __builtin_amdgcn_mfma_f32_16x16x32_f16(ah, bh, acc[nt], 0, 0, 0);
                    acc[nt] = __builtin_amdgcn_mfma_f32_16x16x32_f16(ah, bl, acc[nt], 0, 0, 0);
                    acc[nt] = __builtin_amdgcn_mfma_f32_16x16x32_f16(al, bh, acc[nt], 0, 0, 0);
                }
            }
        }
    }

    // epilogue: lane holds u2-prebias for co=nt*16+m, px=wv*16+q*4+r.
    float bb0 = b_u2[m], bb1 = b_u2[16 + m];
    float ws0 = w_seg[m], ws1 = w_seg[16 + m];
    float bseg = b_seg[0];
    float sr[4];
#pragma unroll
    for (int r = 0; r < 4; ++r) {
        float p = ws0 * fmaxf(acc[0][r] + bb0, 0.f)
                + ws1 * fmaxf(acc[1][r] + bb1, 0.f);
        p += __shfl_xor(p, 1);
        p += __shfl_xor(p, 2);
        p += __shfl_xor(p, 4);
        p += __shfl_xor(p, 8);
        sr[r] = p + bseg;
    }
    if (m == 0) {
        float4 o; o.x = sr[0]; o.y = sr[1]; o.z = sr[2]; o.w = sr[3];
        *(float4*)(seg + ((size_t)n * Ho + y) * Wo + wx + q * 4) = o;
    }
}

// ===========================================================================
// R7/R8 vector kernels, unchanged.
// ===========================================================================

template <int UPA, int TCO>
__global__ __launch_bounds__(BS, 2) void conv3x3_x8_kernel(
    const float* __restrict__ inA, int Ca,
    const float* __restrict__ inB, int Cb,
    const float* __restrict__ w, const float* __restrict__ b,
    float* __restrict__ out,
    int N, int H, int W, int Cout, int do_relu)
{
    const int W8 = W >> 3;
    int idx = blockIdx.x * BS + threadIdx.x;
    int total = N * H * W8;
    if (idx >= total) return;
    int x8 = idx % W8;
    int t  = idx / W8;
    int y  = t % H;
    int n  = t / H;
    int x0 = x8 << 3;
    const int co0 = blockIdx.y * TCO;
    const bool left_ok  = (x0 > 0);
    const bool right_ok = (x0 + 8 < W);
    const int Cin = Ca + Cb;

    float acc[TCO][8];
#pragma unroll
    for (int j = 0; j < TCO; ++j) {
        float bv = b[co0 + j];
#pragma unroll
        for (int p = 0; p < 8; ++p) acc[j][p] = bv;
    }

    for (int ci = 0; ci < Cin; ++ci) {
        float v[3][10];
#pragma unroll
        for (int ky = 0; ky < 3; ++ky) {
            int iy = y + ky - 1;
            if (iy < 0 || iy >= H) {
#pragma unroll
                for (int p = 0; p < 10; ++p) v[ky][p] = 0.f;
                continue;
            }
            if (UPA == 2 && ci < Ca) {
                const float* r = inA + ((size_t)(n * Ca + ci) * (H >> 1) + (iy >> 1)) * (W >> 1);
                int xh = x0 >> 1;
                float sm = left_ok  ? r[xh - 1] : 0.f;
                float4 qq = *(const float4*)(r + xh);
                float s4 = right_ok ? r[xh + 4] : 0.f;
                v[ky][0] = sm;
                v[ky][1] = qq.x; v[ky][2] = qq.x;
                v[ky][3] = qq.y; v[ky][4] = qq.y;
                v[ky][5] = qq.z; v[ky][6] = qq.z;
                v[ky][7] = qq.w; v[ky][8] = qq.w;
                v[ky][9] = s4;
            } else {
                const float* r = (ci < Ca)
                    ? inA + ((size_t)(n * Ca + ci) * H + iy) * W
                    : inB + ((size_t)(n * Cb + (ci - Ca)) * H + iy) * W;
                v[ky][0] = left_ok ? r[x0 - 1] : 0.f;
                float4 q0 = *(const float4*)(r + x0);
                float4 q1 = *(const float4*)(r + x0 + 4);
                v[ky][1] = q0.x; v[ky][2] = q0.y; v[ky][3] = q0.z; v[ky][4] = q0.w;
                v[ky][5] = q1.x; v[ky][6] = q1.y; v[ky][7] = q1.z; v[ky][8] = q1.w;
                v[ky][9] = right_ok ? r[x0 + 8] : 0.f;
            }
        }
#pragma unroll
        for (int j = 0; j < TCO; ++j) {
            const float* wp = w + ((size_t)(co0 + j) * Cin + ci) * 9;
#pragma unroll
            for (int ky = 0; ky < 3; ++ky) {
                float w0 = wp[ky * 3 + 0], w1 = wp[ky * 3 + 1], w2 = wp[ky * 3 + 2];
#pragma unroll
                for (int p = 0; p < 8; ++p)
                    acc[j][p] += w0 * v[ky][p] + w1 * v[ky][p + 1] + w2 * v[ky][p + 2];
            }
        }
    }

#pragma unroll
    for (int j = 0; j < TCO; ++j) {
#pragma unroll
        for (int p = 0; p < 8; ++p)
            if (do_relu) acc[j][p] = fmaxf(acc[j][p], 0.f);
        float* o = out + ((size_t)(n * Cout + co0 + j) * H + y) * W + x0;
        float4 q0; q0.x = acc[j][0]; q0.y = acc[j][1]; q0.z = acc[j][2]; q0.w = acc[j][3];
        float4 q1; q1.x = acc[j][4]; q1.y = acc[j][5]; q1.z = acc[j][6]; q1.w = acc[j][7];
        *(float4*)o = q0;
        *(float4*)(o + 4) = q1;
    }
}

template <int TCO>
__global__ __launch_bounds__(BS) void conv3x3_s2_co_kernel(
    const float* __restrict__ inA, int Ca,
    const float* __restrict__ inB, int Cb,
    const float* __restrict__ w, const float* __restrict__ b,
    float* __restrict__ out,
    int N, int Hi, int Wi, int Cout, int do_relu)
{
    const int Ho = Hi >> 1, Wo = Wi >> 1, Woq = Wo >> 2;
    int idx = blockIdx.x * BS + threadIdx.x;
    int total = N * Ho * Woq;
    if (idx >= total) return;
    int q  = idx % Woq;
    int t  = idx / Woq;
    int oy = t % Ho;
    int n  = t / Ho;
    int ox0 = q << 2;
    int ix0 = ox0 << 1;
    const int co0 = blockIdx.y * TCO;
    const bool right_ok = (ix0 + 8 < Wi);
    const int Cin = Ca + Cb;

    float acc[TCO][4];
#pragma unroll
    for (int j = 0; j < TCO; ++j) {
        float bv = b[co0 + j];
        acc[j][0] = bv; acc[j][1] = bv; acc[j][2] = bv; acc[j][3] = bv;
    }

    for (int ci = 0; ci < Cin; ++ci) {
        const float* base = (ci < Ca)
            ? inA + (size_t)(n * Ca + ci) * Hi * Wi
            : inB + (size_t)(n * Cb + (ci - Ca)) * Hi * Wi;
        float v[3][9];
#pragma unroll
        for (int ky = 0; ky < 3; ++ky) {
            int iy = 2 * oy + ky;
            if (iy >= Hi) {
#pragma unroll
                for (int p = 0; p < 9; ++p) v[ky][p] = 0.f;
                continue;
            }
            const float* r = base + (size_t)iy * Wi + ix0;
            float4 a = *(const float4*)r;
            float4 c = *(const float4*)(r + 4);
            v[ky][0] = a.x; v[ky][1] = a.y; v[ky][2] = a.z; v[ky][3] = a.w;
            v[ky][4] = c.x; v[ky][5] = c.y; v[ky][6] = c.z; v[ky][7] = c.w;
            v[ky][8] = right_ok ? r[8] : 0.f;
        }
#pragma unroll
        for (int j = 0; j < TCO; ++j) {
            const float* wp = w + ((size_t)(co0 + j) * Cin + ci) * 9;
#pragma unroll
            for (int ky = 0; ky < 3; ++ky) {
                float w0 = wp[ky * 3 + 0], w1 = wp[ky * 3 + 1], w2 = wp[ky * 3 + 2];
#pragma unroll
                for (int p = 0; p < 4; ++p)
                    acc[j][p] += w0 * v[ky][2 * p] + w1 * v[ky][2 * p + 1] + w2 * v[ky][2 * p + 2];
            }
        }
    }

#pragma unroll
    for (int j = 0; j < TCO; ++j) {
        float4 o;
        o.x = acc[j][0]; o.y = acc[j][1]; o.z = acc[j][2]; o.w = acc[j][3];
        if (do_relu) {
            o.x = fmaxf(o.x, 0.f); o.y = fmaxf(o.y, 0.f);
            o.z = fmaxf(o.z, 0.f); o.w = fmaxf(o.w, 0.f);
        }
        *(float4*)(out + ((size_t)(n * Cout + co0 + j) * Ho + oy) * Wo + ox0) = o;
    }
}

__global__ __launch_bounds__(BS) void maxpool2_kernel(
    const float* __restrict__ in, float* __restrict__ out, int NC, int H, int W)
{
    int Ho = H >> 1, Wo = W >> 1, Woq = Wo >> 2;
    int idx = blockIdx.x * BS + threadIdx.x;
    int total = NC * Ho * Woq;
    if (idx >= total) return;
    int x4 = idx % Woq;
    int t  = idx / Woq;
    int y  = t % Ho;
    int c  = t / Ho;
    const float* r0 = in + ((size_t)c * H + 2 * y) * W + 8 * x4;
    const float* r1 = r0 + W;
    float4 a0 = *(const float4*)r0;
    float4 a1 = *(const float4*)(r0 + 4);
    float4 b0 = *(const float4*)r1;
    float4 b1 = *(const float4*)(r1 + 4);
    float4 o;
    o.x = fmaxf(fmaxf(a0.x, a0.y), fmaxf(b0.x, b0.y));
    o.y = fmaxf(fmaxf(a0.z, a0.w), fmaxf(b0.z, b0.w));
    o.z = fmaxf(fmaxf(a1.x, a1.y), fmaxf(b1.x, b1.y));
    o.w = fmaxf(fmaxf(a1.z, a1.w), fmaxf(b1.z, b1.w));
    *(float4*)(out + ((size_t)c * Ho + y) * Wo + 4 * x4) = o;
}

template <int TCO>
__global__ __launch_bounds__(BS) void conv1x1_co_kernel(
    const float* __restrict__ in, const float* __restrict__ w,
    const float* __restrict__ b, float* __restrict__ out,
    int N, int Cin, int HW, int Cout, int do_relu)
{
    int HWq = HW >> 2;
    int idx = blockIdx.x * BS + threadIdx.x;
    int total = N * HWq;
    if (idx >= total) return;
    int q = idx % HWq;
    int n = idx / HWq;
    const int co0 = blockIdx.y * TCO;

    float acc[TCO][4];
#pragma unroll
    for (int j = 0; j < TCO; ++j) {
        int co = min(co0 + j, Cout - 1);
        float bv = b[co];
        acc[j][0] = bv; acc[j][1] = bv; acc[j][2] = bv; acc[j][3] = bv;
    }
    const float* base = in + (size_t)n * Cin * HW + 4 * q;
    for (int ci = 0; ci < Cin; ++ci) {
        float4 v = *(const float4*)(base + (size_t)ci * HW);
#pragma unroll
        for (int j = 0; j < TCO; ++j) {
            int co = min(co0 + j, Cout - 1);
            float wv = w[(size_t)co * Cin + ci];
            acc[j][0] += wv * v.x; acc[j][1] += wv * v.y;
            acc[j][2] += wv * v.z; acc[j][3] += wv * v.w;
        }
    }
#pragma unroll
    for (int j = 0; j < TCO; ++j) {
        if (co0 + j >= Cout) break;
        float4 o;
        o.x = acc[j][0]; o.y = acc[j][1]; o.z = acc[j][2]; o.w = acc[j][3];
        if (do_relu) {
            o.x = fmaxf(o.x, 0.f); o.y = fmaxf(o.y, 0.f);
            o.z = fmaxf(o.z, 0.f); o.w = fmaxf(o.w, 0.f);
        }
        *(float4*)(out + ((size_t)(n * Cout + co0 + j)) * HW + 4 * q) = o;
    }
}

__global__ __launch_bounds__(BS) void peaks_kernel(
    const float* __restrict__ hm, float* __restrict__ out,
    int NC, int H, int W, float thresh)
{
    int idx = blockIdx.x * BS + threadIdx.x;
    int total = NC * H * W;
    if (idx >= total) return;
    int x = idx % W;
    int t = idx / W;
    int y = t % H;
    int c = t / H;
    float r = 0.f;
    if (x >= 1 && x < W - 1 && y >= 1 && y < H - 1) {
        const float* base = hm + (size_t)c * H * W;
        float cv = base[y * W + x];
        if (cv > thresh &&
            cv >= base[(y - 1) * W + x] &&
            cv >= base[(y + 1) * W + x] &&
            cv >= base[y * W + (x - 1)] &&
            cv >= base[y * W + (x + 1)])
            r = 1.f;
    }
    out[idx] = r;
}

static inline int nblk(long n) { return (int)((n + BS - 1) / BS); }

extern "C" void kernel_launch(void* const* d_in, const int* in_sizes, int n_in,
                              void* d_out, int out_size, void* d_ws, size_t ws_size,
                              hipStream_t stream)
{
    const float* x     = (const float*)d_in[0];
    const float* w_d1  = (const float*)d_in[1];  const float* b_d1  = (const float*)d_in[2];
    const float* w_d2  = (const float*)d_in[3];  const float* b_d2  = (const float*)d_in[4];
    const float* w_bn  = (const float*)d_in[5];  const float* b_bn  = (const float*)d_in[6];
    const float* w_u1  = (const float*)d_in[7];  const float* b_u1  = (const float*)d_in[8];
    const float* w_u2  = (const float*)d_in[9];  const float* b_u2  = (const float*)d_in[10];
    const float* w_seg = (const float*)d_in[11]; const float* b_seg = (const float*)d_in[12];
    const float* w_p1  = (const float*)d_in[13]; const float* b_p1  = (const float*)d_in[14];
    const float* w_p2  = (const float*)d_in[15]; const float* b_p2  = (const float*)d_in[16];
    const float* w_hm  = (const float*)d_in[17]; const float* b_hm  = (const float*)d_in[18];
    const float* w_paf = (const float*)d_in[19]; const float* b_paf = (const float*)d_in[20];

    const int N = 8, H = 384, W = 384;
    const int H2 = 192, W2 = 192, H4 = 96, W4 = 96;

    float* ws = (float*)d_ws;
    // Workspace extent = 56,623,104 floats = 216 MiB (R2 lifetime map).
    float* u1  = ws;                   // 8*64*192*192 = 18874368
    float* d1  = ws + 18874368;        // 8*32*384*384 = 37748736
    float* d2  = ws + 18874368;        // 8*64*192*192 = 18874368
    float* bn  = ws + 37748736;        // 8*128*96*96  = 9437184
    float* pd1 = ws;                   // 8*32*192*192 = 9437184
    float* pd2 = ws + 47185920;        // 8*64*96*96   = 4718592
    float* p1  = ws;                   // 8*64*192*192 = 18874368
    float* p2  = ws + 18874368;        // 8*128*96*96  = 9437184

    float* out_seg   = (float*)d_out;                 // 1179648
    float* out_hm    = out_seg + 1179648;             // 1253376
    float* out_paf   = out_hm + 1253376;              // 2359296
    float* out_peaks = out_paf + 2359296;             // 1253376
    // packed weights live in the peaks region (consumed at steps 6/8,
    // overwritten by step 13 afterwards). 16B-aligned offsets.
    _Float16* bp_u1 = (_Float16*)(out_seg + 4792320); // 221184 f16 = 110592 fl
    _Float16* bp_u2 = (_Float16*)(out_seg + 4902912); // 55296 f16  = 27648 fl
    // 4792320 = out_peaks offset; 4902912+27648 = 4930560 <= 6045696 ✓

    // 0. pack weights (fragment-ready f16 hi/lo)
    packw_u1_kernel<<<nblk(13824), BS, 0, stream>>>(w_u1, bp_u1);
    packw_u2_kernel<<<nblk(3456), BS, 0, stream>>>(w_u2, bp_u2);
    // 1. d1 = relu(conv3x3(x; 3->32)) @384
    {
        dim3 g(nblk((long)N * H * (W / 8)), 32 / 8);
        conv3x3_x8_kernel<1, 8><<<g, BS, 0, stream>>>(
            x, 3, nullptr, 0, w_d1, b_d1, d1, N, H, W, 32, 1);
    }
    // 2. pd1 = maxpool(d1) @192
    maxpool2_kernel<<<nblk((long)N * 32 * H2 * (W2 / 4)), BS, 0, stream>>>(d1, pd1, N * 32, H, W);
    // 3. d2 = relu(conv3x3(pd1; 32->64)) @192
    {
        dim3 g(nblk((long)N * H2 * (W2 / 8)), 64 / 8);
        conv3x3_x8_kernel<1, 8><<<g, BS, 0, stream>>>(
            pd1, 32, nullptr, 0, w_d2, b_d2, d2, N, H2, W2, 64, 1);
    }
    // 4. pd2 = maxpool(d2) @96
    maxpool2_kernel<<<nblk((long)N * 64 * H4 * (W4 / 4)), BS, 0, stream>>>(d2, pd2, N * 64, H2, W2);
    // 5. bn = relu(conv3x3(pd2; 64->128)) @96
    {
        dim3 g(nblk((long)N * H4 * (W4 / 8)), 128 / 8);
        conv3x3_x8_kernel<1, 8><<<g, BS, 0, stream>>>(
            pd2, 64, nullptr, 0, w_bn, b_bn, bn, N, H4, W4, 128, 1);
    }
    // 6. u1 = relu(conv3x3(concat(up2(bn), d2); 192->64)) @192  [MFMA f16x3]
    u1_mfma_kernel<<<4608, BS, 0, stream>>>(bn, d2, bp_u1, b_u1, u1);
    // 7. d1' = relu(conv3x3(x; 3->32)) @384  (recompute)
    {
        dim3 g(nblk((long)N * H * (W / 8)), 32 / 8);
        conv3x3_x8_kernel<1, 8><<<g, BS, 0, stream>>>(
            x, 3, nullptr, 0, w_d1, b_d1, d1, N, H, W, 32, 1);
    }
    // 8. seg via fused MFMA u2+seg @384
    u2seg_mfma_kernel<<<18432, BS, 0, stream>>>(
        u1, d1, bp_u2, b_u2, w_seg, b_seg, out_seg);
    // 9. p1 = relu(conv3x3_s2(concat(x, seg); 4->64)) @384->192
    {
        dim3 g(nblk((long)N * H2 * (W2 / 4)), 64 / 8);
        conv3x3_s2_co_kernel<8><<<g, BS, 0, stream>>>(
            x, 3, out_seg, 1, w_p1, b_p1, p1, N, H, W, 64, 1);
    }
    // 10. p2 = relu(conv3x3_s2(p1; 64->128)) @192->96
    {
        dim3 g(nblk((long)N * H4 * (W4 / 4)), 128 / 8);
        conv3x3_s2_co_kernel<8><<<g, BS, 0, stream>>>(
            p1, 64, nullptr, 0, w_p2, b_p2, p2, N, H2, W2, 128, 1);
    }
    // 11. hm = conv1x1(p2; 128->17) @96
    {
        dim3 g(nblk((long)N * (H4 * W4 / 4)), 3);
        conv1x1_co_kernel<8><<<g, BS, 0, stream>>>(
            p2, w_hm, b_hm, out_hm, N, 128, H4 * W4, 17, 0);
    }
    // 12. paf = conv1x1(p2; 128->32) @96
    {
        dim3 g(nblk((long)N * (H4 * W4 / 4)), 4);
        conv1x1_co_kernel<8><<<g, BS, 0, stream>>>(
            p2, w_paf, b_paf, out_paf, N, 128, H4 * W4, 32, 0);
    }
    // 13. peaks @96  (overwrites bp_u1/bp_u2 region - already consumed)
    peaks_kernel<<<nblk((long)N * 17 * H4 * W4), BS, 0, stream>>>(
        out_hm, out_peaks, N * 17, H4, W4, 0.1f);
}

// Round 10
// 1730.811 us; speedup vs baseline: 2.7076x; 1.1653x over previous
//
#include <hip/hip_runtime.h>

// ---------------------------------------------------------------------------
// TeacherModel: small U-Net + pose heads. B=8, H=W=384, fp32 NCHW.
// Round 10: fix MFMA staging bank conflicts. R9: u2seg_mfma 556us had
// SQ_LDS_BANK_CONFLICT=5.4e7 from per-element ds_write_b16 at dword-stride 20
// (8-way). Now: one thread stages 8 consecutive ci -> single ds_write_b128
// per plane (8x fewer LDS insts, 2-way conflicts = free). Same math order.
// ---------------------------------------------------------------------------

#define BS 256

typedef _Float16 half8 __attribute__((ext_vector_type(8)));
typedef float floatx4 __attribute__((ext_vector_type(4)));

#define LDSDW 20   // dwords per x position
#define PLANE 4080 // 3*68*LDSDW dwords per plane

// ===========================================================================
// Weight pre-pack (fragment-ready per-lane blobs), u1: 192 Cin -> 6 chunks.
// layout: [plane(hi/lo)][chunk][tap(9)][ntile][lane(64)][8 f16]
// element: ci = chunk*32 + (lane>>4)*8 + j ; co = ntile*16 + (lane&15)
// ===========================================================================
__global__ __launch_bounds__(BS) void packw_u1_kernel(
    const float* __restrict__ w, _Float16* __restrict__ bp)
{
    int tid = blockIdx.x * BS + threadIdx.x;          // 6*9*4*64 = 13824
    if (tid >= 13824) return;
    int lane = tid & 63;
    int t = tid >> 6;
    int nt = t & 3; t >>= 2;
    int tap = t % 9;
    int chunk = t / 9;
    int q = lane >> 4, n = lane & 15;
    int co = nt * 16 + n;
    _Float16* ph = bp + (size_t)tid * 8;
    _Float16* pl = bp + 110592 + (size_t)tid * 8;     // plane = 6*9*4*64*8
#pragma unroll
    for (int j = 0; j < 8; ++j) {
        int ci = chunk * 32 + q * 8 + j;
        float v = w[((size_t)co * 192 + ci) * 9 + tap];
        _Float16 h = (_Float16)v;
        ph[j] = h;
        pl[j] = (_Float16)(v - (float)h);
    }
}

// u2: [32,96,3,3] -> 3 chunks x 9 taps x 2 ntiles
__global__ __launch_bounds__(BS) void packw_u2_kernel(
    const float* __restrict__ w, _Float16* __restrict__ bp)
{
    int tid = blockIdx.x * BS + threadIdx.x;          // 3*9*2*64 = 3456
    if (tid >= 3456) return;
    int lane = tid & 63;
    int t = tid >> 6;
    int nt = t & 1; t >>= 1;
    int tap = t % 9;
    int chunk = t / 9;
    int q = lane >> 4, n = lane & 15;
    int co = nt * 16 + n;
    _Float16* ph = bp + (size_t)tid * 8;
    _Float16* pl = bp + 27648 + (size_t)tid * 8;      // plane = 3*9*2*64*8
#pragma unroll
    for (int j = 0; j < 8; ++j) {
        int ci = chunk * 32 + q * 8 + j;
        float v = w[((size_t)co * 96 + ci) * 9 + tap];
        _Float16 h = (_Float16)v;
        ph[j] = h;
        pl[j] = (_Float16)(v - (float)h);
    }
}

// ===========================================================================
// u1 = relu(conv3x3(concat(up2(bn), d2))) via MFMA, 64 px/block @192.
// ===========================================================================
__global__ __launch_bounds__(BS) void u1_mfma_kernel(
    const float* __restrict__ bn_,   // [8,128,96,96]
    const float* __restrict__ d2_,   // [8,64,192,192]
    const _Float16* __restrict__ bp, // packed weights
    const float* __restrict__ b_u1,  // [64]
    float* __restrict__ out)         // [8,64,192,192]
{
    __shared__ unsigned int lds[2 * PLANE];
    const int Ho = 192, Wo = 192;
    int pxbase = blockIdx.x * 64;
    int yy = pxbase / Wo;
    int x0 = pxbase % Wo;
    int n = yy / Ho;
    int y = yy % Ho;

    int tid = threadIdx.x;
    int lane = tid & 63, wv = tid >> 6;
    int m = lane & 15, q = lane >> 4;
    int wx = x0 + wv * 16;

    floatx4 acc[4];
#pragma unroll
    for (int nt = 0; nt < 4; ++nt) acc[nt] = (floatx4){0.f, 0.f, 0.f, 0.f};

    const int h0  = (y - 1) >> 1;
    const int hx0 = (x0 - 1) >> 1;

    for (int chunk = 0; chunk < 6; ++chunk) {
        __syncthreads();
        if (chunk < 4) {
            // bn half-res: 2 rows x 34 xi x 4 ci-octets; b128 stores
            for (int e = tid; e < 2 * 34 * 4; e += BS) {
                int xi = e % 34;
                int rest = e / 34;
                int oct = rest & 3;
                int row = rest >> 2;
                int hy = h0 + row, hx = hx0 + xi;
                bool ok = (hy >= 0 && hy < 96 && hx >= 0 && hx < 96);
                const float* gp = bn_ +
                    ((size_t)(n * 128 + chunk * 32 + oct * 8) * 96 + hy) * 96 + hx;
                half8 hv, lv;
#pragma unroll
                for (int j = 0; j < 8; ++j) {
                    float v = ok ? gp[(size_t)j * 96 * 96] : 0.f;
                    _Float16 h = (_Float16)v;
                    hv[j] = h;
                    lv[j] = (_Float16)(v - (float)h);
                }
                int base = (row * 68 + xi) * LDSDW + oct * 4;     // 16B aligned
                *(half8*)((char*)lds + (size_t)base * 4) = hv;
                *(half8*)((char*)lds + ((size_t)PLANE + base) * 4) = lv;
            }
        } else {
            // d2 full-res: 3 rows x 68 xi x 4 ci-octets; b128 stores
            for (int e = tid; e < 3 * 68 * 4; e += BS) {
                int xi = e % 68;
                int rest = e / 68;
                int oct = rest & 3;
                int row = rest >> 2;
                int iy = y - 1 + row, gx = x0 - 1 + xi;
                bool ok = (xi < 67 && iy >= 0 && iy < Ho && gx >= 0 && gx < Wo);
                const float* gp = d2_ +
                    ((size_t)(n * 64 + (chunk - 4) * 32 + oct * 8) * Ho + iy) * Wo + gx;
                half8 hv, lv;
#pragma unroll
                for (int j = 0; j < 8; ++j) {
                    float v = ok ? gp[(size_t)j * Ho * Wo] : 0.f;
                    _Float16 h = (_Float16)v;
                    hv[j] = h;
                    lv[j] = (_Float16)(v - (float)h);
                }
                int base = (row * 68 + xi) * LDSDW + oct * 4;
                *(half8*)((char*)lds + (size_t)base * 4) = hv;
                *(half8*)((char*)lds + ((size_t)PLANE + base) * 4) = lv;
            }
        }
        __syncthreads();
#pragma unroll
        for (int ky = 0; ky < 3; ++ky) {
#pragma unroll
            for (int kx = 0; kx < 3; ++kx) {
                int row, xi;
                if (chunk < 4) {
                    row = ((y + ky - 1) >> 1) - h0;
                    xi  = ((wx + m + kx - 1) >> 1) - hx0;
                } else {
                    row = ky;
                    xi  = (wx - x0) + m + kx;
                }
                int adw = (row * 68 + xi) * LDSDW + q * 4;
                half8 ah = *(const half8*)((const char*)lds + (size_t)adw * 4);
                half8 al = *(const half8*)((const char*)lds + ((size_t)PLANE + adw) * 4);
                int tap = ky * 3 + kx;
                const _Float16* bpp = bp + ((size_t)(chunk * 9 + tap) * 4) * 64 * 8;
#pragma unroll
                for (int nt = 0; nt < 4; ++nt) {
                    half8 bh = *(const half8*)(bpp + ((size_t)nt * 64 + lane) * 8);
                    half8 bl = *(const half8*)(bpp + 110592 + ((size_t)nt * 64 + lane) * 8);
                    acc[nt] = __builtin_amdgcn_mfma_f32_16x16x32_f16(ah, bh, acc[nt], 0, 0, 0);
                    acc[nt] = __builtin_amdgcn_mfma_f32_16x16x32_f16(ah, bl, acc[nt], 0, 0, 0);
                    acc[nt] = __builtin_amdgcn_mfma_f32_16x16x32_f16(al, bh, acc[nt], 0, 0, 0);
                }
            }
        }
    }

    __syncthreads();
#pragma unroll
    for (int nt = 0; nt < 4; ++nt) {
#pragma unroll
        for (int r = 0; r < 4; ++r) {
            int co = nt * 16 + m;
            int pxl = wv * 16 + q * 4 + r;
            ((float*)lds)[co * 64 + pxl] = acc[nt][r];
        }
    }
    __syncthreads();
    {
        int co = tid >> 2, g = tid & 3;
        float bb = b_u1[co];
        const float* lp = (const float*)lds + co * 64 + g * 16;
        float* op = out + ((size_t)(n * 64 + co) * Ho + y) * Wo + x0 + g * 16;
#pragma unroll
        for (int u = 0; u < 16; u += 4) {
            float4 vv = *(const float4*)(lp + u);
            vv.x = fmaxf(vv.x + bb, 0.f);
            vv.y = fmaxf(vv.y + bb, 0.f);
            vv.z = fmaxf(vv.z + bb, 0.f);
            vv.w = fmaxf(vv.w + bb, 0.f);
            *(float4*)(op + u) = vv;
        }
    }
}

// ===========================================================================
// seg = b_seg + sum_co w_seg[co]*relu(conv3x3(concat(up2(u1), d1))[co] + b_u2)
// via MFMA; 64 px/block @384; seg fused in-register (shfl_xor over co lanes).
// ===========================================================================
__global__ __launch_bounds__(BS) void u2seg_mfma_kernel(
    const float* __restrict__ u1_,   // [8,64,192,192]
    const float* __restrict__ d1_,   // [8,32,384,384]
    const _Float16* __restrict__ bp, // packed u2 weights
    const float* __restrict__ b_u2,  // [32]
    const float* __restrict__ w_seg, // [32]
    const float* __restrict__ b_seg, // [1]
    float* __restrict__ seg)         // [8,1,384,384]
{
    __shared__ unsigned int lds[2 * PLANE];
    const int Ho = 384, Wo = 384;
    int pxbase = blockIdx.x * 64;
    int yy = pxbase / Wo;
    int x0 = pxbase % Wo;
    int n = yy / Ho;
    int y = yy % Ho;

    int tid = threadIdx.x;
    int lane = tid & 63, wv = tid >> 6;
    int m = lane & 15, q = lane >> 4;
    int wx = x0 + wv * 16;

    floatx4 acc[2];
    acc[0] = (floatx4){0.f, 0.f, 0.f, 0.f};
    acc[1] = (floatx4){0.f, 0.f, 0.f, 0.f};

    const int h0  = (y - 1) >> 1;
    const int hx0 = (x0 - 1) >> 1;

    for (int chunk = 0; chunk < 3; ++chunk) {
        __syncthreads();
        if (chunk < 2) {
            // u1 half-res: 2 rows x 34 xi x 4 ci-octets; b128 stores
            for (int e = tid; e < 2 * 34 * 4; e += BS) {
                int xi = e % 34;
                int rest = e / 34;
                int oct = rest & 3;
                int row = rest >> 2;
                int hy = h0 + row, hx = hx0 + xi;
                bool ok = (hy >= 0 && hy < 192 && hx >= 0 && hx < 192);
                const float* gp = u1_ +
                    ((size_t)(n * 64 + chunk * 32 + oct * 8) * 192 + hy) * 192 + hx;
                half8 hv, lv;
#pragma unroll
                for (int j = 0; j < 8; ++j) {
                    float v = ok ? gp[(size_t)j * 192 * 192] : 0.f;
                    _Float16 h = (_Float16)v;
                    hv[j] = h;
                    lv[j] = (_Float16)(v - (float)h);
                }
                int base = (row * 68 + xi) * LDSDW + oct * 4;
                *(half8*)((char*)lds + (size_t)base * 4) = hv;
                *(half8*)((char*)lds + ((size_t)PLANE + base) * 4) = lv;
            }
        } else {
            // d1 full-res: 3 rows x 68 xi x 4 ci-octets; b128 stores
            for (int e = tid; e < 3 * 68 * 4; e += BS) {
                int xi = e % 68;
                int rest = e / 68;
                int oct = rest & 3;
                int row = rest >> 2;
                int iy = y - 1 + row, gx = x0 - 1 + xi;
                bool ok = (xi < 67 && iy >= 0 && iy < Ho && gx >= 0 && gx < Wo);
                const float* gp = d1_ +
                    ((size_t)(n * 32 + oct * 8) * Ho + iy) * Wo + gx;
                half8 hv, lv;
#pragma unroll
                for (int j = 0; j < 8; ++j) {
                    float v = ok ? gp[(size_t)j * Ho * Wo] : 0.f;
                    _Float16 h = (_Float16)v;
                    hv[j] = h;
                    lv[j] = (_Float16)(v - (float)h);
                }
                int base = (row * 68 + xi) * LDSDW + oct * 4;
                *(half8*)((char*)lds + (size_t)base * 4) = hv;
                *(half8*)((char*)lds + ((size_t)PLANE + base) * 4) = lv;
            }
        }
        __syncthreads();
#pragma unroll
        for (int ky = 0; ky < 3; ++ky) {
#pragma unroll
            for (int kx = 0; kx < 3; ++kx) {
                int row, xi;
                if (chunk < 2) {
                    row = ((y + ky - 1) >> 1) - h0;
                    xi  = ((wx + m + kx - 1) >> 1) - hx0;
                } else {
                    row = ky;
                    xi  = (wx - x0) + m + kx;
                }
                int adw = (row * 68 + xi) * LDSDW + q * 4;
                half8 ah = *(const half8*)((const char*)lds + (size_t)adw * 4);
                half8 al = *(const half8*)((const char*)lds + ((size_t)PLANE + adw) * 4);
                int tap = ky * 3 + kx;
                const _Float16* bpp = bp + ((size_t)(chunk * 9 + tap) * 2) * 64 * 8;
#pragma unroll
                for (int nt = 0; nt < 2; ++nt) {
                    half8 bh = *(const half8*)(bpp + ((size_t)nt * 64 + lane) * 8);
                    half8 bl = *(const half8*)(bpp + 27648 + ((size_t)nt * 64 + lane) * 8);
                    acc[nt] = __builtin_amdgcn_mfma_f32_16x16x32_f16(ah, bh, acc[nt], 0, 0, 0);
                    acc[nt] = __builtin_amdgcn_mfma_f32_16x16x32_f16(ah, bl, acc[nt], 0, 0, 0);
                    acc[nt] = __builtin_amdgcn_mfma_f32_16x16x32_f16(al, bh, acc[nt], 0, 0, 0);
                }
            }
        }
    }

    // epilogue: lane holds u2-prebias for co=nt*16+m, px=wv*16+q*4+r.
    float bb0 = b_u2[m], bb1 = b_u2[16 + m];
    float ws0 = w_seg[m], ws1 = w_seg[16 + m];
    float bseg = b_seg[0];
    float sr[4];
#pragma unroll
    for (int r = 0; r < 4; ++r) {
        float p = ws0 * fmaxf(acc[0][r] + bb0, 0.f)
                + ws1 * fmaxf(acc[1][r] + bb1, 0.f);
        p += __shfl_xor(p, 1);
        p += __shfl_xor(p, 2);
        p += __shfl_xor(p, 4);
        p += __shfl_xor(p, 8);
        sr[r] = p + bseg;
    }
    if (m == 0) {
        float4 o; o.x = sr[0]; o.y = sr[1]; o.z = sr[2]; o.w = sr[3];
        *(float4*)(seg + ((size_t)n * Ho + y) * Wo + wx + q * 4) = o;
    }
}

// ===========================================================================
// R7/R8 vector kernels, unchanged.
// ===========================================================================

template <int UPA, int TCO>
__global__ __launch_bounds__(BS, 2) void conv3x3_x8_kernel(
    const float* __restrict__ inA, int Ca,
    const float* __restrict__ inB, int Cb,
    const float* __restrict__ w, const float* __restrict__ b,
    float* __restrict__ out,
    int N, int H, int W, int Cout, int do_relu)
{
    const int W8 = W >> 3;
    int idx = blockIdx.x * BS + threadIdx.x;
    int total = N * H * W8;
    if (idx >= total) return;
    int x8 = idx % W8;
    int t  = idx / W8;
    int y  = t % H;
    int n  = t / H;
    int x0 = x8 << 3;
    const int co0 = blockIdx.y * TCO;
    const bool left_ok  = (x0 > 0);
    const bool right_ok = (x0 + 8 < W);
    const int Cin = Ca + Cb;

    float acc[TCO][8];
#pragma unroll
    for (int j = 0; j < TCO; ++j) {
        float bv = b[co0 + j];
#pragma unroll
        for (int p = 0; p < 8; ++p) acc[j][p] = bv;
    }

    for (int ci = 0; ci < Cin; ++ci) {
        float v[3][10];
#pragma unroll
        for (int ky = 0; ky < 3; ++ky) {
            int iy = y + ky - 1;
            if (iy < 0 || iy >= H) {
#pragma unroll
                for (int p = 0; p < 10; ++p) v[ky][p] = 0.f;
                continue;
            }
            if (UPA == 2 && ci < Ca) {
                const float* r = inA + ((size_t)(n * Ca + ci) * (H >> 1) + (iy >> 1)) * (W >> 1);
                int xh = x0 >> 1;
                float sm = left_ok  ? r[xh - 1] : 0.f;
                float4 qq = *(const float4*)(r + xh);
                float s4 = right_ok ? r[xh + 4] : 0.f;
                v[ky][0] = sm;
                v[ky][1] = qq.x; v[ky][2] = qq.x;
                v[ky][3] = qq.y; v[ky][4] = qq.y;
                v[ky][5] = qq.z; v[ky][6] = qq.z;
                v[ky][7] = qq.w; v[ky][8] = qq.w;
                v[ky][9] = s4;
            } else {
                const float* r = (ci < Ca)
                    ? inA + ((size_t)(n * Ca + ci) * H + iy) * W
                    : inB + ((size_t)(n * Cb + (ci - Ca)) * H + iy) * W;
                v[ky][0] = left_ok ? r[x0 - 1] : 0.f;
                float4 q0 = *(const float4*)(r + x0);
                float4 q1 = *(const float4*)(r + x0 + 4);
                v[ky][1] = q0.x; v[ky][2] = q0.y; v[ky][3] = q0.z; v[ky][4] = q0.w;
                v[ky][5] = q1.x; v[ky][6] = q1.y; v[ky][7] = q1.z; v[ky][8] = q1.w;
                v[ky][9] = right_ok ? r[x0 + 8] : 0.f;
            }
        }
#pragma unroll
        for (int j = 0; j < TCO; ++j) {
            const float* wp = w + ((size_t)(co0 + j) * Cin + ci) * 9;
#pragma unroll
            for (int ky = 0; ky < 3; ++ky) {
                float w0 = wp[ky * 3 + 0], w1 = wp[ky * 3 + 1], w2 = wp[ky * 3 + 2];
#pragma unroll
                for (int p = 0; p < 8; ++p)
                    acc[j][p] += w0 * v[ky][p] + w1 * v[ky][p + 1] + w2 * v[ky][p + 2];
            }
        }
    }

#pragma unroll
    for (int j = 0; j < TCO; ++j) {
#pragma unroll
        for (int p = 0; p < 8; ++p)
            if (do_relu) acc[j][p] = fmaxf(acc[j][p], 0.f);
        float* o = out + ((size_t)(n * Cout + co0 + j) * H + y) * W + x0;
        float4 q0; q0.x = acc[j][0]; q0.y = acc[j][1]; q0.z = acc[j][2]; q0.w = acc[j][3];
        float4 q1; q1.x = acc[j][4]; q1.y = acc[j][5]; q1.z = acc[j][6]; q1.w = acc[j][7];
        *(float4*)o = q0;
        *(float4*)(o + 4) = q1;
    }
}

template <int TCO>
__global__ __launch_bounds__(BS) void conv3x3_s2_co_kernel(
    const float* __restrict__ inA, int Ca,
    const float* __restrict__ inB, int Cb,
    const float* __restrict__ w, const float* __restrict__ b,
    float* __restrict__ out,
    int N, int Hi, int Wi, int Cout, int do_relu)
{
    const int Ho = Hi >> 1, Wo = Wi >> 1, Woq = Wo >> 2;
    int idx = blockIdx.x * BS + threadIdx.x;
    int total = N * Ho * Woq;
    if (idx >= total) return;
    int q  = idx % Woq;
    int t  = idx / Woq;
    int oy = t % Ho;
    int n  = t / Ho;
    int ox0 = q << 2;
    int ix0 = ox0 << 1;
    const int co0 = blockIdx.y * TCO;
    const bool right_ok = (ix0 + 8 < Wi);
    const int Cin = Ca + Cb;

    float acc[TCO][4];
#pragma unroll
    for (int j = 0; j < TCO; ++j) {
        float bv = b[co0 + j];
        acc[j][0] = bv; acc[j][1] = bv; acc[j][2] = bv; acc[j][3] = bv;
    }

    for (int ci = 0; ci < Cin; ++ci) {
        const float* base = (ci < Ca)
            ? inA + (size_t)(n * Ca + ci) * Hi * Wi
            : inB + (size_t)(n * Cb + (ci - Ca)) * Hi * Wi;
        float v[3][9];
#pragma unroll
        for (int ky = 0; ky < 3; ++ky) {
            int iy = 2 * oy + ky;
            if (iy >= Hi) {
#pragma unroll
                for (int p = 0; p < 9; ++p) v[ky][p] = 0.f;
                continue;
            }
            const float* r = base + (size_t)iy * Wi + ix0;
            float4 a = *(const float4*)r;
            float4 c = *(const float4*)(r + 4);
            v[ky][0] = a.x; v[ky][1] = a.y; v[ky][2] = a.z; v[ky][3] = a.w;
            v[ky][4] = c.x; v[ky][5] = c.y; v[ky][6] = c.z; v[ky][7] = c.w;
            v[ky][8] = right_ok ? r[8] : 0.f;
        }
#pragma unroll
        for (int j = 0; j < TCO; ++j) {
            const float* wp = w + ((size_t)(co0 + j) * Cin + ci) * 9;
#pragma unroll
            for (int ky = 0; ky < 3; ++ky) {
                float w0 = wp[ky * 3 + 0], w1 = wp[ky * 3 + 1], w2 = wp[ky * 3 + 2];
#pragma unroll
                for (int p = 0; p < 4; ++p)
                    acc[j][p] += w0 * v[ky][2 * p] + w1 * v[ky][2 * p + 1] + w2 * v[ky][2 * p + 2];
            }
        }
    }

#pragma unroll
    for (int j = 0; j < TCO; ++j) {
        float4 o;
        o.x = acc[j][0]; o.y = acc[j][1]; o.z = acc[j][2]; o.w = acc[j][3];
        if (do_relu) {
            o.x = fmaxf(o.x, 0.f); o.y = fmaxf(o.y, 0.f);
            o.z = fmaxf(o.z, 0.f); o.w = fmaxf(o.w, 0.f);
        }
        *(float4*)(out + ((size_t)(n * Cout + co0 + j) * Ho + oy) * Wo + ox0) = o;
    }
}

__global__ __launch_bounds__(BS) void maxpool2_kernel(
    const float* __restrict__ in, float* __restrict__ out, int NC, int H, int W)
{
    int Ho = H >> 1, Wo = W >> 1, Woq = Wo >> 2;
    int idx = blockIdx.x * BS + threadIdx.x;
    int total = NC * Ho * Woq;
    if (idx >= total) return;
    int x4 = idx % Woq;
    int t  = idx / Woq;
    int y  = t % Ho;
    int c  = t / Ho;
    const float* r0 = in + ((size_t)c * H + 2 * y) * W + 8 * x4;
    const float* r1 = r0 + W;
    float4 a0 = *(const float4*)r0;
    float4 a1 = *(const float4*)(r0 + 4);
    float4 b0 = *(const float4*)r1;
    float4 b1 = *(const float4*)(r1 + 4);
    float4 o;
    o.x = fmaxf(fmaxf(a0.x, a0.y), fmaxf(b0.x, b0.y));
    o.y = fmaxf(fmaxf(a0.z, a0.w), fmaxf(b0.z, b0.w));
    o.z = fmaxf(fmaxf(a1.x, a1.y), fmaxf(b1.x, b1.y));
    o.w = fmaxf(fmaxf(a1.z, a1.w), fmaxf(b1.z, b1.w));
    *(float4*)(out + ((size_t)c * Ho + y) * Wo + 4 * x4) = o;
}

template <int TCO>
__global__ __launch_bounds__(BS) void conv1x1_co_kernel(
    const float* __restrict__ in, const float* __restrict__ w,
    const float* __restrict__ b, float* __restrict__ out,
    int N, int Cin, int HW, int Cout, int do_relu)
{
    int HWq = HW >> 2;
    int idx = blockIdx.x * BS + threadIdx.x;
    int total = N * HWq;
    if (idx >= total) return;
    int q = idx % HWq;
    int n = idx / HWq;
    const int co0 = blockIdx.y * TCO;

    float acc[TCO][4];
#pragma unroll
    for (int j = 0; j < TCO; ++j) {
        int co = min(co0 + j, Cout - 1);
        float bv = b[co];
        acc[j][0] = bv; acc[j][1] = bv; acc[j][2] = bv; acc[j][3] = bv;
    }
    const float* base = in + (size_t)n * Cin * HW + 4 * q;
    for (int ci = 0; ci < Cin; ++ci) {
        float4 v = *(const float4*)(base + (size_t)ci * HW);
#pragma unroll
        for (int j = 0; j < TCO; ++j) {
            int co = min(co0 + j, Cout - 1);
            float wv = w[(size_t)co * Cin + ci];
            acc[j][0] += wv * v.x; acc[j][1] += wv * v.y;
            acc[j][2] += wv * v.z; acc[j][3] += wv * v.w;
        }
    }
#pragma unroll
    for (int j = 0; j < TCO; ++j) {
        if (co0 + j >= Cout) break;
        float4 o;
        o.x = acc[j][0]; o.y = acc[j][1]; o.z = acc[j][2]; o.w = acc[j][3];
        if (do_relu) {
            o.x = fmaxf(o.x, 0.f); o.y = fmaxf(o.y, 0.f);
            o.z = fmaxf(o.z, 0.f); o.w = fmaxf(o.w, 0.f);
        }
        *(float4*)(out + ((size_t)(n * Cout + co0 + j)) * HW + 4 * q) = o;
    }
}

__global__ __launch_bounds__(BS) void peaks_kernel(
    const float* __restrict__ hm, float* __restrict__ out,
    int NC, int H, int W, float thresh)
{
    int idx = blockIdx.x * BS + threadIdx.x;
    int total = NC * H * W;
    if (idx >= total) return;
    int x = idx % W;
    int t = idx / W;
    int y = t % H;
    int c = t / H;
    float r = 0.f;
    if (x >= 1 && x < W - 1 && y >= 1 && y < H - 1) {
        const float* base = hm + (size_t)c * H * W;
        float cv = base[y * W + x];
        if (cv > thresh &&
            cv >= base[(y - 1) * W + x] &&
            cv >= base[(y + 1) * W + x] &&
            cv >= base[y * W + (x - 1)] &&
            cv >= base[y * W + (x + 1)])
            r = 1.f;
    }
    out[idx] = r;
}

static inline int nblk(long n) { return (int)((n + BS - 1) / BS); }

extern "C" void kernel_launch(void* const* d_in, const int* in_sizes, int n_in,
                              void* d_out, int out_size, void* d_ws, size_t ws_size,
                              hipStream_t stream)
{
    const float* x     = (const float*)d_in[0];
    const float* w_d1  = (const float*)d_in[1];  const float* b_d1  = (const float*)d_in[2];
    const float* w_d2  = (const float*)d_in[3];  const float* b_d2  = (const float*)d_in[4];
    const float* w_bn  = (const float*)d_in[5];  const float* b_bn  = (const float*)d_in[6];
    const float* w_u1  = (const float*)d_in[7];  const float* b_u1  = (const float*)d_in[8];
    const float* w_u2  = (const float*)d_in[9];  const float* b_u2  = (const float*)d_in[10];
    const float* w_seg = (const float*)d_in[11]; const float* b_seg = (const float*)d_in[12];
    const float* w_p1  = (const float*)d_in[13]; const float* b_p1  = (const float*)d_in[14];
    const float* w_p2  = (const float*)d_in[15]; const float* b_p2  = (const float*)d_in[16];
    const float* w_hm  = (const float*)d_in[17]; const float* b_hm  = (const float*)d_in[18];
    const float* w_paf = (const float*)d_in[19]; const float* b_paf = (const float*)d_in[20];

    const int N = 8, H = 384, W = 384;
    const int H2 = 192, W2 = 192, H4 = 96, W4 = 96;

    float* ws = (float*)d_ws;
    // Workspace extent = 56,623,104 floats = 216 MiB (R2 lifetime map).
    float* u1  = ws;                   // 8*64*192*192 = 18874368
    float* d1  = ws + 18874368;        // 8*32*384*384 = 37748736
    float* d2  = ws + 18874368;        // 8*64*192*192 = 18874368
    float* bn  = ws + 37748736;        // 8*128*96*96  = 9437184
    float* pd1 = ws;                   // 8*32*192*192 = 9437184
    float* pd2 = ws + 47185920;        // 8*64*96*96   = 4718592
    float* p1  = ws;                   // 8*64*192*192 = 18874368
    float* p2  = ws + 18874368;        // 8*128*96*96  = 9437184

    float* out_seg   = (float*)d_out;                 // 1179648
    float* out_hm    = out_seg + 1179648;             // 1253376
    float* out_paf   = out_hm + 1253376;              // 2359296
    float* out_peaks = out_paf + 2359296;             // 1253376
    _Float16* bp_u1 = (_Float16*)(out_seg + 4792320); // in peaks region
    _Float16* bp_u2 = (_Float16*)(out_seg + 4902912);

    // 0. pack weights (fragment-ready f16 hi/lo)
    packw_u1_kernel<<<nblk(13824), BS, 0, stream>>>(w_u1, bp_u1);
    packw_u2_kernel<<<nblk(3456), BS, 0, stream>>>(w_u2, bp_u2);
    // 1. d1 = relu(conv3x3(x; 3->32)) @384
    {
        dim3 g(nblk((long)N * H * (W / 8)), 32 / 8);
        conv3x3_x8_kernel<1, 8><<<g, BS, 0, stream>>>(
            x, 3, nullptr, 0, w_d1, b_d1, d1, N, H, W, 32, 1);
    }
    // 2. pd1 = maxpool(d1) @192
    maxpool2_kernel<<<nblk((long)N * 32 * H2 * (W2 / 4)), BS, 0, stream>>>(d1, pd1, N * 32, H, W);
    // 3. d2 = relu(conv3x3(pd1; 32->64)) @192
    {
        dim3 g(nblk((long)N * H2 * (W2 / 8)), 64 / 8);
        conv3x3_x8_kernel<1, 8><<<g, BS, 0, stream>>>(
            pd1, 32, nullptr, 0, w_d2, b_d2, d2, N, H2, W2, 64, 1);
    }
    // 4. pd2 = maxpool(d2) @96
    maxpool2_kernel<<<nblk((long)N * 64 * H4 * (W4 / 4)), BS, 0, stream>>>(d2, pd2, N * 64, H2, W2);
    // 5. bn = relu(conv3x3(pd2; 64->128)) @96
    {
        dim3 g(nblk((long)N * H4 * (W4 / 8)), 128 / 8);
        conv3x3_x8_kernel<1, 8><<<g, BS, 0, stream>>>(
            pd2, 64, nullptr, 0, w_bn, b_bn, bn, N, H4, W4, 128, 1);
    }
    // 6. u1 = relu(conv3x3(concat(up2(bn), d2); 192->64)) @192  [MFMA f16x3]
    u1_mfma_kernel<<<4608, BS, 0, stream>>>(bn, d2, bp_u1, b_u1, u1);
    // 7. d1' = relu(conv3x3(x; 3->32)) @384  (recompute)
    {
        dim3 g(nblk((long)N * H * (W / 8)), 32 / 8);
        conv3x3_x8_kernel<1, 8><<<g, BS, 0, stream>>>(
            x, 3, nullptr, 0, w_d1, b_d1, d1, N, H, W, 32, 1);
    }
    // 8. seg via fused MFMA u2+seg @384
    u2seg_mfma_kernel<<<18432, BS, 0, stream>>>(
        u1, d1, bp_u2, b_u2, w_seg, b_seg, out_seg);
    // 9. p1 = relu(conv3x3_s2(concat(x, seg); 4->64)) @384->192
    {
        dim3 g(nblk((long)N * H2 * (W2 / 4)), 64 / 8);
        conv3x3_s2_co_kernel<8><<<g, BS, 0, stream>>>(
            x, 3, out_seg, 1, w_p1, b_p1, p1, N, H, W, 64, 1);
    }
    // 10. p2 = relu(conv3x3_s2(p1; 64->128)) @192->96
    {
        dim3 g(nblk((long)N * H4 * (W4 / 4)), 128 / 8);
        conv3x3_s2_co_kernel<8><<<g, BS, 0, stream>>>(
            p1, 64, nullptr, 0, w_p2, b_p2, p2, N, H2, W2, 128, 1);
    }
    // 11. hm = conv1x1(p2; 128->17) @96
    {
        dim3 g(nblk((long)N * (H4 * W4 / 4)), 3);
        conv1x1_co_kernel<8><<<g, BS, 0, stream>>>(
            p2, w_hm, b_hm, out_hm, N, 128, H4 * W4, 17, 0);
    }
    // 12. paf = conv1x1(p2; 128->32) @96
    {
        dim3 g(nblk((long)N * (H4 * W4 / 4)), 4);
        conv1x1_co_kernel<8><<<g, BS, 0, stream>>>(
            p2, w_paf, b_paf, out_paf, N, 128, H4 * W4, 32, 0);
    }
    // 13. peaks @96  (overwrites bp_u1/bp_u2 region - already consumed)
    peaks_kernel<<<nblk((long)N * 17 * H4 * W4), BS, 0, stream>>>(
        out_hm, out_peaks, N * 17, H4, W4, 0.1f);
}

// Round 11
// 1434.510 us; speedup vs baseline: 3.2669x; 1.2066x over previous
//
#include <hip/hip_runtime.h>

// ---------------------------------------------------------------------------
// TeacherModel: small U-Net + pose heads. B=8, H=W=384, fp32 NCHW.
// Round 11: generic stride-1 MFMA conv (f16 hi/lo 3-term split, octet-b128
// staging from R10) for d2 (32->64 @192) and bn (64->128 @96). Block = 2 rows
// x 32 px. R10: these two were ~220us each on the 50 TF vector path; MFMA
// math is ~16us each -> land staging/memory-bound ~100us. u1/u2seg engines
// unchanged (382us u2seg, validated absmax 0.0078125 across 3 rounds).
// ---------------------------------------------------------------------------

#define BS 256

typedef _Float16 half8 __attribute__((ext_vector_type(8)));
typedef float floatx4 __attribute__((ext_vector_type(4)));

#define LDSDW 20   // dwords per x position
#define PLANE 4080 // 3*68*LDSDW dwords per plane (u1/u2seg layout)

// ===========================================================================
// Generic weight pre-pack: layout [plane(hi/lo)][chunk][tap(9)][nt][lane][8]
// element: ci = chunk*32 + (lane>>4)*8 + j ; co = nt*16 + (lane&15)
// (bit-identical to the R8-R10 bespoke packs)
// ===========================================================================
__global__ __launch_bounds__(BS) void packw_gen_kernel(
    const float* __restrict__ w, _Float16* __restrict__ bp, int Cin, int Cout)
{
    int total = (Cin >> 5) * 9 * (Cout >> 4) * 64;
    int tid = blockIdx.x * BS + threadIdx.x;
    if (tid >= total) return;
    int lane = tid & 63;
    int t = tid >> 6;
    int NTl = Cout >> 4;
    int nt = t % NTl; t /= NTl;
    int tap = t % 9;
    int chunk = t / 9;
    int q = lane >> 4, n = lane & 15;
    int co = nt * 16 + n;
    _Float16* ph = bp + (size_t)tid * 8;
    _Float16* pl = bp + (size_t)total * 8 + (size_t)tid * 8;
#pragma unroll
    for (int j = 0; j < 8; ++j) {
        int ci = chunk * 32 + q * 8 + j;
        float v = w[((size_t)co * Cin + ci) * 9 + tap];
        _Float16 h = (_Float16)v;
        ph[j] = h;
        pl[j] = (_Float16)(v - (float)h);
    }
}

// ===========================================================================
// Generic stride-1 3x3 SAME conv via MFMA: out = relu(conv(in)).
// Block = 2 output rows x 32 px. Stage 4 input rows x 34 xi per 32-ci chunk.
// ===========================================================================
template <int CHUNKS, int NT, int HH, int WW>
__global__ __launch_bounds__(BS) void conv3x3_mfma_kernel(
    const float* __restrict__ in_,   // [8, CHUNKS*32, HH, WW]
    const _Float16* __restrict__ bp, // packed weights
    const float* __restrict__ bias,  // [NT*16]
    float* __restrict__ out)         // [8, NT*16, HH, WW]
{
    constexpr int PL = 4 * 34 * LDSDW;                // 2720 dw per plane
    constexpr int EPI = 64 * NT * 16;                 // epilogue dw
    constexpr int LDS_DW = (2 * PL > EPI) ? 2 * PL : EPI;
    __shared__ unsigned int lds[LDS_DW];

    int xblks = WW / 32;
    int b = blockIdx.x;
    int xb = b % xblks; b /= xblks;
    int yp = b % (HH / 2);
    int n  = b / (HH / 2);
    int y0 = yp * 2;
    int x0 = xb * 32;

    int tid = threadIdx.x;
    int lane = tid & 63, wv = tid >> 6;
    int m = lane & 15, q = lane >> 4;
    int lrow = wv >> 1;              // output row within block (0/1)
    int lx   = (wv & 1) * 16;        // x offset within 32

    floatx4 acc[NT];
#pragma unroll
    for (int nt = 0; nt < NT; ++nt) acc[nt] = (floatx4){0.f, 0.f, 0.f, 0.f};

    const int planeW = CHUNKS * 9 * NT * 64 * 8;      // f16 per plane

    for (int chunk = 0; chunk < CHUNKS; ++chunk) {
        __syncthreads();
        // stage: 4 rows x 34 xi x 4 ci-octets, b128 stores
        for (int e = tid; e < 4 * 34 * 4; e += BS) {
            int xi = e % 34;
            int rest = e / 34;
            int oct = rest & 3;
            int row = rest >> 2;                      // 0..3
            int iy = y0 - 1 + row, gx = x0 - 1 + xi;
            bool ok = (iy >= 0 && iy < HH && gx >= 0 && gx < WW);
            const float* gp = in_ +
                ((size_t)(n * (CHUNKS * 32) + chunk * 32 + oct * 8) * HH + iy) * WW + gx;
            half8 hv, lv;
#pragma unroll
            for (int j = 0; j < 8; ++j) {
                float v = ok ? gp[(size_t)j * HH * WW] : 0.f;
                _Float16 h = (_Float16)v;
                hv[j] = h;
                lv[j] = (_Float16)(v - (float)h);
            }
            int base = (row * 34 + xi) * LDSDW + oct * 4;   // 16B aligned
            *(half8*)((char*)lds + (size_t)base * 4) = hv;
            *(half8*)((char*)lds + ((size_t)PL + base) * 4) = lv;
        }
        __syncthreads();
#pragma unroll
        for (int ky = 0; ky < 3; ++ky) {
#pragma unroll
            for (int kx = 0; kx < 3; ++kx) {
                int row = lrow + ky;                  // 0..3
                int xi  = lx + m + kx;                // 0..33
                int adw = (row * 34 + xi) * LDSDW + q * 4;
                half8 ah = *(const half8*)((const char*)lds + (size_t)adw * 4);
                half8 al = *(const half8*)((const char*)lds + ((size_t)PL + adw) * 4);
                int tap = ky * 3 + kx;
                const _Float16* bpp = bp + ((size_t)(chunk * 9 + tap) * NT) * 64 * 8;
#pragma unroll
                for (int nt = 0; nt < NT; ++nt) {
                    half8 bh = *(const half8*)(bpp + ((size_t)nt * 64 + lane) * 8);
                    half8 bl = *(const half8*)(bpp + planeW + ((size_t)nt * 64 + lane) * 8);
                    acc[nt] = __builtin_amdgcn_mfma_f32_16x16x32_f16(ah, bh, acc[nt], 0, 0, 0);
                    acc[nt] = __builtin_amdgcn_mfma_f32_16x16x32_f16(ah, bl, acc[nt], 0, 0, 0);
                    acc[nt] = __builtin_amdgcn_mfma_f32_16x16x32_f16(al, bh, acc[nt], 0, 0, 0);
                }
            }
        }
    }

    // epilogue: LDS transpose, bias+relu, coalesced stores
    __syncthreads();
#pragma unroll
    for (int nt = 0; nt < NT; ++nt) {
#pragma unroll
        for (int r = 0; r < 4; ++r) {
            int co = nt * 16 + m;
            int pxl = wv * 16 + q * 4 + r;            // px within block
            ((float*)lds)[co * 64 + pxl] = acc[nt][r];
        }
    }
    __syncthreads();
    {
        constexpr int thPerCo = 256 / (NT * 16);      // NT=4 -> 4, NT=8 -> 2
        constexpr int pxPerTh = 64 / thPerCo;         // 16 or 32
        int co = tid / thPerCo;
        int sub = tid % thPerCo;
        int pxb = sub * pxPerTh;
        float bb = bias[co];
#pragma unroll
        for (int u = 0; u < pxPerTh; u += 4) {
            int p = pxb + u;
            int row = y0 + (p >> 5), xx = x0 + (p & 31);
            const float* lp = (const float*)lds + co * 64 + p;
            float4 vv = *(const float4*)lp;
            vv.x = fmaxf(vv.x + bb, 0.f);
            vv.y = fmaxf(vv.y + bb, 0.f);
            vv.z = fmaxf(vv.z + bb, 0.f);
            vv.w = fmaxf(vv.w + bb, 0.f);
            *(float4*)(out + ((size_t)(n * NT * 16 + co) * HH + row) * WW + xx) = vv;
        }
    }
}

// ===========================================================================
// u1 = relu(conv3x3(concat(up2(bn), d2))) via MFMA, 64 px/block @192. (R10)
// ===========================================================================
__global__ __launch_bounds__(BS) void u1_mfma_kernel(
    const float* __restrict__ bn_,   // [8,128,96,96]
    const float* __restrict__ d2_,   // [8,64,192,192]
    const _Float16* __restrict__ bp, // packed weights
    const float* __restrict__ b_u1,  // [64]
    float* __restrict__ out)         // [8,64,192,192]
{
    __shared__ unsigned int lds[2 * PLANE];
    const int Ho = 192, Wo = 192;
    int pxbase = blockIdx.x * 64;
    int yy = pxbase / Wo;
    int x0 = pxbase % Wo;
    int n = yy / Ho;
    int y = yy % Ho;

    int tid = threadIdx.x;
    int lane = tid & 63, wv = tid >> 6;
    int m = lane & 15, q = lane >> 4;
    int wx = x0 + wv * 16;

    floatx4 acc[4];
#pragma unroll
    for (int nt = 0; nt < 4; ++nt) acc[nt] = (floatx4){0.f, 0.f, 0.f, 0.f};

    const int h0  = (y - 1) >> 1;
    const int hx0 = (x0 - 1) >> 1;

    for (int chunk = 0; chunk < 6; ++chunk) {
        __syncthreads();
        if (chunk < 4) {
            for (int e = tid; e < 2 * 34 * 4; e += BS) {
                int xi = e % 34;
                int rest = e / 34;
                int oct = rest & 3;
                int row = rest >> 2;
                int hy = h0 + row, hx = hx0 + xi;
                bool ok = (hy >= 0 && hy < 96 && hx >= 0 && hx < 96);
                const float* gp = bn_ +
                    ((size_t)(n * 128 + chunk * 32 + oct * 8) * 96 + hy) * 96 + hx;
                half8 hv, lv;
#pragma unroll
                for (int j = 0; j < 8; ++j) {
                    float v = ok ? gp[(size_t)j * 96 * 96] : 0.f;
                    _Float16 h = (_Float16)v;
                    hv[j] = h;
                    lv[j] = (_Float16)(v - (float)h);
                }
                int base = (row * 68 + xi) * LDSDW + oct * 4;
                *(half8*)((char*)lds + (size_t)base * 4) = hv;
                *(half8*)((char*)lds + ((size_t)PLANE + base) * 4) = lv;
            }
        } else {
            for (int e = tid; e < 3 * 68 * 4; e += BS) {
                int xi = e % 68;
                int rest = e / 68;
                int oct = rest & 3;
                int row = rest >> 2;
                int iy = y - 1 + row, gx = x0 - 1 + xi;
                bool ok = (xi < 67 && iy >= 0 && iy < Ho && gx >= 0 && gx < Wo);
                const float* gp = d2_ +
                    ((size_t)(n * 64 + (chunk - 4) * 32 + oct * 8) * Ho + iy) * Wo + gx;
                half8 hv, lv;
#pragma unroll
                for (int j = 0; j < 8; ++j) {
                    float v = ok ? gp[(size_t)j * Ho * Wo] : 0.f;
                    _Float16 h = (_Float16)v;
                    hv[j] = h;
                    lv[j] = (_Float16)(v - (float)h);
                }
                int base = (row * 68 + xi) * LDSDW + oct * 4;
                *(half8*)((char*)lds + (size_t)base * 4) = hv;
                *(half8*)((char*)lds + ((size_t)PLANE + base) * 4) = lv;
            }
        }
        __syncthreads();
#pragma unroll
        for (int ky = 0; ky < 3; ++ky) {
#pragma unroll
            for (int kx = 0; kx < 3; ++kx) {
                int row, xi;
                if (chunk < 4) {
                    row = ((y + ky - 1) >> 1) - h0;
                    xi  = ((wx + m + kx - 1) >> 1) - hx0;
                } else {
                    row = ky;
                    xi  = (wx - x0) + m + kx;
                }
                int adw = (row * 68 + xi) * LDSDW + q * 4;
                half8 ah = *(const half8*)((const char*)lds + (size_t)adw * 4);
                half8 al = *(const half8*)((const char*)lds + ((size_t)PLANE + adw) * 4);
                int tap = ky * 3 + kx;
                const _Float16* bpp = bp + ((size_t)(chunk * 9 + tap) * 4) * 64 * 8;
#pragma unroll
                for (int nt = 0; nt < 4; ++nt) {
                    half8 bh = *(const half8*)(bpp + ((size_t)nt * 64 + lane) * 8);
                    half8 bl = *(const half8*)(bpp + 110592 + ((size_t)nt * 64 + lane) * 8);
                    acc[nt] = __builtin_amdgcn_mfma_f32_16x16x32_f16(ah, bh, acc[nt], 0, 0, 0);
                    acc[nt] = __builtin_amdgcn_mfma_f32_16x16x32_f16(ah, bl, acc[nt], 0, 0, 0);
                    acc[nt] = __builtin_amdgcn_mfma_f32_16x16x32_f16(al, bh, acc[nt], 0, 0, 0);
                }
            }
        }
    }

    __syncthreads();
#pragma unroll
    for (int nt = 0; nt < 4; ++nt) {
#pragma unroll
        for (int r = 0; r < 4; ++r) {
            int co = nt * 16 + m;
            int pxl = wv * 16 + q * 4 + r;
            ((float*)lds)[co * 64 + pxl] = acc[nt][r];
        }
    }
    __syncthreads();
    {
        int co = tid >> 2, g = tid & 3;
        float bb = b_u1[co];
        const float* lp = (const float*)lds + co * 64 + g * 16;
        float* op = out + ((size_t)(n * 64 + co) * Ho + y) * Wo + x0 + g * 16;
#pragma unroll
        for (int u = 0; u < 16; u += 4) {
            float4 vv = *(const float4*)(lp + u);
            vv.x = fmaxf(vv.x + bb, 0.f);
            vv.y = fmaxf(vv.y + bb, 0.f);
            vv.z = fmaxf(vv.z + bb, 0.f);
            vv.w = fmaxf(vv.w + bb, 0.f);
            *(float4*)(op + u) = vv;
        }
    }
}

// ===========================================================================
// seg via fused MFMA u2+seg (R10, shfl_xor co-reduce).
// ===========================================================================
__global__ __launch_bounds__(BS) void u2seg_mfma_kernel(
    const float* __restrict__ u1_,   // [8,64,192,192]
    const float* __restrict__ d1_,   // [8,32,384,384]
    const _Float16* __restrict__ bp, // packed u2 weights
    const float* __restrict__ b_u2,  // [32]
    const float* __restrict__ w_seg, // [32]
    const float* __restrict__ b_seg, // [1]
    float* __restrict__ seg)         // [8,1,384,384]
{
    __shared__ unsigned int lds[2 * PLANE];
    const int Ho = 384, Wo = 384;
    int pxbase = blockIdx.x * 64;
    int yy = pxbase / Wo;
    int x0 = pxbase % Wo;
    int n = yy / Ho;
    int y = yy % Ho;

    int tid = threadIdx.x;
    int lane = tid & 63, wv = tid >> 6;
    int m = lane & 15, q = lane >> 4;
    int wx = x0 + wv * 16;

    floatx4 acc[2];
    acc[0] = (floatx4){0.f, 0.f, 0.f, 0.f};
    acc[1] = (floatx4){0.f, 0.f, 0.f, 0.f};

    const int h0  = (y - 1) >> 1;
    const int hx0 = (x0 - 1) >> 1;

    for (int chunk = 0; chunk < 3; ++chunk) {
        __syncthreads();
        if (chunk < 2) {
            for (int e = tid; e < 2 * 34 * 4; e += BS) {
                int xi = e % 34;
                int rest = e / 34;
                int oct = rest & 3;
                int row = rest >> 2;
                int hy = h0 + row, hx = hx0 + xi;
                bool ok = (hy >= 0 && hy < 192 && hx >= 0 && hx < 192);
                const float* gp = u1_ +
                    ((size_t)(n * 64 + chunk * 32 + oct * 8) * 192 + hy) * 192 + hx;
                half8 hv, lv;
#pragma unroll
                for (int j = 0; j < 8; ++j) {
                    float v = ok ? gp[(size_t)j * 192 * 192] : 0.f;
                    _Float16 h = (_Float16)v;
                    hv[j] = h;
                    lv[j] = (_Float16)(v - (float)h);
                }
                int base = (row * 68 + xi) * LDSDW + oct * 4;
                *(half8*)((char*)lds + (size_t)base * 4) = hv;
                *(half8*)((char*)lds + ((size_t)PLANE + base) * 4) = lv;
            }
        } else {
            for (int e = tid; e < 3 * 68 * 4; e += BS) {
                int xi = e % 68;
                int rest = e / 68;
                int oct = rest & 3;
                int row = rest >> 2;
                int iy = y - 1 + row, gx = x0 - 1 + xi;
                bool ok = (xi < 67 && iy >= 0 && iy < Ho && gx >= 0 && gx < Wo);
                const float* gp = d1_ +
                    ((size_t)(n * 32 + oct * 8) * Ho + iy) * Wo + gx;
                half8 hv, lv;
#pragma unroll
                for (int j = 0; j < 8; ++j) {
                    float v = ok ? gp[(size_t)j * Ho * Wo] : 0.f;
                    _Float16 h = (_Float16)v;
                    hv[j] = h;
                    lv[j] = (_Float16)(v - (float)h);
                }
                int base = (row * 68 + xi) * LDSDW + oct * 4;
                *(half8*)((char*)lds + (size_t)base * 4) = hv;
                *(half8*)((char*)lds + ((size_t)PLANE + base) * 4) = lv;
            }
        }
        __syncthreads();
#pragma unroll
        for (int ky = 0; ky < 3; ++ky) {
#pragma unroll
            for (int kx = 0; kx < 3; ++kx) {
                int row, xi;
                if (chunk < 2) {
                    row = ((y + ky - 1) >> 1) - h0;
                    xi  = ((wx + m + kx - 1) >> 1) - hx0;
                } else {
                    row = ky;
                    xi  = (wx - x0) + m + kx;
                }
                int adw = (row * 68 + xi) * LDSDW + q * 4;
                half8 ah = *(const half8*)((const char*)lds + (size_t)adw * 4);
                half8 al = *(const half8*)((const char*)lds + ((size_t)PLANE + adw) * 4);
                int tap = ky * 3 + kx;
                const _Float16* bpp = bp + ((size_t)(chunk * 9 + tap) * 2) * 64 * 8;
#pragma unroll
                for (int nt = 0; nt < 2; ++nt) {
                    half8 bh = *(const half8*)(bpp + ((size_t)nt * 64 + lane) * 8);
                    half8 bl = *(const half8*)(bpp + 27648 + ((size_t)nt * 64 + lane) * 8);
                    acc[nt] = __builtin_amdgcn_mfma_f32_16x16x32_f16(ah, bh, acc[nt], 0, 0, 0);
                    acc[nt] = __builtin_amdgcn_mfma_f32_16x16x32_f16(ah, bl, acc[nt], 0, 0, 0);
                    acc[nt] = __builtin_amdgcn_mfma_f32_16x16x32_f16(al, bh, acc[nt], 0, 0, 0);
                }
            }
        }
    }

    float bb0 = b_u2[m], bb1 = b_u2[16 + m];
    float ws0 = w_seg[m], ws1 = w_seg[16 + m];
    float bseg = b_seg[0];
    float sr[4];
#pragma unroll
    for (int r = 0; r < 4; ++r) {
        float p = ws0 * fmaxf(acc[0][r] + bb0, 0.f)
                + ws1 * fmaxf(acc[1][r] + bb1, 0.f);
        p += __shfl_xor(p, 1);
        p += __shfl_xor(p, 2);
        p += __shfl_xor(p, 4);
        p += __shfl_xor(p, 8);
        sr[r] = p + bseg;
    }
    if (m == 0) {
        float4 o; o.x = sr[0]; o.y = sr[1]; o.z = sr[2]; o.w = sr[3];
        *(float4*)(seg + ((size_t)n * Ho + y) * Wo + wx + q * 4) = o;
    }
}

// ===========================================================================
// Vector kernels (R7-R10), unchanged.
// ===========================================================================

template <int UPA, int TCO>
__global__ __launch_bounds__(BS, 2) void conv3x3_x8_kernel(
    const float* __restrict__ inA, int Ca,
    const float* __restrict__ inB, int Cb,
    const float* __restrict__ w, const float* __restrict__ b,
    float* __restrict__ out,
    int N, int H, int W, int Cout, int do_relu)
{
    const int W8 = W >> 3;
    int idx = blockIdx.x * BS + threadIdx.x;
    int total = N * H * W8;
    if (idx >= total) return;
    int x8 = idx % W8;
    int t  = idx / W8;
    int y  = t % H;
    int n  = t / H;
    int x0 = x8 << 3;
    const int co0 = blockIdx.y * TCO;
    const bool left_ok  = (x0 > 0);
    const bool right_ok = (x0 + 8 < W);
    const int Cin = Ca + Cb;

    float acc[TCO][8];
#pragma unroll
    for (int j = 0; j < TCO; ++j) {
        float bv = b[co0 + j];
#pragma unroll
        for (int p = 0; p < 8; ++p) acc[j][p] = bv;
    }

    for (int ci = 0; ci < Cin; ++ci) {
        float v[3][10];
#pragma unroll
        for (int ky = 0; ky < 3; ++ky) {
            int iy = y + ky - 1;
            if (iy < 0 || iy >= H) {
#pragma unroll
                for (int p = 0; p < 10; ++p) v[ky][p] = 0.f;
                continue;
            }
            if (UPA == 2 && ci < Ca) {
                const float* r = inA + ((size_t)(n * Ca + ci) * (H >> 1) + (iy >> 1)) * (W >> 1);
                int xh = x0 >> 1;
                float sm = left_ok  ? r[xh - 1] : 0.f;
                float4 qq = *(const float4*)(r + xh);
                float s4 = right_ok ? r[xh + 4] : 0.f;
                v[ky][0] = sm;
                v[ky][1] = qq.x; v[ky][2] = qq.x;
                v[ky][3] = qq.y; v[ky][4] = qq.y;
                v[ky][5] = qq.z; v[ky][6] = qq.z;
                v[ky][7] = qq.w; v[ky][8] = qq.w;
                v[ky][9] = s4;
            } else {
                const float* r = (ci < Ca)
                    ? inA + ((size_t)(n * Ca + ci) * H + iy) * W
                    : inB + ((size_t)(n * Cb + (ci - Ca)) * H + iy) * W;
                v[ky][0] = left_ok ? r[x0 - 1] : 0.f;
                float4 q0 = *(const float4*)(r + x0);
                float4 q1 = *(const float4*)(r + x0 + 4);
                v[ky][1] = q0.x; v[ky][2] = q0.y; v[ky][3] = q0.z; v[ky][4] = q0.w;
                v[ky][5] = q1.x; v[ky][6] = q1.y; v[ky][7] = q1.z; v[ky][8] = q1.w;
                v[ky][9] = right_ok ? r[x0 + 8] : 0.f;
            }
        }
#pragma unroll
        for (int j = 0; j < TCO; ++j) {
            const float* wp = w + ((size_t)(co0 + j) * Cin + ci) * 9;
#pragma unroll
            for (int ky = 0; ky < 3; ++ky) {
                float w0 = wp[ky * 3 + 0], w1 = wp[ky * 3 + 1], w2 = wp[ky * 3 + 2];
#pragma unroll
                for (int p = 0; p < 8; ++p)
                    acc[j][p] += w0 * v[ky][p] + w1 * v[ky][p + 1] + w2 * v[ky][p + 2];
            }
        }
    }

#pragma unroll
    for (int j = 0; j < TCO; ++j) {
#pragma unroll
        for (int p = 0; p < 8; ++p)
            if (do_relu) acc[j][p] = fmaxf(acc[j][p], 0.f);
        float* o = out + ((size_t)(n * Cout + co0 + j) * H + y) * W + x0;
        float4 q0; q0.x = acc[j][0]; q0.y = acc[j][1]; q0.z = acc[j][2]; q0.w = acc[j][3];
        float4 q1; q1.x = acc[j][4]; q1.y = acc[j][5]; q1.z = acc[j][6]; q1.w = acc[j][7];
        *(float4*)o = q0;
        *(float4*)(o + 4) = q1;
    }
}

template <int TCO>
__global__ __launch_bounds__(BS) void conv3x3_s2_co_kernel(
    const float* __restrict__ inA, int Ca,
    const float* __restrict__ inB, int Cb,
    const float* __restrict__ w, const float* __restrict__ b,
    float* __restrict__ out,
    int N, int Hi, int Wi, int Cout, int do_relu)
{
    const int Ho = Hi >> 1, Wo = Wi >> 1, Woq = Wo >> 2;
    int idx = blockIdx.x * BS + threadIdx.x;
    int total = N * Ho * Woq;
    if (idx >= total) return;
    int q  = idx % Woq;
    int t  = idx / Woq;
    int oy = t % Ho;
    int n  = t / Ho;
    int ox0 = q << 2;
    int ix0 = ox0 << 1;
    const int co0 = blockIdx.y * TCO;
    const bool right_ok = (ix0 + 8 < Wi);
    const int Cin = Ca + Cb;

    float acc[TCO][4];
#pragma unroll
    for (int j = 0; j < TCO; ++j) {
        float bv = b[co0 + j];
        acc[j][0] = bv; acc[j][1] = bv; acc[j][2] = bv; acc[j][3] = bv;
    }

    for (int ci = 0; ci < Cin; ++ci) {
        const float* base = (ci < Ca)
            ? inA + (size_t)(n * Ca + ci) * Hi * Wi
            : inB + (size_t)(n * Cb + (ci - Ca)) * Hi * Wi;
        float v[3][9];
#pragma unroll
        for (int ky = 0; ky < 3; ++ky) {
            int iy = 2 * oy + ky;
            if (iy >= Hi) {
#pragma unroll
                for (int p = 0; p < 9; ++p) v[ky][p] = 0.f;
                continue;
            }
            const float* r = base + (size_t)iy * Wi + ix0;
            float4 a = *(const float4*)r;
            float4 c = *(const float4*)(r + 4);
            v[ky][0] = a.x; v[ky][1] = a.y; v[ky][2] = a.z; v[ky][3] = a.w;
            v[ky][4] = c.x; v[ky][5] = c.y; v[ky][6] = c.z; v[ky][7] = c.w;
            v[ky][8] = right_ok ? r[8] : 0.f;
        }
#pragma unroll
        for (int j = 0; j < TCO; ++j) {
            const float* wp = w + ((size_t)(co0 + j) * Cin + ci) * 9;
#pragma unroll
            for (int ky = 0; ky < 3; ++ky) {
                float w0 = wp[ky * 3 + 0], w1 = wp[ky * 3 + 1], w2 = wp[ky * 3 + 2];
#pragma unroll
                for (int p = 0; p < 4; ++p)
                    acc[j][p] += w0 * v[ky][2 * p] + w1 * v[ky][2 * p + 1] + w2 * v[ky][2 * p + 2];
            }
        }
    }

#pragma unroll
    for (int j = 0; j < TCO; ++j) {
        float4 o;
        o.x = acc[j][0]; o.y = acc[j][1]; o.z = acc[j][2]; o.w = acc[j][3];
        if (do_relu) {
            o.x = fmaxf(o.x, 0.f); o.y = fmaxf(o.y, 0.f);
            o.z = fmaxf(o.z, 0.f); o.w = fmaxf(o.w, 0.f);
        }
        *(float4*)(out + ((size_t)(n * Cout + co0 + j) * Ho + oy) * Wo + ox0) = o;
    }
}

__global__ __launch_bounds__(BS) void maxpool2_kernel(
    const float* __restrict__ in, float* __restrict__ out, int NC, int H, int W)
{
    int Ho = H >> 1, Wo = W >> 1, Woq = Wo >> 2;
    int idx = blockIdx.x * BS + threadIdx.x;
    int total = NC * Ho * Woq;
    if (idx >= total) return;
    int x4 = idx % Woq;
    int t  = idx / Woq;
    int y  = t % Ho;
    int c  = t / Ho;
    const float* r0 = in + ((size_t)c * H + 2 * y) * W + 8 * x4;
    const float* r1 = r0 + W;
    float4 a0 = *(const float4*)r0;
    float4 a1 = *(const float4*)(r0 + 4);
    float4 b0 = *(const float4*)r1;
    float4 b1 = *(const float4*)(r1 + 4);
    float4 o;
    o.x = fmaxf(fmaxf(a0.x, a0.y), fmaxf(b0.x, b0.y));
    o.y = fmaxf(fmaxf(a0.z, a0.w), fmaxf(b0.z, b0.w));
    o.z = fmaxf(fmaxf(a1.x, a1.y), fmaxf(b1.x, b1.y));
    o.w = fmaxf(fmaxf(a1.z, a1.w), fmaxf(b1.z, b1.w));
    *(float4*)(out + ((size_t)c * Ho + y) * Wo + 4 * x4) = o;
}

template <int TCO>
__global__ __launch_bounds__(BS) void conv1x1_co_kernel(
    const float* __restrict__ in, const float* __restrict__ w,
    const float* __restrict__ b, float* __restrict__ out,
    int N, int Cin, int HW, int Cout, int do_relu)
{
    int HWq = HW >> 2;
    int idx = blockIdx.x * BS + threadIdx.x;
    int total = N * HWq;
    if (idx >= total) return;
    int q = idx % HWq;
    int n = idx / HWq;
    const int co0 = blockIdx.y * TCO;

    float acc[TCO][4];
#pragma unroll
    for (int j = 0; j < TCO; ++j) {
        int co = min(co0 + j, Cout - 1);
        float bv = b[co];
        acc[j][0] = bv; acc[j][1] = bv; acc[j][2] = bv; acc[j][3] = bv;
    }
    const float* base = in + (size_t)n * Cin * HW + 4 * q;
    for (int ci = 0; ci < Cin; ++ci) {
        float4 v = *(const float4*)(base + (size_t)ci * HW);
#pragma unroll
        for (int j = 0; j < TCO; ++j) {
            int co = min(co0 + j, Cout - 1);
            float wv = w[(size_t)co * Cin + ci];
            acc[j][0] += wv * v.x; acc[j][1] += wv * v.y;
            acc[j][2] += wv * v.z; acc[j][3] += wv * v.w;
        }
    }
#pragma unroll
    for (int j = 0; j < TCO; ++j) {
        if (co0 + j >= Cout) break;
        float4 o;
        o.x = acc[j][0]; o.y = acc[j][1]; o.z = acc[j][2]; o.w = acc[j][3];
        if (do_relu) {
            o.x = fmaxf(o.x, 0.f); o.y = fmaxf(o.y, 0.f);
            o.z = fmaxf(o.z, 0.f); o.w = fmaxf(o.w, 0.f);
        }
        *(float4*)(out + ((size_t)(n * Cout + co0 + j)) * HW + 4 * q) = o;
    }
}

__global__ __launch_bounds__(BS) void peaks_kernel(
    const float* __restrict__ hm, float* __restrict__ out,
    int NC, int H, int W, float thresh)
{
    int idx = blockIdx.x * BS + threadIdx.x;
    int total = NC * H * W;
    if (idx >= total) return;
    int x = idx % W;
    int t = idx / W;
    int y = t % H;
    int c = t / H;
    float r = 0.f;
    if (x >= 1 && x < W - 1 && y >= 1 && y < H - 1) {
        const float* base = hm + (size_t)c * H * W;
        float cv = base[y * W + x];
        if (cv > thresh &&
            cv >= base[(y - 1) * W + x] &&
            cv >= base[(y + 1) * W + x] &&
            cv >= base[y * W + (x - 1)] &&
            cv >= base[y * W + (x + 1)])
            r = 1.f;
    }
    out[idx] = r;
}

static inline int nblk(long n) { return (int)((n + BS - 1) / BS); }

extern "C" void kernel_launch(void* const* d_in, const int* in_sizes, int n_in,
                              void* d_out, int out_size, void* d_ws, size_t ws_size,
                              hipStream_t stream)
{
    const float* x     = (const float*)d_in[0];
    const float* w_d1  = (const float*)d_in[1];  const float* b_d1  = (const float*)d_in[2];
    const float* w_d2  = (const float*)d_in[3];  const float* b_d2  = (const float*)d_in[4];
    const float* w_bn  = (const float*)d_in[5];  const float* b_bn  = (const float*)d_in[6];
    const float* w_u1  = (const float*)d_in[7];  const float* b_u1  = (const float*)d_in[8];
    const float* w_u2  = (const float*)d_in[9];  const float* b_u2  = (const float*)d_in[10];
    const float* w_seg = (const float*)d_in[11]; const float* b_seg = (const float*)d_in[12];
    const float* w_p1  = (const float*)d_in[13]; const float* b_p1  = (const float*)d_in[14];
    const float* w_p2  = (const float*)d_in[15]; const float* b_p2  = (const float*)d_in[16];
    const float* w_hm  = (const float*)d_in[17]; const float* b_hm  = (const float*)d_in[18];
    const float* w_paf = (const float*)d_in[19]; const float* b_paf = (const float*)d_in[20];

    const int N = 8, H = 384, W = 384;
    const int H2 = 192, W2 = 192, H4 = 96, W4 = 96;

    float* ws = (float*)d_ws;
    // Workspace extent = 56,623,104 floats = 216 MiB (R2 lifetime map).
    float* u1  = ws;                   // 8*64*192*192 = 18874368
    float* d1  = ws + 18874368;        // 8*32*384*384 = 37748736
    float* d2  = ws + 18874368;        // 8*64*192*192 = 18874368
    float* bn  = ws + 37748736;        // 8*128*96*96  = 9437184
    float* pd1 = ws;                   // 8*32*192*192 = 9437184
    float* pd2 = ws + 47185920;        // 8*64*96*96   = 4718592
    float* p1  = ws;                   // 8*64*192*192 = 18874368
    float* p2  = ws + 18874368;        // 8*128*96*96  = 9437184

    float* out_seg   = (float*)d_out;                 // 1179648
    float* out_hm    = out_seg + 1179648;             // 1253376
    float* out_paf   = out_hm + 1253376;              // 2359296
    float* out_peaks = out_paf + 2359296;             // 1253376
    // packed weights live in the peaks region [4792320, 6045696), consumed
    // before step 13 overwrites it. All 16B-aligned.
    _Float16* bp_u1 = (_Float16*)(out_seg + 4792320); // 110592 fl
    _Float16* bp_u2 = (_Float16*)(out_seg + 4902912); // 27648 fl
    _Float16* bp_d2 = (_Float16*)(out_seg + 4930560); // 1*9*4*64*8*2 f16 = 18432 fl
    _Float16* bp_bn = (_Float16*)(out_seg + 4948992); // 2*9*8*64*8*2 f16 = 73728 fl
    // ends 5022720 <= 6045696 OK

    // 0. pack weights (fragment-ready f16 hi/lo)
    packw_gen_kernel<<<nblk(13824), BS, 0, stream>>>(w_u1, bp_u1, 192, 64);
    packw_gen_kernel<<<nblk(3456),  BS, 0, stream>>>(w_u2, bp_u2, 96, 32);
    packw_gen_kernel<<<nblk(2304),  BS, 0, stream>>>(w_d2, bp_d2, 32, 64);
    packw_gen_kernel<<<nblk(9216),  BS, 0, stream>>>(w_bn, bp_bn, 64, 128);
    // 1. d1 = relu(conv3x3(x; 3->32)) @384
    {
        dim3 g(nblk((long)N * H * (W / 8)), 32 / 8);
        conv3x3_x8_kernel<1, 8><<<g, BS, 0, stream>>>(
            x, 3, nullptr, 0, w_d1, b_d1, d1, N, H, W, 32, 1);
    }
    // 2. pd1 = maxpool(d1) @192
    maxpool2_kernel<<<nblk((long)N * 32 * H2 * (W2 / 4)), BS, 0, stream>>>(d1, pd1, N * 32, H, W);
    // 3. d2 = relu(conv3x3(pd1; 32->64)) @192  [MFMA]
    conv3x3_mfma_kernel<1, 4, 192, 192><<<8 * 96 * 6, BS, 0, stream>>>(
        pd1, bp_d2, b_d2, d2);
    // 4. pd2 = maxpool(d2) @96
    maxpool2_kernel<<<nblk((long)N * 64 * H4 * (W4 / 4)), BS, 0, stream>>>(d2, pd2, N * 64, H2, W2);
    // 5. bn = relu(conv3x3(pd2; 64->128)) @96  [MFMA]
    conv3x3_mfma_kernel<2, 8, 96, 96><<<8 * 48 * 3, BS, 0, stream>>>(
        pd2, bp_bn, b_bn, bn);
    // 6. u1 = relu(conv3x3(concat(up2(bn), d2); 192->64)) @192  [MFMA]
    u1_mfma_kernel<<<4608, BS, 0, stream>>>(bn, d2, bp_u1, b_u1, u1);
    // 7. d1' = relu(conv3x3(x; 3->32)) @384  (recompute)
    {
        dim3 g(nblk((long)N * H * (W / 8)), 32 / 8);
        conv3x3_x8_kernel<1, 8><<<g, BS, 0, stream>>>(
            x, 3, nullptr, 0, w_d1, b_d1, d1, N, H, W, 32, 1);
    }
    // 8. seg via fused MFMA u2+seg @384
    u2seg_mfma_kernel<<<18432, BS, 0, stream>>>(
        u1, d1, bp_u2, b_u2, w_seg, b_seg, out_seg);
    // 9. p1 = relu(conv3x3_s2(concat(x, seg); 4->64)) @384->192
    {
        dim3 g(nblk((long)N * H2 * (W2 / 4)), 64 / 8);
        conv3x3_s2_co_kernel<8><<<g, BS, 0, stream>>>(
            x, 3, out_seg, 1, w_p1, b_p1, p1, N, H, W, 64, 1);
    }
    // 10. p2 = relu(conv3x3_s2(p1; 64->128)) @192->96
    {
        dim3 g(nblk((long)N * H4 * (W4 / 4)), 128 / 8);
        conv3x3_s2_co_kernel<8><<<g, BS, 0, stream>>>(
            p1, 64, nullptr, 0, w_p2, b_p2, p2, N, H2, W2, 128, 1);
    }
    // 11. hm = conv1x1(p2; 128->17) @96
    {
        dim3 g(nblk((long)N * (H4 * W4 / 4)), 3);
        conv1x1_co_kernel<8><<<g, BS, 0, stream>>>(
            p2, w_hm, b_hm, out_hm, N, 128, H4 * W4, 17, 0);
    }
    // 12. paf = conv1x1(p2; 128->32) @96
    {
        dim3 g(nblk((long)N * (H4 * W4 / 4)), 4);
        conv1x1_co_kernel<8><<<g, BS, 0, stream>>>(
            p2, w_paf, b_paf, out_paf, N, 128, H4 * W4, 32, 0);
    }
    // 13. peaks @96  (overwrites packed-weight region - already consumed)
    peaks_kernel<<<nblk((long)N * 17 * H4 * W4), BS, 0, stream>>>(
        out_hm, out_peaks, N * 17, H4, W4, 0.1f);
}

// Round 12
// 1220.481 us; speedup vs baseline: 3.8398x; 1.1754x over previous
//
#include <hip/hip_runtime.h>

// ---------------------------------------------------------------------------
// TeacherModel: small U-Net + pose heads. B=8, H=W=384, fp32 NCHW.
// Round 12: 4-row blocking for u1/u2seg MFMA kernels. R11: u2seg 380us with
// 702MB FETCH vs 226MB unique (3x halo re-read from 1-row blocks), MfmaUtil
// 22%, nothing saturated. Now: block = 4 output rows x 64 px -> halo re-read
// 3x->1.5x (d1/d2) and 4x->2x (u1/bn), 4x fewer barriers/px, B-frags
// amortized over 4 M-tiles. Same accumulation order => absmax must stay
// exactly 0.0078125.
// ---------------------------------------------------------------------------

#define BS 256

typedef _Float16 half8 __attribute__((ext_vector_type(8)));
typedef float floatx4 __attribute__((ext_vector_type(4)));

#define LDSDW 20    // dwords per x position
#define PL4 8160    // 6*68*LDSDW dwords per plane (4-row kernels)

// ===========================================================================
// Generic weight pre-pack: layout [plane(hi/lo)][chunk][tap(9)][nt][lane][8]
// element: ci = chunk*32 + (lane>>4)*8 + j ; co = nt*16 + (lane&15)
// ===========================================================================
__global__ __launch_bounds__(BS) void packw_gen_kernel(
    const float* __restrict__ w, _Float16* __restrict__ bp, int Cin, int Cout)
{
    int total = (Cin >> 5) * 9 * (Cout >> 4) * 64;
    int tid = blockIdx.x * BS + threadIdx.x;
    if (tid >= total) return;
    int lane = tid & 63;
    int t = tid >> 6;
    int NTl = Cout >> 4;
    int nt = t % NTl; t /= NTl;
    int tap = t % 9;
    int chunk = t / 9;
    int q = lane >> 4, n = lane & 15;
    int co = nt * 16 + n;
    _Float16* ph = bp + (size_t)tid * 8;
    _Float16* pl = bp + (size_t)total * 8 + (size_t)tid * 8;
#pragma unroll
    for (int j = 0; j < 8; ++j) {
        int ci = chunk * 32 + q * 8 + j;
        float v = w[((size_t)co * Cin + ci) * 9 + tap];
        _Float16 h = (_Float16)v;
        ph[j] = h;
        pl[j] = (_Float16)(v - (float)h);
    }
}

// ===========================================================================
// Generic stride-1 3x3 SAME conv via MFMA (R11): block = 2 rows x 32 px.
// Used for d2 (1,4,@192) and bn (2,8,@96).
// ===========================================================================
template <int CHUNKS, int NT, int HH, int WW>
__global__ __launch_bounds__(BS) void conv3x3_mfma_kernel(
    const float* __restrict__ in_,
    const _Float16* __restrict__ bp,
    const float* __restrict__ bias,
    float* __restrict__ out)
{
    constexpr int PL = 4 * 34 * LDSDW;
    constexpr int EPI = 64 * NT * 16;
    constexpr int LDS_DW = (2 * PL > EPI) ? 2 * PL : EPI;
    __shared__ unsigned int lds[LDS_DW];

    int xblks = WW / 32;
    int b = blockIdx.x;
    int xb = b % xblks; b /= xblks;
    int yp = b % (HH / 2);
    int n  = b / (HH / 2);
    int y0 = yp * 2;
    int x0 = xb * 32;

    int tid = threadIdx.x;
    int lane = tid & 63, wv = tid >> 6;
    int m = lane & 15, q = lane >> 4;
    int lrow = wv >> 1;
    int lx   = (wv & 1) * 16;

    floatx4 acc[NT];
#pragma unroll
    for (int nt = 0; nt < NT; ++nt) acc[nt] = (floatx4){0.f, 0.f, 0.f, 0.f};

    const int planeW = CHUNKS * 9 * NT * 64 * 8;

    for (int chunk = 0; chunk < CHUNKS; ++chunk) {
        __syncthreads();
        for (int e = tid; e < 4 * 34 * 4; e += BS) {
            int xi = e % 34;
            int rest = e / 34;
            int oct = rest & 3;
            int row = rest >> 2;
            int iy = y0 - 1 + row, gx = x0 - 1 + xi;
            bool ok = (iy >= 0 && iy < HH && gx >= 0 && gx < WW);
            const float* gp = in_ +
                ((size_t)(n * (CHUNKS * 32) + chunk * 32 + oct * 8) * HH + iy) * WW + gx;
            half8 hv, lv;
#pragma unroll
            for (int j = 0; j < 8; ++j) {
                float v = ok ? gp[(size_t)j * HH * WW] : 0.f;
                _Float16 h = (_Float16)v;
                hv[j] = h;
                lv[j] = (_Float16)(v - (float)h);
            }
            int base = (row * 34 + xi) * LDSDW + oct * 4;
            *(half8*)((char*)lds + (size_t)base * 4) = hv;
            *(half8*)((char*)lds + ((size_t)PL + base) * 4) = lv;
        }
        __syncthreads();
#pragma unroll
        for (int ky = 0; ky < 3; ++ky) {
#pragma unroll
            for (int kx = 0; kx < 3; ++kx) {
                int row = lrow + ky;
                int xi  = lx + m + kx;
                int adw = (row * 34 + xi) * LDSDW + q * 4;
                half8 ah = *(const half8*)((const char*)lds + (size_t)adw * 4);
                half8 al = *(const half8*)((const char*)lds + ((size_t)PL + adw) * 4);
                int tap = ky * 3 + kx;
                const _Float16* bpp = bp + ((size_t)(chunk * 9 + tap) * NT) * 64 * 8;
#pragma unroll
                for (int nt = 0; nt < NT; ++nt) {
                    half8 bh = *(const half8*)(bpp + ((size_t)nt * 64 + lane) * 8);
                    half8 bl = *(const half8*)(bpp + planeW + ((size_t)nt * 64 + lane) * 8);
                    acc[nt] = __builtin_amdgcn_mfma_f32_16x16x32_f16(ah, bh, acc[nt], 0, 0, 0);
                    acc[nt] = __builtin_amdgcn_mfma_f32_16x16x32_f16(ah, bl, acc[nt], 0, 0, 0);
                    acc[nt] = __builtin_amdgcn_mfma_f32_16x16x32_f16(al, bh, acc[nt], 0, 0, 0);
                }
            }
        }
    }

    __syncthreads();
#pragma unroll
    for (int nt = 0; nt < NT; ++nt) {
#pragma unroll
        for (int r = 0; r < 4; ++r) {
            int co = nt * 16 + m;
            int pxl = wv * 16 + q * 4 + r;
            ((float*)lds)[co * 64 + pxl] = acc[nt][r];
        }
    }
    __syncthreads();
    {
        constexpr int thPerCo = 256 / (NT * 16);
        constexpr int pxPerTh = 64 / thPerCo;
        int co = tid / thPerCo;
        int sub = tid % thPerCo;
        int pxb = sub * pxPerTh;
        float bb = bias[co];
#pragma unroll
        for (int u = 0; u < pxPerTh; u += 4) {
            int p = pxb + u;
            int row = y0 + (p >> 5), xx = x0 + (p & 31);
            const float* lp = (const float*)lds + co * 64 + p;
            float4 vv = *(const float4*)lp;
            vv.x = fmaxf(vv.x + bb, 0.f);
            vv.y = fmaxf(vv.y + bb, 0.f);
            vv.z = fmaxf(vv.z + bb, 0.f);
            vv.w = fmaxf(vv.w + bb, 0.f);
            *(float4*)(out + ((size_t)(n * NT * 16 + co) * HH + row) * WW + xx) = vv;
        }
    }
}

// ===========================================================================
// u1 = relu(conv3x3(concat(up2(bn), d2))) via MFMA, 4 rows x 64 px @192.
// Wave wv handles output row y0+wv; acc[mt 0..3][nt 0..3].
// ===========================================================================
__global__ __launch_bounds__(BS) void u1_mfma_kernel(
    const float* __restrict__ bn_,   // [8,128,96,96]
    const float* __restrict__ d2_,   // [8,64,192,192]
    const _Float16* __restrict__ bp,
    const float* __restrict__ b_u1,  // [64]
    float* __restrict__ out)         // [8,64,192,192]
{
    __shared__ unsigned int lds[2 * PL4];             // 65280 B
    const int Ho = 192, Wo = 192;
    int b = blockIdx.x;
    int xb = b % 3; b /= 3;
    int yb = b % 48;
    int n  = b / 48;
    int y0 = yb * 4;
    int x0 = xb * 64;

    int tid = threadIdx.x;
    int lane = tid & 63, wv = tid >> 6;
    int m = lane & 15, q = lane >> 4;
    int yr = y0 + wv;

    floatx4 acc[4][4];                                // [mt][nt]
#pragma unroll
    for (int mt = 0; mt < 4; ++mt)
#pragma unroll
        for (int nt = 0; nt < 4; ++nt) acc[mt][nt] = (floatx4){0.f, 0.f, 0.f, 0.f};

    const int hh0 = (y0 - 1) >> 1;
    const int hx0 = (x0 - 1) >> 1;

    for (int chunk = 0; chunk < 6; ++chunk) {
        __syncthreads();
        if (chunk < 4) {
            // bn half-res: 4 rows x 34 xi x 4 octets
            for (int e = tid; e < 4 * 34 * 4; e += BS) {
                int xi = e % 34;
                int rest = e / 34;
                int oct = rest & 3;
                int row = rest >> 2;
                int hy = hh0 + row, hx = hx0 + xi;
                bool ok = (hy >= 0 && hy < 96 && hx >= 0 && hx < 96);
                const float* gp = bn_ +
                    ((size_t)(n * 128 + chunk * 32 + oct * 8) * 96 + hy) * 96 + hx;
                half8 hv, lv;
#pragma unroll
                for (int j = 0; j < 8; ++j) {
                    float v = ok ? gp[(size_t)j * 96 * 96] : 0.f;
                    _Float16 h = (_Float16)v;
                    hv[j] = h;
                    lv[j] = (_Float16)(v - (float)h);
                }
                int base = (row * 68 + xi) * LDSDW + oct * 4;
                *(half8*)((char*)lds + (size_t)base * 4) = hv;
                *(half8*)((char*)lds + ((size_t)PL4 + base) * 4) = lv;
            }
        } else {
            // d2 full-res: 6 rows x 68 xi x 4 octets
            for (int e = tid; e < 6 * 68 * 4; e += BS) {
                int xi = e % 68;
                int rest = e / 68;
                int oct = rest & 3;
                int row = rest >> 2;
                int iy = y0 - 1 + row, gx = x0 - 1 + xi;
                bool ok = (xi < 67 && iy >= 0 && iy < Ho && gx >= 0 && gx < Wo);
                const float* gp = d2_ +
                    ((size_t)(n * 64 + (chunk - 4) * 32 + oct * 8) * Ho + iy) * Wo + gx;
                half8 hv, lv;
#pragma unroll
                for (int j = 0; j < 8; ++j) {
                    float v = ok ? gp[(size_t)j * Ho * Wo] : 0.f;
                    _Float16 h = (_Float16)v;
                    hv[j] = h;
                    lv[j] = (_Float16)(v - (float)h);
                }
                int base = (row * 68 + xi) * LDSDW + oct * 4;
                *(half8*)((char*)lds + (size_t)base * 4) = hv;
                *(half8*)((char*)lds + ((size_t)PL4 + base) * 4) = lv;
            }
        }
        __syncthreads();
#pragma unroll
        for (int ky = 0; ky < 3; ++ky) {
#pragma unroll
            for (int kx = 0; kx < 3; ++kx) {
                int tap = ky * 3 + kx;
                const _Float16* bpp = bp + ((size_t)(chunk * 9 + tap) * 4) * 64 * 8;
                half8 bh[4], bl[4];
#pragma unroll
                for (int nt = 0; nt < 4; ++nt) {
                    bh[nt] = *(const half8*)(bpp + ((size_t)nt * 64 + lane) * 8);
                    bl[nt] = *(const half8*)(bpp + 110592 + ((size_t)nt * 64 + lane) * 8);
                }
                int row;
                if (chunk < 4) row = ((yr + ky - 1) >> 1) - hh0;
                else           row = wv + ky;
#pragma unroll
                for (int mt = 0; mt < 4; ++mt) {
                    int px = 16 * mt + m;
                    int xi = (chunk < 4) ? (((x0 + px + kx - 1) >> 1) - hx0)
                                         : (px + kx);
                    int adw = (row * 68 + xi) * LDSDW + q * 4;
                    half8 ah = *(const half8*)((const char*)lds + (size_t)adw * 4);
                    half8 al = *(const half8*)((const char*)lds + ((size_t)PL4 + adw) * 4);
#pragma unroll
                    for (int nt = 0; nt < 4; ++nt) {
                        acc[mt][nt] = __builtin_amdgcn_mfma_f32_16x16x32_f16(ah, bh[nt], acc[mt][nt], 0, 0, 0);
                        acc[mt][nt] = __builtin_amdgcn_mfma_f32_16x16x32_f16(ah, bl[nt], acc[mt][nt], 0, 0, 0);
                        acc[mt][nt] = __builtin_amdgcn_mfma_f32_16x16x32_f16(al, bh[nt], acc[mt][nt], 0, 0, 0);
                    }
                }
            }
        }
    }

    // epilogue: two passes (32 cos each) via LDS transpose
#pragma unroll
    for (int h = 0; h < 2; ++h) {
        __syncthreads();
#pragma unroll
        for (int ntl = 0; ntl < 2; ++ntl) {
#pragma unroll
            for (int mt = 0; mt < 4; ++mt) {
#pragma unroll
                for (int r = 0; r < 4; ++r) {
                    ((float*)lds)[(ntl * 16 + m) * 256 + wv * 64 + 16 * mt + q * 4 + r]
                        = acc[mt][h * 2 + ntl][r];
                }
            }
        }
        __syncthreads();
        {
            int col = tid >> 3;                 // 0..31
            int g   = tid & 7;
            int row = g >> 1, xx = (g & 1) * 32;
            int co = h * 32 + col;
            float bb = b_u1[co];
            const float* lp = (const float*)lds + col * 256 + row * 64 + xx;
            float* op = out + ((size_t)(n * 64 + co) * Ho + y0 + row) * Wo + x0 + xx;
#pragma unroll
            for (int u = 0; u < 32; u += 4) {
                float4 vv = *(const float4*)(lp + u);
                vv.x = fmaxf(vv.x + bb, 0.f);
                vv.y = fmaxf(vv.y + bb, 0.f);
                vv.z = fmaxf(vv.z + bb, 0.f);
                vv.w = fmaxf(vv.w + bb, 0.f);
                *(float4*)(op + u) = vv;
            }
        }
    }
}

// ===========================================================================
// seg via fused MFMA u2+seg, 4 rows x 64 px @384; shfl_xor co-reduce.
// ===========================================================================
__global__ __launch_bounds__(BS) void u2seg_mfma_kernel(
    const float* __restrict__ u1_,   // [8,64,192,192]
    const float* __restrict__ d1_,   // [8,32,384,384]
    const _Float16* __restrict__ bp,
    const float* __restrict__ b_u2,  // [32]
    const float* __restrict__ w_seg, // [32]
    const float* __restrict__ b_seg, // [1]
    float* __restrict__ seg)         // [8,1,384,384]
{
    __shared__ unsigned int lds[2 * PL4];             // 65280 B
    const int Ho = 384, Wo = 384;
    int b = blockIdx.x;
    int xb = b % 6; b /= 6;
    int yb = b % 96;
    int n  = b / 96;
    int y0 = yb * 4;
    int x0 = xb * 64;

    int tid = threadIdx.x;
    int lane = tid & 63, wv = tid >> 6;
    int m = lane & 15, q = lane >> 4;
    int yr = y0 + wv;

    floatx4 acc[4][2];                                // [mt][nt]
#pragma unroll
    for (int mt = 0; mt < 4; ++mt) {
        acc[mt][0] = (floatx4){0.f, 0.f, 0.f, 0.f};
        acc[mt][1] = (floatx4){0.f, 0.f, 0.f, 0.f};
    }

    const int hh0 = (y0 - 1) >> 1;
    const int hx0 = (x0 - 1) >> 1;

    for (int chunk = 0; chunk < 3; ++chunk) {
        __syncthreads();
        if (chunk < 2) {
            // u1 half-res: 4 rows x 34 xi x 4 octets
            for (int e = tid; e < 4 * 34 * 4; e += BS) {
                int xi = e % 34;
                int rest = e / 34;
                int oct = rest & 3;
                int row = rest >> 2;
                int hy = hh0 + row, hx = hx0 + xi;
                bool ok = (hy >= 0 && hy < 192 && hx >= 0 && hx < 192);
                const float* gp = u1_ +
                    ((size_t)(n * 64 + chunk * 32 + oct * 8) * 192 + hy) * 192 + hx;
                half8 hv, lv;
#pragma unroll
                for (int j = 0; j < 8; ++j) {
                    float v = ok ? gp[(size_t)j * 192 * 192] : 0.f;
                    _Float16 h = (_Float16)v;
                    hv[j] = h;
                    lv[j] = (_Float16)(v - (float)h);
                }
                int base = (row * 68 + xi) * LDSDW + oct * 4;
                *(half8*)((char*)lds + (size_t)base * 4) = hv;
                *(half8*)((char*)lds + ((size_t)PL4 + base) * 4) = lv;
            }
        } else {
            // d1 full-res: 6 rows x 68 xi x 4 octets
            for (int e = tid; e < 6 * 68 * 4; e += BS) {
                int xi = e % 68;
                int rest = e / 68;
                int oct = rest & 3;
                int row = rest >> 2;
                int iy = y0 - 1 + row, gx = x0 - 1 + xi;
                bool ok = (xi < 67 && iy >= 0 && iy < Ho && gx >= 0 && gx < Wo);
                const float* gp = d1_ +
                    ((size_t)(n * 32 + oct * 8) * Ho + iy) * Wo + gx;
                half8 hv, lv;
#pragma unroll
                for (int j = 0; j < 8; ++j) {
                    float v = ok ? gp[(size_t)j * Ho * Wo] : 0.f;
                    _Float16 h = (_Float16)v;
                    hv[j] = h;
                    lv[j] = (_Float16)(v - (float)h);
                }
                int base = (row * 68 + xi) * LDSDW + oct * 4;
                *(half8*)((char*)lds + (size_t)base * 4) = hv;
                *(half8*)((char*)lds + ((size_t)PL4 + base) * 4) = lv;
            }
        }
        __syncthreads();
#pragma unroll
        for (int ky = 0; ky < 3; ++ky) {
#pragma unroll
            for (int kx = 0; kx < 3; ++kx) {
                int tap = ky * 3 + kx;
                const _Float16* bpp = bp + ((size_t)(chunk * 9 + tap) * 2) * 64 * 8;
                half8 bh0 = *(const half8*)(bpp + (size_t)lane * 8);
                half8 bl0 = *(const half8*)(bpp + 27648 + (size_t)lane * 8);
                half8 bh1 = *(const half8*)(bpp + ((size_t)64 + lane) * 8);
                half8 bl1 = *(const half8*)(bpp + 27648 + ((size_t)64 + lane) * 8);
                int row;
                if (chunk < 2) row = ((yr + ky - 1) >> 1) - hh0;
                else           row = wv + ky;
#pragma unroll
                for (int mt = 0; mt < 4; ++mt) {
                    int px = 16 * mt + m;
                    int xi = (chunk < 2) ? (((x0 + px + kx - 1) >> 1) - hx0)
                                         : (px + kx);
                    int adw = (row * 68 + xi) * LDSDW + q * 4;
                    half8 ah = *(const half8*)((const char*)lds + (size_t)adw * 4);
                    half8 al = *(const half8*)((const char*)lds + ((size_t)PL4 + adw) * 4);
                    acc[mt][0] = __builtin_amdgcn_mfma_f32_16x16x32_f16(ah, bh0, acc[mt][0], 0, 0, 0);
                    acc[mt][0] = __builtin_amdgcn_mfma_f32_16x16x32_f16(ah, bl0, acc[mt][0], 0, 0, 0);
                    acc[mt][0] = __builtin_amdgcn_mfma_f32_16x16x32_f16(al, bh0, acc[mt][0], 0, 0, 0);
                    acc[mt][1] = __builtin_amdgcn_mfma_f32_16x16x32_f16(ah, bh1, acc[mt][1], 0, 0, 0);
                    acc[mt][1] = __builtin_amdgcn_mfma_f32_16x16x32_f16(ah, bl1, acc[mt][1], 0, 0, 0);
                    acc[mt][1] = __builtin_amdgcn_mfma_f32_16x16x32_f16(al, bh1, acc[mt][1], 0, 0, 0);
                }
            }
        }
    }

    // epilogue: relu+w_seg dot, shfl_xor reduce over 16 co-lanes, per mt
    float bb0 = b_u2[m], bb1 = b_u2[16 + m];
    float ws0 = w_seg[m], ws1 = w_seg[16 + m];
    float bseg = b_seg[0];
#pragma unroll
    for (int mt = 0; mt < 4; ++mt) {
        float sr[4];
#pragma unroll
        for (int r = 0; r < 4; ++r) {
            float p = ws0 * fmaxf(acc[mt][0][r] + bb0, 0.f)
                    + ws1 * fmaxf(acc[mt][1][r] + bb1, 0.f);
            p += __shfl_xor(p, 1);
            p += __shfl_xor(p, 2);
            p += __shfl_xor(p, 4);
            p += __shfl_xor(p, 8);
            sr[r] = p + bseg;
        }
        if (m == 0) {
            float4 o; o.x = sr[0]; o.y = sr[1]; o.z = sr[2]; o.w = sr[3];
            *(float4*)(seg + ((size_t)n * Ho + yr) * Wo + x0 + 16 * mt + q * 4) = o;
        }
    }
}

// ===========================================================================
// Vector kernels (R7-R11), unchanged.
// ===========================================================================

template <int UPA, int TCO>
__global__ __launch_bounds__(BS, 2) void conv3x3_x8_kernel(
    const float* __restrict__ inA, int Ca,
    const float* __restrict__ inB, int Cb,
    const float* __restrict__ w, const float* __restrict__ b,
    float* __restrict__ out,
    int N, int H, int W, int Cout, int do_relu)
{
    const int W8 = W >> 3;
    int idx = blockIdx.x * BS + threadIdx.x;
    int total = N * H * W8;
    if (idx >= total) return;
    int x8 = idx % W8;
    int t  = idx / W8;
    int y  = t % H;
    int n  = t / H;
    int x0 = x8 << 3;
    const int co0 = blockIdx.y * TCO;
    const bool left_ok  = (x0 > 0);
    const bool right_ok = (x0 + 8 < W);
    const int Cin = Ca + Cb;

    float acc[TCO][8];
#pragma unroll
    for (int j = 0; j < TCO; ++j) {
        float bv = b[co0 + j];
#pragma unroll
        for (int p = 0; p < 8; ++p) acc[j][p] = bv;
    }

    for (int ci = 0; ci < Cin; ++ci) {
        float v[3][10];
#pragma unroll
        for (int ky = 0; ky < 3; ++ky) {
            int iy = y + ky - 1;
            if (iy < 0 || iy >= H) {
#pragma unroll
                for (int p = 0; p < 10; ++p) v[ky][p] = 0.f;
                continue;
            }
            if (UPA == 2 && ci < Ca) {
                const float* r = inA + ((size_t)(n * Ca + ci) * (H >> 1) + (iy >> 1)) * (W >> 1);
                int xh = x0 >> 1;
                float sm = left_ok  ? r[xh - 1] : 0.f;
                float4 qq = *(const float4*)(r + xh);
                float s4 = right_ok ? r[xh + 4] : 0.f;
                v[ky][0] = sm;
                v[ky][1] = qq.x; v[ky][2] = qq.x;
                v[ky][3] = qq.y; v[ky][4] = qq.y;
                v[ky][5] = qq.z; v[ky][6] = qq.z;
                v[ky][7] = qq.w; v[ky][8] = qq.w;
                v[ky][9] = s4;
            } else {
                const float* r = (ci < Ca)
                    ? inA + ((size_t)(n * Ca + ci) * H + iy) * W
                    : inB + ((size_t)(n * Cb + (ci - Ca)) * H + iy) * W;
                v[ky][0] = left_ok ? r[x0 - 1] : 0.f;
                float4 q0 = *(const float4*)(r + x0);
                float4 q1 = *(const float4*)(r + x0 + 4);
                v[ky][1] = q0.x; v[ky][2] = q0.y; v[ky][3] = q0.z; v[ky][4] = q0.w;
                v[ky][5] = q1.x; v[ky][6] = q1.y; v[ky][7] = q1.z; v[ky][8] = q1.w;
                v[ky][9] = right_ok ? r[x0 + 8] : 0.f;
            }
        }
#pragma unroll
        for (int j = 0; j < TCO; ++j) {
            const float* wp = w + ((size_t)(co0 + j) * Cin + ci) * 9;
#pragma unroll
            for (int ky = 0; ky < 3; ++ky) {
                float w0 = wp[ky * 3 + 0], w1 = wp[ky * 3 + 1], w2 = wp[ky * 3 + 2];
#pragma unroll
                for (int p = 0; p < 8; ++p)
                    acc[j][p] += w0 * v[ky][p] + w1 * v[ky][p + 1] + w2 * v[ky][p + 2];
            }
        }
    }

#pragma unroll
    for (int j = 0; j < TCO; ++j) {
#pragma unroll
        for (int p = 0; p < 8; ++p)
            if (do_relu) acc[j][p] = fmaxf(acc[j][p], 0.f);
        float* o = out + ((size_t)(n * Cout + co0 + j) * H + y) * W + x0;
        float4 q0; q0.x = acc[j][0]; q0.y = acc[j][1]; q0.z = acc[j][2]; q0.w = acc[j][3];
        float4 q1; q1.x = acc[j][4]; q1.y = acc[j][5]; q1.z = acc[j][6]; q1.w = acc[j][7];
        *(float4*)o = q0;
        *(float4*)(o + 4) = q1;
    }
}

template <int TCO>
__global__ __launch_bounds__(BS) void conv3x3_s2_co_kernel(
    const float* __restrict__ inA, int Ca,
    const float* __restrict__ inB, int Cb,
    const float* __restrict__ w, const float* __restrict__ b,
    float* __restrict__ out,
    int N, int Hi, int Wi, int Cout, int do_relu)
{
    const int Ho = Hi >> 1, Wo = Wi >> 1, Woq = Wo >> 2;
    int idx = blockIdx.x * BS + threadIdx.x;
    int total = N * Ho * Woq;
    if (idx >= total) return;
    int q  = idx % Woq;
    int t  = idx / Woq;
    int oy = t % Ho;
    int n  = t / Ho;
    int ox0 = q << 2;
    int ix0 = ox0 << 1;
    const int co0 = blockIdx.y * TCO;
    const bool right_ok = (ix0 + 8 < Wi);
    const int Cin = Ca + Cb;

    float acc[TCO][4];
#pragma unroll
    for (int j = 0; j < TCO; ++j) {
        float bv = b[co0 + j];
        acc[j][0] = bv; acc[j][1] = bv; acc[j][2] = bv; acc[j][3] = bv;
    }

    for (int ci = 0; ci < Cin; ++ci) {
        const float* base = (ci < Ca)
            ? inA + (size_t)(n * Ca + ci) * Hi * Wi
            : inB + (size_t)(n * Cb + (ci - Ca)) * Hi * Wi;
        float v[3][9];
#pragma unroll
        for (int ky = 0; ky < 3; ++ky) {
            int iy = 2 * oy + ky;
            if (iy >= Hi) {
#pragma unroll
                for (int p = 0; p < 9; ++p) v[ky][p] = 0.f;
                continue;
            }
            const float* r = base + (size_t)iy * Wi + ix0;
            float4 a = *(const float4*)r;
            float4 c = *(const float4*)(r + 4);
            v[ky][0] = a.x; v[ky][1] = a.y; v[ky][2] = a.z; v[ky][3] = a.w;
            v[ky][4] = c.x; v[ky][5] = c.y; v[ky][6] = c.z; v[ky][7] = c.w;
            v[ky][8] = right_ok ? r[8] : 0.f;
        }
#pragma unroll
        for (int j = 0; j < TCO; ++j) {
            const float* wp = w + ((size_t)(co0 + j) * Cin + ci) * 9;
#pragma unroll
            for (int ky = 0; ky < 3; ++ky) {
                float w0 = wp[ky * 3 + 0], w1 = wp[ky * 3 + 1], w2 = wp[ky * 3 + 2];
#pragma unroll
                for (int p = 0; p < 4; ++p)
                    acc[j][p] += w0 * v[ky][2 * p] + w1 * v[ky][2 * p + 1] + w2 * v[ky][2 * p + 2];
            }
        }
    }

#pragma unroll
    for (int j = 0; j < TCO; ++j) {
        float4 o;
        o.x = acc[j][0]; o.y = acc[j][1]; o.z = acc[j][2]; o.w = acc[j][3];
        if (do_relu) {
            o.x = fmaxf(o.x, 0.f); o.y = fmaxf(o.y, 0.f);
            o.z = fmaxf(o.z, 0.f); o.w = fmaxf(o.w, 0.f);
        }
        *(float4*)(out + ((size_t)(n * Cout + co0 + j) * Ho + oy) * Wo + ox0) = o;
    }
}

__global__ __launch_bounds__(BS) void maxpool2_kernel(
    const float* __restrict__ in, float* __restrict__ out, int NC, int H, int W)
{
    int Ho = H >> 1, Wo = W >> 1, Woq = Wo >> 2;
    int idx = blockIdx.x * BS + threadIdx.x;
    int total = NC * Ho * Woq;
    if (idx >= total) return;
    int x4 = idx % Woq;
    int t  = idx / Woq;
    int y  = t % Ho;
    int c  = t / Ho;
    const float* r0 = in + ((size_t)c * H + 2 * y) * W + 8 * x4;
    const float* r1 = r0 + W;
    float4 a0 = *(const float4*)r0;
    float4 a1 = *(const float4*)(r0 + 4);
    float4 b0 = *(const float4*)r1;
    float4 b1 = *(const float4*)(r1 + 4);
    float4 o;
    o.x = fmaxf(fmaxf(a0.x, a0.y), fmaxf(b0.x, b0.y));
    o.y = fmaxf(fmaxf(a0.z, a0.w), fmaxf(b0.z, b0.w));
    o.z = fmaxf(fmaxf(a1.x, a1.y), fmaxf(b1.x, b1.y));
    o.w = fmaxf(fmaxf(a1.z, a1.w), fmaxf(b1.z, b1.w));
    *(float4*)(out + ((size_t)c * Ho + y) * Wo + 4 * x4) = o;
}

template <int TCO>
__global__ __launch_bounds__(BS) void conv1x1_co_kernel(
    const float* __restrict__ in, const float* __restrict__ w,
    const float* __restrict__ b, float* __restrict__ out,
    int N, int Cin, int HW, int Cout, int do_relu)
{
    int HWq = HW >> 2;
    int idx = blockIdx.x * BS + threadIdx.x;
    int total = N * HWq;
    if (idx >= total) return;
    int q = idx % HWq;
    int n = idx / HWq;
    const int co0 = blockIdx.y * TCO;

    float acc[TCO][4];
#pragma unroll
    for (int j = 0; j < TCO; ++j) {
        int co = min(co0 + j, Cout - 1);
        float bv = b[co];
        acc[j][0] = bv; acc[j][1] = bv; acc[j][2] = bv; acc[j][3] = bv;
    }
    const float* base = in + (size_t)n * Cin * HW + 4 * q;
    for (int ci = 0; ci < Cin; ++ci) {
        float4 v = *(const float4*)(base + (size_t)ci * HW);
#pragma unroll
        for (int j = 0; j < TCO; ++j) {
            int co = min(co0 + j, Cout - 1);
            float wv = w[(size_t)co * Cin + ci];
            acc[j][0] += wv * v.x; acc[j][1] += wv * v.y;
            acc[j][2] += wv * v.z; acc[j][3] += wv * v.w;
        }
    }
#pragma unroll
    for (int j = 0; j < TCO; ++j) {
        if (co0 + j >= Cout) break;
        float4 o;
        o.x = acc[j][0]; o.y = acc[j][1]; o.z = acc[j][2]; o.w = acc[j][3];
        if (do_relu) {
            o.x = fmaxf(o.x, 0.f); o.y = fmaxf(o.y, 0.f);
            o.z = fmaxf(o.z, 0.f); o.w = fmaxf(o.w, 0.f);
        }
        *(float4*)(out + ((size_t)(n * Cout + co0 + j)) * HW + 4 * q) = o;
    }
}

__global__ __launch_bounds__(BS) void peaks_kernel(
    const float* __restrict__ hm, float* __restrict__ out,
    int NC, int H, int W, float thresh)
{
    int idx = blockIdx.x * BS + threadIdx.x;
    int total = NC * H * W;
    if (idx >= total) return;
    int x = idx % W;
    int t = idx / W;
    int y = t % H;
    int c = t / H;
    float r = 0.f;
    if (x >= 1 && x < W - 1 && y >= 1 && y < H - 1) {
        const float* base = hm + (size_t)c * H * W;
        float cv = base[y * W + x];
        if (cv > thresh &&
            cv >= base[(y - 1) * W + x] &&
            cv >= base[(y + 1) * W + x] &&
            cv >= base[y * W + (x - 1)] &&
            cv >= base[y * W + (x + 1)])
            r = 1.f;
    }
    out[idx] = r;
}

static inline int nblk(long n) { return (int)((n + BS - 1) / BS); }

extern "C" void kernel_launch(void* const* d_in, const int* in_sizes, int n_in,
                              void* d_out, int out_size, void* d_ws, size_t ws_size,
                              hipStream_t stream)
{
    const float* x     = (const float*)d_in[0];
    const float* w_d1  = (const float*)d_in[1];  const float* b_d1  = (const float*)d_in[2];
    const float* w_d2  = (const float*)d_in[3];  const float* b_d2  = (const float*)d_in[4];
    const float* w_bn  = (const float*)d_in[5];  const float* b_bn  = (const float*)d_in[6];
    const float* w_u1  = (const float*)d_in[7];  const float* b_u1  = (const float*)d_in[8];
    const float* w_u2  = (const float*)d_in[9];  const float* b_u2  = (const float*)d_in[10];
    const float* w_seg = (const float*)d_in[11]; const float* b_seg = (const float*)d_in[12];
    const float* w_p1  = (const float*)d_in[13]; const float* b_p1  = (const float*)d_in[14];
    const float* w_p2  = (const float*)d_in[15]; const float* b_p2  = (const float*)d_in[16];
    const float* w_hm  = (const float*)d_in[17]; const float* b_hm  = (const float*)d_in[18];
    const float* w_paf = (const float*)d_in[19]; const float* b_paf = (const float*)d_in[20];

    const int N = 8, H = 384, W = 384;
    const int H2 = 192, W2 = 192, H4 = 96, W4 = 96;

    float* ws = (float*)d_ws;
    // Workspace extent = 56,623,104 floats = 216 MiB (R2 lifetime map).
    float* u1  = ws;                   // 8*64*192*192 = 18874368
    float* d1  = ws + 18874368;        // 8*32*384*384 = 37748736
    float* d2  = ws + 18874368;        // 8*64*192*192 = 18874368
    float* bn  = ws + 37748736;        // 8*128*96*96  = 9437184
    float* pd1 = ws;                   // 8*32*192*192 = 9437184
    float* pd2 = ws + 47185920;        // 8*64*96*96   = 4718592
    float* p1  = ws;                   // 8*64*192*192 = 18874368
    float* p2  = ws + 18874368;        // 8*128*96*96  = 9437184

    float* out_seg   = (float*)d_out;                 // 1179648
    float* out_hm    = out_seg + 1179648;             // 1253376
    float* out_paf   = out_hm + 1253376;              // 2359296
    float* out_peaks = out_paf + 2359296;             // 1253376
    // packed weights in the peaks region [4792320, 6045696), consumed before
    // step 13 overwrites it. 16B-aligned.
    _Float16* bp_u1 = (_Float16*)(out_seg + 4792320); // 110592 fl
    _Float16* bp_u2 = (_Float16*)(out_seg + 4902912); // 27648 fl
    _Float16* bp_d2 = (_Float16*)(out_seg + 4930560); // 18432 fl
    _Float16* bp_bn = (_Float16*)(out_seg + 4948992); // 73728 fl -> ends 5022720

    // 0. pack weights
    packw_gen_kernel<<<nblk(13824), BS, 0, stream>>>(w_u1, bp_u1, 192, 64);
    packw_gen_kernel<<<nblk(3456),  BS, 0, stream>>>(w_u2, bp_u2, 96, 32);
    packw_gen_kernel<<<nblk(2304),  BS, 0, stream>>>(w_d2, bp_d2, 32, 64);
    packw_gen_kernel<<<nblk(9216),  BS, 0, stream>>>(w_bn, bp_bn, 64, 128);
    // 1. d1 = relu(conv3x3(x; 3->32)) @384
    {
        dim3 g(nblk((long)N * H * (W / 8)), 32 / 8);
        conv3x3_x8_kernel<1, 8><<<g, BS, 0, stream>>>(
            x, 3, nullptr, 0, w_d1, b_d1, d1, N, H, W, 32, 1);
    }
    // 2. pd1 = maxpool(d1) @192
    maxpool2_kernel<<<nblk((long)N * 32 * H2 * (W2 / 4)), BS, 0, stream>>>(d1, pd1, N * 32, H, W);
    // 3. d2 = relu(conv3x3(pd1; 32->64)) @192  [MFMA]
    conv3x3_mfma_kernel<1, 4, 192, 192><<<8 * 96 * 6, BS, 0, stream>>>(
        pd1, bp_d2, b_d2, d2);
    // 4. pd2 = maxpool(d2) @96
    maxpool2_kernel<<<nblk((long)N * 64 * H4 * (W4 / 4)), BS, 0, stream>>>(d2, pd2, N * 64, H2, W2);
    // 5. bn = relu(conv3x3(pd2; 64->128)) @96  [MFMA]
    conv3x3_mfma_kernel<2, 8, 96, 96><<<8 * 48 * 3, BS, 0, stream>>>(
        pd2, bp_bn, b_bn, bn);
    // 6. u1 = relu(conv3x3(concat(up2(bn), d2); 192->64)) @192  [MFMA 4-row]
    u1_mfma_kernel<<<8 * 48 * 3, BS, 0, stream>>>(bn, d2, bp_u1, b_u1, u1);
    // 7. d1' = relu(conv3x3(x; 3->32)) @384  (recompute)
    {
        dim3 g(nblk((long)N * H * (W / 8)), 32 / 8);
        conv3x3_x8_kernel<1, 8><<<g, BS, 0, stream>>>(
            x, 3, nullptr, 0, w_d1, b_d1, d1, N, H, W, 32, 1);
    }
    // 8. seg via fused MFMA u2+seg @384  [MFMA 4-row]
    u2seg_mfma_kernel<<<8 * 96 * 6, BS, 0, stream>>>(
        u1, d1, bp_u2, b_u2, w_seg, b_seg, out_seg);
    // 9. p1 = relu(conv3x3_s2(concat(x, seg); 4->64)) @384->192
    {
        dim3 g(nblk((long)N * H2 * (W2 / 4)), 64 / 8);
        conv3x3_s2_co_kernel<8><<<g, BS, 0, stream>>>(
            x, 3, out_seg, 1, w_p1, b_p1, p1, N, H, W, 64, 1);
    }
    // 10. p2 = relu(conv3x3_s2(p1; 64->128)) @192->96
    {
        dim3 g(nblk((long)N * H4 * (W4 / 4)), 128 / 8);
        conv3x3_s2_co_kernel<8><<<g, BS, 0, stream>>>(
            p1, 64, nullptr, 0, w_p2, b_p2, p2, N, H2, W2, 128, 1);
    }
    // 11. hm = conv1x1(p2; 128->17) @96
    {
        dim3 g(nblk((long)N * (H4 * W4 / 4)), 3);
        conv1x1_co_kernel<8><<<g, BS, 0, stream>>>(
            p2, w_hm, b_hm, out_hm, N, 128, H4 * W4, 17, 0);
    }
    // 12. paf = conv1x1(p2; 128->32) @96
    {
        dim3 g(nblk((long)N * (H4 * W4 / 4)), 4);
        conv1x1_co_kernel<8><<<g, BS, 0, stream>>>(
            p2, w_paf, b_paf, out_paf, N, 128, H4 * W4, 32, 0);
    }
    // 13. peaks @96  (overwrites packed-weight region - already consumed)
    peaks_kernel<<<nblk((long)N * 17 * H4 * W4), BS, 0, stream>>>(
        out_hm, out_peaks, N * 17, H4, W4, 0.1f);
}

// Round 13
// 1092.479 us; speedup vs baseline: 4.2897x; 1.1172x over previous
//
#include <hip/hip_runtime.h>

// ---------------------------------------------------------------------------
// TeacherModel: small U-Net + pose heads. B=8, H=W=384, fp32 NCHW.
// Round 13: two more f16x3-MFMA engine deployments.
//  - p2 (64->128, s2 @192->96): stride-2 MFMA with parity-split xi swizzle
//    (pos=(xi&1)*34+(xi>>1)) so tap reads are phase-contiguous (2-way, free).
//    R12: 253us at 43 TF vector.
//  - hm/paf 1x1 heads -> MFMA GEMM (K=128, N=17pad32/32). R12: ~150us vector.
// Engine validated across 5 kernels, absmax bit-stable 0.0078125 since R8.
// ---------------------------------------------------------------------------

#define BS 256

typedef _Float16 half8 __attribute__((ext_vector_type(8)));
typedef float floatx4 __attribute__((ext_vector_type(4)));

#define LDSDW 20    // dwords per x position
#define PL4 8160    // 6*68*LDSDW dwords per plane (4-row kernels)

// ===========================================================================
// Generic 3x3 weight pre-pack: [plane(hi/lo)][chunk][tap(9)][nt][lane][8]
// ci = chunk*32 + (lane>>4)*8 + j ; co = nt*16 + (lane&15)
// ===========================================================================
__global__ __launch_bounds__(BS) void packw_gen_kernel(
    const float* __restrict__ w, _Float16* __restrict__ bp, int Cin, int Cout)
{
    int total = (Cin >> 5) * 9 * (Cout >> 4) * 64;
    int tid = blockIdx.x * BS + threadIdx.x;
    if (tid >= total) return;
    int lane = tid & 63;
    int t = tid >> 6;
    int NTl = Cout >> 4;
    int nt = t % NTl; t /= NTl;
    int tap = t % 9;
    int chunk = t / 9;
    int q = lane >> 4, n = lane & 15;
    int co = nt * 16 + n;
    _Float16* ph = bp + (size_t)tid * 8;
    _Float16* pl = bp + (size_t)total * 8 + (size_t)tid * 8;
#pragma unroll
    for (int j = 0; j < 8; ++j) {
        int ci = chunk * 32 + q * 8 + j;
        float v = w[((size_t)co * Cin + ci) * 9 + tap];
        _Float16 h = (_Float16)v;
        ph[j] = h;
        pl[j] = (_Float16)(v - (float)h);
    }
}

// 1x1 weight pre-pack: [plane][chunk][nt][lane][8]; co >= Cout -> 0.
__global__ __launch_bounds__(BS) void packw_1x1_kernel(
    const float* __restrict__ w, _Float16* __restrict__ bp, int Cin, int NTl, int Cout)
{
    int total = (Cin >> 5) * NTl * 64;
    int tid = blockIdx.x * BS + threadIdx.x;
    if (tid >= total) return;
    int lane = tid & 63;
    int t = tid >> 6;
    int nt = t % NTl;
    int chunk = t / NTl;
    int q = lane >> 4, n = lane & 15;
    int co = nt * 16 + n;
    _Float16* ph = bp + (size_t)tid * 8;
    _Float16* pl = bp + (size_t)total * 8 + (size_t)tid * 8;
#pragma unroll
    for (int j = 0; j < 8; ++j) {
        int ci = chunk * 32 + q * 8 + j;
        float v = (co < Cout) ? w[(size_t)co * Cin + ci] : 0.f;
        _Float16 h = (_Float16)v;
        ph[j] = h;
        pl[j] = (_Float16)(v - (float)h);
    }
}

// ===========================================================================
// Generic stride-1 3x3 SAME conv via MFMA (R11): block = 2 rows x 32 px.
// ===========================================================================
template <int CHUNKS, int NT, int HH, int WW>
__global__ __launch_bounds__(BS) void conv3x3_mfma_kernel(
    const float* __restrict__ in_,
    const _Float16* __restrict__ bp,
    const float* __restrict__ bias,
    float* __restrict__ out)
{
    constexpr int PL = 4 * 34 * LDSDW;
    constexpr int EPI = 64 * NT * 16;
    constexpr int LDS_DW = (2 * PL > EPI) ? 2 * PL : EPI;
    __shared__ unsigned int lds[LDS_DW];

    int xblks = WW / 32;
    int b = blockIdx.x;
    int xb = b % xblks; b /= xblks;
    int yp = b % (HH / 2);
    int n  = b / (HH / 2);
    int y0 = yp * 2;
    int x0 = xb * 32;

    int tid = threadIdx.x;
    int lane = tid & 63, wv = tid >> 6;
    int m = lane & 15, q = lane >> 4;
    int lrow = wv >> 1;
    int lx   = (wv & 1) * 16;

    floatx4 acc[NT];
#pragma unroll
    for (int nt = 0; nt < NT; ++nt) acc[nt] = (floatx4){0.f, 0.f, 0.f, 0.f};

    const int planeW = CHUNKS * 9 * NT * 64 * 8;

    for (int chunk = 0; chunk < CHUNKS; ++chunk) {
        __syncthreads();
        for (int e = tid; e < 4 * 34 * 4; e += BS) {
            int xi = e % 34;
            int rest = e / 34;
            int oct = rest & 3;
            int row = rest >> 2;
            int iy = y0 - 1 + row, gx = x0 - 1 + xi;
            bool ok = (iy >= 0 && iy < HH && gx >= 0 && gx < WW);
            const float* gp = in_ +
                ((size_t)(n * (CHUNKS * 32) + chunk * 32 + oct * 8) * HH + iy) * WW + gx;
            half8 hv, lv;
#pragma unroll
            for (int j = 0; j < 8; ++j) {
                float v = ok ? gp[(size_t)j * HH * WW] : 0.f;
                _Float16 h = (_Float16)v;
                hv[j] = h;
                lv[j] = (_Float16)(v - (float)h);
            }
            int base = (row * 34 + xi) * LDSDW + oct * 4;
            *(half8*)((char*)lds + (size_t)base * 4) = hv;
            *(half8*)((char*)lds + ((size_t)PL + base) * 4) = lv;
        }
        __syncthreads();
#pragma unroll
        for (int ky = 0; ky < 3; ++ky) {
#pragma unroll
            for (int kx = 0; kx < 3; ++kx) {
                int row = lrow + ky;
                int xi  = lx + m + kx;
                int adw = (row * 34 + xi) * LDSDW + q * 4;
                half8 ah = *(const half8*)((const char*)lds + (size_t)adw * 4);
                half8 al = *(const half8*)((const char*)lds + ((size_t)PL + adw) * 4);
                int tap = ky * 3 + kx;
                const _Float16* bpp = bp + ((size_t)(chunk * 9 + tap) * NT) * 64 * 8;
#pragma unroll
                for (int nt = 0; nt < NT; ++nt) {
                    half8 bh = *(const half8*)(bpp + ((size_t)nt * 64 + lane) * 8);
                    half8 bl = *(const half8*)(bpp + planeW + ((size_t)nt * 64 + lane) * 8);
                    acc[nt] = __builtin_amdgcn_mfma_f32_16x16x32_f16(ah, bh, acc[nt], 0, 0, 0);
                    acc[nt] = __builtin_amdgcn_mfma_f32_16x16x32_f16(ah, bl, acc[nt], 0, 0, 0);
                    acc[nt] = __builtin_amdgcn_mfma_f32_16x16x32_f16(al, bh, acc[nt], 0, 0, 0);
                }
            }
        }
    }

    __syncthreads();
#pragma unroll
    for (int nt = 0; nt < NT; ++nt) {
#pragma unroll
        for (int r = 0; r < 4; ++r) {
            int co = nt * 16 + m;
            int pxl = wv * 16 + q * 4 + r;
            ((float*)lds)[co * 64 + pxl] = acc[nt][r];
        }
    }
    __syncthreads();
    {
        constexpr int thPerCo = 256 / (NT * 16);
        constexpr int pxPerTh = 64 / thPerCo;
        int co = tid / thPerCo;
        int sub = tid % thPerCo;
        int pxb = sub * pxPerTh;
        float bb = bias[co];
#pragma unroll
        for (int u = 0; u < pxPerTh; u += 4) {
            int p = pxb + u;
            int row = y0 + (p >> 5), xx = x0 + (p & 31);
            const float* lp = (const float*)lds + co * 64 + p;
            float4 vv = *(const float4*)lp;
            vv.x = fmaxf(vv.x + bb, 0.f);
            vv.y = fmaxf(vv.y + bb, 0.f);
            vv.z = fmaxf(vv.z + bb, 0.f);
            vv.w = fmaxf(vv.w + bb, 0.f);
            *(float4*)(out + ((size_t)(n * NT * 16 + co) * HH + row) * WW + xx) = vv;
        }
    }
}

// ===========================================================================
// Stride-2 3x3 conv (pad_lo=0, pad_hi=1) via MFMA: block = 2 out-rows x 32 px.
// Staging uses parity-split xi swizzle: pos = (xi&1)*34 + (xi>>1), so tap
// reads (ix = 2*ox + kx) are phase-contiguous -> LDS stride 20 (2-way, free).
// ===========================================================================
template <int CHUNKS, int NT, int WI>
__global__ __launch_bounds__(BS) void conv3x3s2_mfma_kernel(
    const float* __restrict__ in_,   // [8, CHUNKS*32, WI, WI]
    const _Float16* __restrict__ bp,
    const float* __restrict__ bias,  // [NT*16]
    float* __restrict__ out)         // [8, NT*16, WI/2, WI/2]
{
    constexpr int WO = WI / 2;
    constexpr int PLs = 5 * 68 * LDSDW;               // 6800 dw per plane
    constexpr int EPI = 64 * NT * 16;
    constexpr int LDS_DW = (2 * PLs > EPI) ? 2 * PLs : EPI;
    __shared__ unsigned int lds[LDS_DW];

    int xblks = WO / 32;
    int b = blockIdx.x;
    int xb = b % xblks; b /= xblks;
    int yp = b % (WO / 2);
    int n  = b / (WO / 2);
    int y0 = yp * 2;                                  // output rows y0, y0+1
    int x0 = xb * 32;

    int tid = threadIdx.x;
    int lane = tid & 63, wv = tid >> 6;
    int m = lane & 15, q = lane >> 4;
    int lrow = wv >> 1;
    int lx   = (wv & 1) * 16;

    floatx4 acc[NT];
#pragma unroll
    for (int nt = 0; nt < NT; ++nt) acc[nt] = (floatx4){0.f, 0.f, 0.f, 0.f};

    const int planeW = CHUNKS * 9 * NT * 64 * 8;

    for (int chunk = 0; chunk < CHUNKS; ++chunk) {
        __syncthreads();
        // stage 5 input rows x 65 xi (pad 68) x 4 octets; swizzled x position
        for (int e = tid; e < 5 * 68 * 4; e += BS) {
            int xi = e % 68;
            int rest = e / 68;
            int oct = rest & 3;
            int row = rest >> 2;                      // 0..4
            int iy = 2 * y0 + row, ix = 2 * x0 + xi;  // pad_lo = 0
            bool ok = (xi < 65 && iy < WI && ix < WI);
            const float* gp = in_ +
                ((size_t)(n * (CHUNKS * 32) + chunk * 32 + oct * 8) * WI + iy) * WI + ix;
            half8 hv, lv;
#pragma unroll
            for (int j = 0; j < 8; ++j) {
                float v = ok ? gp[(size_t)j * WI * WI] : 0.f;
                _Float16 h = (_Float16)v;
                hv[j] = h;
                lv[j] = (_Float16)(v - (float)h);
            }
            int pos = (xi & 1) * 34 + (xi >> 1);      // parity split
            int base = (row * 68 + pos) * LDSDW + oct * 4;
            *(half8*)((char*)lds + (size_t)base * 4) = hv;
            *(half8*)((char*)lds + ((size_t)PLs + base) * 4) = lv;
        }
        __syncthreads();
#pragma unroll
        for (int ky = 0; ky < 3; ++ky) {
#pragma unroll
            for (int kx = 0; kx < 3; ++kx) {
                int row = 2 * lrow + ky;              // 0..4
                int pos = (kx & 1) * 34 + (lx + m) + (kx >> 1);
                int adw = (row * 68 + pos) * LDSDW + q * 4;
                half8 ah = *(const half8*)((const char*)lds + (size_t)adw * 4);
                half8 al = *(const half8*)((const char*)lds + ((size_t)PLs + adw) * 4);
                int tap = ky * 3 + kx;
                const _Float16* bpp = bp + ((size_t)(chunk * 9 + tap) * NT) * 64 * 8;
#pragma unroll
                for (int nt = 0; nt < NT; ++nt) {
                    half8 bh = *(const half8*)(bpp + ((size_t)nt * 64 + lane) * 8);
                    half8 bl = *(const half8*)(bpp + planeW + ((size_t)nt * 64 + lane) * 8);
                    acc[nt] = __builtin_amdgcn_mfma_f32_16x16x32_f16(ah, bh, acc[nt], 0, 0, 0);
                    acc[nt] = __builtin_amdgcn_mfma_f32_16x16x32_f16(ah, bl, acc[nt], 0, 0, 0);
                    acc[nt] = __builtin_amdgcn_mfma_f32_16x16x32_f16(al, bh, acc[nt], 0, 0, 0);
                }
            }
        }
    }

    __syncthreads();
#pragma unroll
    for (int nt = 0; nt < NT; ++nt) {
#pragma unroll
        for (int r = 0; r < 4; ++r) {
            int co = nt * 16 + m;
            int pxl = wv * 16 + q * 4 + r;
            ((float*)lds)[co * 64 + pxl] = acc[nt][r];
        }
    }
    __syncthreads();
    {
        constexpr int thPerCo = 256 / (NT * 16);
        constexpr int pxPerTh = 64 / thPerCo;
        int co = tid / thPerCo;
        int sub = tid % thPerCo;
        int pxb = sub * pxPerTh;
        float bb = bias[co];
#pragma unroll
        for (int u = 0; u < pxPerTh; u += 4) {
            int p = pxb + u;
            int row = y0 + (p >> 5), xx = x0 + (p & 31);
            const float* lp = (const float*)lds + co * 64 + p;
            float4 vv = *(const float4*)lp;
            vv.x = fmaxf(vv.x + bb, 0.f);
            vv.y = fmaxf(vv.y + bb, 0.f);
            vv.z = fmaxf(vv.z + bb, 0.f);
            vv.w = fmaxf(vv.w + bb, 0.f);
            *(float4*)(out + ((size_t)(n * NT * 16 + co) * WO + row) * WO + xx) = vv;
        }
    }
}

// ===========================================================================
// 1x1 conv via MFMA GEMM: M = 64 px/block, N = NT*16 (store only co < Cout),
// K = CHUNKS*32. No relu (heads).
// ===========================================================================
template <int CHUNKS, int NT>
__global__ __launch_bounds__(BS) void conv1x1_mfma_kernel(
    const float* __restrict__ in_,   // [8, CHUNKS*32, HW]
    const _Float16* __restrict__ bp,
    const float* __restrict__ bias,  // [Cout]
    float* __restrict__ out,         // [8, Cout, HW]
    int Cout, int HW)
{
    constexpr int PL1 = 64 * LDSDW;                   // 1280 dw per plane
    constexpr int EPI = 64 * NT * 16;
    constexpr int LDS_DW = (2 * PL1 > EPI) ? 2 * PL1 : EPI;
    __shared__ unsigned int lds[LDS_DW];

    int pblks = HW / 64;
    int b = blockIdx.x;
    int pb = b % pblks;
    int n  = b / pblks;
    int sp0 = pb * 64;

    int tid = threadIdx.x;
    int lane = tid & 63, wv = tid >> 6;
    int m = lane & 15, q = lane >> 4;

    floatx4 acc[NT];
#pragma unroll
    for (int nt = 0; nt < NT; ++nt) acc[nt] = (floatx4){0.f, 0.f, 0.f, 0.f};

    const int planeW = CHUNKS * NT * 64 * 8;

    for (int chunk = 0; chunk < CHUNKS; ++chunk) {
        __syncthreads();
        // stage 64 px x 4 octets (one item per thread)
        {
            int px = tid & 63;
            int oct = tid >> 6;
            const float* gp = in_ +
                ((size_t)(n * (CHUNKS * 32) + chunk * 32 + oct * 8)) * HW + sp0 + px;
            half8 hv, lv;
#pragma unroll
            for (int j = 0; j < 8; ++j) {
                float v = gp[(size_t)j * HW];
                _Float16 h = (_Float16)v;
                hv[j] = h;
                lv[j] = (_Float16)(v - (float)h);
            }
            int base = px * LDSDW + oct * 4;
            *(half8*)((char*)lds + (size_t)base * 4) = hv;
            *(half8*)((char*)lds + ((size_t)PL1 + base) * 4) = lv;
        }
        __syncthreads();
        {
            int adw = (wv * 16 + m) * LDSDW + q * 4;
            half8 ah = *(const half8*)((const char*)lds + (size_t)adw * 4);
            half8 al = *(const half8*)((const char*)lds + ((size_t)PL1 + adw) * 4);
            const _Float16* bpp = bp + ((size_t)chunk * NT) * 64 * 8;
#pragma unroll
            for (int nt = 0; nt < NT; ++nt) {
                half8 bh = *(const half8*)(bpp + ((size_t)nt * 64 + lane) * 8);
                half8 bl = *(const half8*)(bpp + planeW + ((size_t)nt * 64 + lane) * 8);
                acc[nt] = __builtin_amdgcn_mfma_f32_16x16x32_f16(ah, bh, acc[nt], 0, 0, 0);
                acc[nt] = __builtin_amdgcn_mfma_f32_16x16x32_f16(ah, bl, acc[nt], 0, 0, 0);
                acc[nt] = __builtin_amdgcn_mfma_f32_16x16x32_f16(al, bh, acc[nt], 0, 0, 0);
            }
        }
    }

    __syncthreads();
#pragma unroll
    for (int nt = 0; nt < NT; ++nt) {
#pragma unroll
        for (int r = 0; r < 4; ++r) {
            ((float*)lds)[(nt * 16 + m) * 64 + wv * 16 + q * 4 + r] = acc[nt][r];
        }
    }
    __syncthreads();
    {
        constexpr int thPerCo = 256 / (NT * 16);      // NT=2 -> 8
        constexpr int pxPerTh = 64 / thPerCo;         // 8
        int co = tid / thPerCo;
        int g  = tid % thPerCo;
        if (co < Cout) {
            float bb = bias[co];
            const float* lp = (const float*)lds + co * 64 + g * pxPerTh;
            float* op = out + ((size_t)(n * Cout + co)) * HW + sp0 + g * pxPerTh;
#pragma unroll
            for (int u = 0; u < pxPerTh; u += 4) {
                float4 vv = *(const float4*)(lp + u);
                vv.x += bb; vv.y += bb; vv.z += bb; vv.w += bb;
                *(float4*)(op + u) = vv;
            }
        }
    }
}

// ===========================================================================
// u1 = relu(conv3x3(concat(up2(bn), d2))) via MFMA, 4 rows x 64 px @192. (R12)
// ===========================================================================
__global__ __launch_bounds__(BS) void u1_mfma_kernel(
    const float* __restrict__ bn_,   // [8,128,96,96]
    const float* __restrict__ d2_,   // [8,64,192,192]
    const _Float16* __restrict__ bp,
    const float* __restrict__ b_u1,  // [64]
    float* __restrict__ out)         // [8,64,192,192]
{
    __shared__ unsigned int lds[2 * PL4];
    const int Ho = 192, Wo = 192;
    int b = blockIdx.x;
    int xb = b % 3; b /= 3;
    int yb = b % 48;
    int n  = b / 48;
    int y0 = yb * 4;
    int x0 = xb * 64;

    int tid = threadIdx.x;
    int lane = tid & 63, wv = tid >> 6;
    int m = lane & 15, q = lane >> 4;
    int yr = y0 + wv;

    floatx4 acc[4][4];
#pragma unroll
    for (int mt = 0; mt < 4; ++mt)
#pragma unroll
        for (int nt = 0; nt < 4; ++nt) acc[mt][nt] = (floatx4){0.f, 0.f, 0.f, 0.f};

    const int hh0 = (y0 - 1) >> 1;
    const int hx0 = (x0 - 1) >> 1;

    for (int chunk = 0; chunk < 6; ++chunk) {
        __syncthreads();
        if (chunk < 4) {
            for (int e = tid; e < 4 * 34 * 4; e += BS) {
                int xi = e % 34;
                int rest = e / 34;
                int oct = rest & 3;
                int row = rest >> 2;
                int hy = hh0 + row, hx = hx0 + xi;
                bool ok = (hy >= 0 && hy < 96 && hx >= 0 && hx < 96);
                const float* gp = bn_ +
                    ((size_t)(n * 128 + chunk * 32 + oct * 8) * 96 + hy) * 96 + hx;
                half8 hv, lv;
#pragma unroll
                for (int j = 0; j < 8; ++j) {
                    float v = ok ? gp[(size_t)j * 96 * 96] : 0.f;
                    _Float16 h = (_Float16)v;
                    hv[j] = h;
                    lv[j] = (_Float16)(v - (float)h);
                }
                int base = (row * 68 + xi) * LDSDW + oct * 4;
                *(half8*)((char*)lds + (size_t)base * 4) = hv;
                *(half8*)((char*)lds + ((size_t)PL4 + base) * 4) = lv;
            }
        } else {
            for (int e = tid; e < 6 * 68 * 4; e += BS) {
                int xi = e % 68;
                int rest = e / 68;
                int oct = rest & 3;
                int row = rest >> 2;
                int iy = y0 - 1 + row, gx = x0 - 1 + xi;
                bool ok = (xi < 67 && iy >= 0 && iy < Ho && gx >= 0 && gx < Wo);
                const float* gp = d2_ +
                    ((size_t)(n * 64 + (chunk - 4) * 32 + oct * 8) * Ho + iy) * Wo + gx;
                half8 hv, lv;
#pragma unroll
                for (int j = 0; j < 8; ++j) {
                    float v = ok ? gp[(size_t)j * Ho * Wo] : 0.f;
                    _Float16 h = (_Float16)v;
                    hv[j] = h;
                    lv[j] = (_Float16)(v - (float)h);
                }
                int base = (row * 68 + xi) * LDSDW + oct * 4;
                *(half8*)((char*)lds + (size_t)base * 4) = hv;
                *(half8*)((char*)lds + ((size_t)PL4 + base) * 4) = lv;
            }
        }
        __syncthreads();
#pragma unroll
        for (int ky = 0; ky < 3; ++ky) {
#pragma unroll
            for (int kx = 0; kx < 3; ++kx) {
                int tap = ky * 3 + kx;
                const _Float16* bpp = bp + ((size_t)(chunk * 9 + tap) * 4) * 64 * 8;
                half8 bh[4], bl[4];
#pragma unroll
                for (int nt = 0; nt < 4; ++nt) {
                    bh[nt] = *(const half8*)(bpp + ((size_t)nt * 64 + lane) * 8);
                    bl[nt] = *(const half8*)(bpp + 110592 + ((size_t)nt * 64 + lane) * 8);
                }
                int row;
                if (chunk < 4) row = ((yr + ky - 1) >> 1) - hh0;
                else           row = wv + ky;
#pragma unroll
                for (int mt = 0; mt < 4; ++mt) {
                    int px = 16 * mt + m;
                    int xi = (chunk < 4) ? (((x0 + px + kx - 1) >> 1) - hx0)
                                         : (px + kx);
                    int adw = (row * 68 + xi) * LDSDW + q * 4;
                    half8 ah = *(const half8*)((const char*)lds + (size_t)adw * 4);
                    half8 al = *(const half8*)((const char*)lds + ((size_t)PL4 + adw) * 4);
#pragma unroll
                    for (int nt = 0; nt < 4; ++nt) {
                        acc[mt][nt] = __builtin_amdgcn_mfma_f32_16x16x32_f16(ah, bh[nt], acc[mt][nt], 0, 0, 0);
                        acc[mt][nt] = __builtin_amdgcn_mfma_f32_16x16x32_f16(ah, bl[nt], acc[mt][nt], 0, 0, 0);
                        acc[mt][nt] = __builtin_amdgcn_mfma_f32_16x16x32_f16(al, bh[nt], acc[mt][nt], 0, 0, 0);
                    }
                }
            }
        }
    }

#pragma unroll
    for (int h = 0; h < 2; ++h) {
        __syncthreads();
#pragma unroll
        for (int ntl = 0; ntl < 2; ++ntl) {
#pragma unroll
            for (int mt = 0; mt < 4; ++mt) {
#pragma unroll
                for (int r = 0; r < 4; ++r) {
                    ((float*)lds)[(ntl * 16 + m) * 256 + wv * 64 + 16 * mt + q * 4 + r]
                        = acc[mt][h * 2 + ntl][r];
                }
            }
        }
        __syncthreads();
        {
            int col = tid >> 3;
            int g   = tid & 7;
            int row = g >> 1, xx = (g & 1) * 32;
            int co = h * 32 + col;
            float bb = b_u1[co];
            const float* lp = (const float*)lds + col * 256 + row * 64 + xx;
            float* op = out + ((size_t)(n * 64 + co) * Ho + y0 + row) * Wo + x0 + xx;
#pragma unroll
            for (int u = 0; u < 32; u += 4) {
                float4 vv = *(const float4*)(lp + u);
                vv.x = fmaxf(vv.x + bb, 0.f);
                vv.y = fmaxf(vv.y + bb, 0.f);
                vv.z = fmaxf(vv.z + bb, 0.f);
                vv.w = fmaxf(vv.w + bb, 0.f);
                *(float4*)(op + u) = vv;
            }
        }
    }
}

// ===========================================================================
// seg via fused MFMA u2+seg, 4 rows x 64 px @384; shfl_xor co-reduce. (R12)
// ===========================================================================
__global__ __launch_bounds__(BS) void u2seg_mfma_kernel(
    const float* __restrict__ u1_,   // [8,64,192,192]
    const float* __restrict__ d1_,   // [8,32,384,384]
    const _Float16* __restrict__ bp,
    const float* __restrict__ b_u2,  // [32]
    const float* __restrict__ w_seg, // [32]
    const float* __restrict__ b_seg, // [1]
    float* __restrict__ seg)         // [8,1,384,384]
{
    __shared__ unsigned int lds[2 * PL4];
    const int Ho = 384, Wo = 384;
    int b = blockIdx.x;
    int xb = b % 6; b /= 6;
    int yb = b % 96;
    int n  = b / 96;
    int y0 = yb * 4;
    int x0 = xb * 64;

    int tid = threadIdx.x;
    int lane = tid & 63, wv = tid >> 6;
    int m = lane & 15, q = lane >> 4;
    int yr = y0 + wv;

    floatx4 acc[4][2];
#pragma unroll
    for (int mt = 0; mt < 4; ++mt) {
        acc[mt][0] = (floatx4){0.f, 0.f, 0.f, 0.f};
        acc[mt][1] = (floatx4){0.f, 0.f, 0.f, 0.f};
    }

    const int hh0 = (y0 - 1) >> 1;
    const int hx0 = (x0 - 1) >> 1;

    for (int chunk = 0; chunk < 3; ++chunk) {
        __syncthreads();
        if (chunk < 2) {
            for (int e = tid; e < 4 * 34 * 4; e += BS) {
                int xi = e % 34;
                int rest = e / 34;
                int oct = rest & 3;
                int row = rest >> 2;
                int hy = hh0 + row, hx = hx0 + xi;
                bool ok = (hy >= 0 && hy < 192 && hx >= 0 && hx < 192);
                const float* gp = u1_ +
                    ((size_t)(n * 64 + chunk * 32 + oct * 8) * 192 + hy) * 192 + hx;
                half8 hv, lv;
#pragma unroll
                for (int j = 0; j < 8; ++j) {
                    float v = ok ? gp[(size_t)j * 192 * 192] : 0.f;
                    _Float16 h = (_Float16)v;
                    hv[j] = h;
                    lv[j] = (_Float16)(v - (float)h);
                }
                int base = (row * 68 + xi) * LDSDW + oct * 4;
                *(half8*)((char*)lds + (size_t)base * 4) = hv;
                *(half8*)((char*)lds + ((size_t)PL4 + base) * 4) = lv;
            }
        } else {
            for (int e = tid; e < 6 * 68 * 4; e += BS) {
                int xi = e % 68;
                int rest = e / 68;
                int oct = rest & 3;
                int row = rest >> 2;
                int iy = y0 - 1 + row, gx = x0 - 1 + xi;
                bool ok = (xi < 67 && iy >= 0 && iy < Ho && gx >= 0 && gx < Wo);
                const float* gp = d1_ +
                    ((size_t)(n * 32 + oct * 8) * Ho + iy) * Wo + gx;
                half8 hv, lv;
#pragma unroll
                for (int j = 0; j < 8; ++j) {
                    float v = ok ? gp[(size_t)j * Ho * Wo] : 0.f;
                    _Float16 h = (_Float16)v;
                    hv[j] = h;
                    lv[j] = (_Float16)(v - (float)h);
                }
                int base = (row * 68 + xi) * LDSDW + oct * 4;
                *(half8*)((char*)lds + (size_t)base * 4) = hv;
                *(half8*)((char*)lds + ((size_t)PL4 + base) * 4) = lv;
            }
        }
        __syncthreads();
#pragma unroll
        for (int ky = 0; ky < 3; ++ky) {
#pragma unroll
            for (int kx = 0; kx < 3; ++kx) {
                int tap = ky * 3 + kx;
                const _Float16* bpp = bp + ((size_t)(chunk * 9 + tap) * 2) * 64 * 8;
                half8 bh0 = *(const half8*)(bpp + (size_t)lane * 8);
                half8 bl0 = *(const half8*)(bpp + 27648 + (size_t)lane * 8);
                half8 bh1 = *(const half8*)(bpp + ((size_t)64 + lane) * 8);
                half8 bl1 = *(const half8*)(bpp + 27648 + ((size_t)64 + lane) * 8);
                int row;
                if (chunk < 2) row = ((yr + ky - 1) >> 1) - hh0;
                else           row = wv + ky;
#pragma unroll
                for (int mt = 0; mt < 4; ++mt) {
                    int px = 16 * mt + m;
                    int xi = (chunk < 2) ? (((x0 + px + kx - 1) >> 1) - hx0)
                                         : (px + kx);
                    int adw = (row * 68 + xi) * LDSDW + q * 4;
                    half8 ah = *(const half8*)((const char*)lds + (size_t)adw * 4);
                    half8 al = *(const half8*)((const char*)lds + ((size_t)PL4 + adw) * 4);
                    acc[mt][0] = __builtin_amdgcn_mfma_f32_16x16x32_f16(ah, bh0, acc[mt][0], 0, 0, 0);
                    acc[mt][0] = __builtin_amdgcn_mfma_f32_16x16x32_f16(ah, bl0, acc[mt][0], 0, 0, 0);
                    acc[mt][0] = __builtin_amdgcn_mfma_f32_16x16x32_f16(al, bh0, acc[mt][0], 0, 0, 0);
                    acc[mt][1] = __builtin_amdgcn_mfma_f32_16x16x32_f16(ah, bh1, acc[mt][1], 0, 0, 0);
                    acc[mt][1] = __builtin_amdgcn_mfma_f32_16x16x32_f16(ah, bl1, acc[mt][1], 0, 0, 0);
                    acc[mt][1] = __builtin_amdgcn_mfma_f32_16x16x32_f16(al, bh1, acc[mt][1], 0, 0, 0);
                }
            }
        }
    }

    float bb0 = b_u2[m], bb1 = b_u2[16 + m];
    float ws0 = w_seg[m], ws1 = w_seg[16 + m];
    float bseg = b_seg[0];
#pragma unroll
    for (int mt = 0; mt < 4; ++mt) {
        float sr[4];
#pragma unroll
        for (int r = 0; r < 4; ++r) {
            float p = ws0 * fmaxf(acc[mt][0][r] + bb0, 0.f)
                    + ws1 * fmaxf(acc[mt][1][r] + bb1, 0.f);
            p += __shfl_xor(p, 1);
            p += __shfl_xor(p, 2);
            p += __shfl_xor(p, 4);
            p += __shfl_xor(p, 8);
            sr[r] = p + bseg;
        }
        if (m == 0) {
            float4 o; o.x = sr[0]; o.y = sr[1]; o.z = sr[2]; o.w = sr[3];
            *(float4*)(seg + ((size_t)n * Ho + yr) * Wo + x0 + 16 * mt + q * 4) = o;
        }
    }
}

// ===========================================================================
// Vector kernels, unchanged.
// ===========================================================================

template <int UPA, int TCO>
__global__ __launch_bounds__(BS, 2) void conv3x3_x8_kernel(
    const float* __restrict__ inA, int Ca,
    const float* __restrict__ inB, int Cb,
    const float* __restrict__ w, const float* __restrict__ b,
    float* __restrict__ out,
    int N, int H, int W, int Cout, int do_relu)
{
    const int W8 = W >> 3;
    int idx = blockIdx.x * BS + threadIdx.x;
    int total = N * H * W8;
    if (idx >= total) return;
    int x8 = idx % W8;
    int t  = idx / W8;
    int y  = t % H;
    int n  = t / H;
    int x0 = x8 << 3;
    const int co0 = blockIdx.y * TCO;
    const bool left_ok  = (x0 > 0);
    const bool right_ok = (x0 + 8 < W);
    const int Cin = Ca + Cb;

    float acc[TCO][8];
#pragma unroll
    for (int j = 0; j < TCO; ++j) {
        float bv = b[co0 + j];
#pragma unroll
        for (int p = 0; p < 8; ++p) acc[j][p] = bv;
    }

    for (int ci = 0; ci < Cin; ++ci) {
        float v[3][10];
#pragma unroll
        for (int ky = 0; ky < 3; ++ky) {
            int iy = y + ky - 1;
            if (iy < 0 || iy >= H) {
#pragma unroll
                for (int p = 0; p < 10; ++p) v[ky][p] = 0.f;
                continue;
            }
            if (UPA == 2 && ci < Ca) {
                const float* r = inA + ((size_t)(n * Ca + ci) * (H >> 1) + (iy >> 1)) * (W >> 1);
                int xh = x0 >> 1;
                float sm = left_ok  ? r[xh - 1] : 0.f;
                float4 qq = *(const float4*)(r + xh);
                float s4 = right_ok ? r[xh + 4] : 0.f;
                v[ky][0] = sm;
                v[ky][1] = qq.x; v[ky][2] = qq.x;
                v[ky][3] = qq.y; v[ky][4] = qq.y;
                v[ky][5] = qq.z; v[ky][6] = qq.z;
                v[ky][7] = qq.w; v[ky][8] = qq.w;
                v[ky][9] = s4;
            } else {
                const float* r = (ci < Ca)
                    ? inA + ((size_t)(n * Ca + ci) * H + iy) * W
                    : inB + ((size_t)(n * Cb + (ci - Ca)) * H + iy) * W;
                v[ky][0] = left_ok ? r[x0 - 1] : 0.f;
                float4 q0 = *(const float4*)(r + x0);
                float4 q1 = *(const float4*)(r + x0 + 4);
                v[ky][1] = q0.x; v[ky][2] = q0.y; v[ky][3] = q0.z; v[ky][4] = q0.w;
                v[ky][5] = q1.x; v[ky][6] = q1.y; v[ky][7] = q1.z; v[ky][8] = q1.w;
                v[ky][9] = right_ok ? r[x0 + 8] : 0.f;
            }
        }
#pragma unroll
        for (int j = 0; j < TCO; ++j) {
            const float* wp = w + ((size_t)(co0 + j) * Cin + ci) * 9;
#pragma unroll
            for (int ky = 0; ky < 3; ++ky) {
                float w0 = wp[ky * 3 + 0], w1 = wp[ky * 3 + 1], w2 = wp[ky * 3 + 2];
#pragma unroll
                for (int p = 0; p < 8; ++p)
                    acc[j][p] += w0 * v[ky][p] + w1 * v[ky][p + 1] + w2 * v[ky][p + 2];
            }
        }
    }

#pragma unroll
    for (int j = 0; j < TCO; ++j) {
#pragma unroll
        for (int p = 0; p < 8; ++p)
            if (do_relu) acc[j][p] = fmaxf(acc[j][p], 0.f);
        float* o = out + ((size_t)(n * Cout + co0 + j) * H + y) * W + x0;
        float4 q0; q0.x = acc[j][0]; q0.y = acc[j][1]; q0.z = acc[j][2]; q0.w = acc[j][3];
        float4 q1; q1.x = acc[j][4]; q1.y = acc[j][5]; q1.z = acc[j][6]; q1.w = acc[j][7];
        *(float4*)o = q0;
        *(float4*)(o + 4) = q1;
    }
}

template <int TCO>
__global__ __launch_bounds__(BS) void conv3x3_s2_co_kernel(
    const float* __restrict__ inA, int Ca,
    const float* __restrict__ inB, int Cb,
    const float* __restrict__ w, const float* __restrict__ b,
    float* __restrict__ out,
    int N, int Hi, int Wi, int Cout, int do_relu)
{
    const int Ho = Hi >> 1, Wo = Wi >> 1, Woq = Wo >> 2;
    int idx = blockIdx.x * BS + threadIdx.x;
    int total = N * Ho * Woq;
    if (idx >= total) return;
    int q  = idx % Woq;
    int t  = idx / Woq;
    int oy = t % Ho;
    int n  = t / Ho;
    int ox0 = q << 2;
    int ix0 = ox0 << 1;
    const int co0 = blockIdx.y * TCO;
    const bool right_ok = (ix0 + 8 < Wi);
    const int Cin = Ca + Cb;

    float acc[TCO][4];
#pragma unroll
    for (int j = 0; j < TCO; ++j) {
        float bv = b[co0 + j];
        acc[j][0] = bv; acc[j][1] = bv; acc[j][2] = bv; acc[j][3] = bv;
    }

    for (int ci = 0; ci < Cin; ++ci) {
        const float* base = (ci < Ca)
            ? inA + (size_t)(n * Ca + ci) * Hi * Wi
            : inB + (size_t)(n * Cb + (ci - Ca)) * Hi * Wi;
        float v[3][9];
#pragma unroll
        for (int ky = 0; ky < 3; ++ky) {
            int iy = 2 * oy + ky;
            if (iy >= Hi) {
#pragma unroll
                for (int p = 0; p < 9; ++p) v[ky][p] = 0.f;
                continue;
            }
            const float* r = base + (size_t)iy * Wi + ix0;
            float4 a = *(const float4*)r;
            float4 c = *(const float4*)(r + 4);
            v[ky][0] = a.x; v[ky][1] = a.y; v[ky][2] = a.z; v[ky][3] = a.w;
            v[ky][4] = c.x; v[ky][5] = c.y; v[ky][6] = c.z; v[ky][7] = c.w;
            v[ky][8] = right_ok ? r[8] : 0.f;
        }
#pragma unroll
        for (int j = 0; j < TCO; ++j) {
            const float* wp = w + ((size_t)(co0 + j) * Cin + ci) * 9;
#pragma unroll
            for (int ky = 0; ky < 3; ++ky) {
                float w0 = wp[ky * 3 + 0], w1 = wp[ky * 3 + 1], w2 = wp[ky * 3 + 2];
#pragma unroll
                for (int p = 0; p < 4; ++p)
                    acc[j][p] += w0 * v[ky][2 * p] + w1 * v[ky][2 * p + 1] + w2 * v[ky][2 * p + 2];
            }
        }
    }

#pragma unroll
    for (int j = 0; j < TCO; ++j) {
        float4 o;
        o.x = acc[j][0]; o.y = acc[j][1]; o.z = acc[j][2]; o.w = acc[j][3];
        if (do_relu) {
            o.x = fmaxf(o.x, 0.f); o.y = fmaxf(o.y, 0.f);
            o.z = fmaxf(o.z, 0.f); o.w = fmaxf(o.w, 0.f);
        }
        *(float4*)(out + ((size_t)(n * Cout + co0 + j) * Ho + oy) * Wo + ox0) = o;
    }
}

__global__ __launch_bounds__(BS) void maxpool2_kernel(
    const float* __restrict__ in, float* __restrict__ out, int NC, int H, int W)
{
    int Ho = H >> 1, Wo = W >> 1, Woq = Wo >> 2;
    int idx = blockIdx.x * BS + threadIdx.x;
    int total = NC * Ho * Woq;
    if (idx >= total) return;
    int x4 = idx % Woq;
    int t  = idx / Woq;
    int y  = t % Ho;
    int c  = t / Ho;
    const float* r0 = in + ((size_t)c * H + 2 * y) * W + 8 * x4;
    const float* r1 = r0 + W;
    float4 a0 = *(const float4*)r0;
    float4 a1 = *(const float4*)(r0 + 4);
    float4 b0 = *(const float4*)r1;
    float4 b1 = *(const float4*)(r1 + 4);
    float4 o;
    o.x = fmaxf(fmaxf(a0.x, a0.y), fmaxf(b0.x, b0.y));
    o.y = fmaxf(fmaxf(a0.z, a0.w), fmaxf(b0.z, b0.w));
    o.z = fmaxf(fmaxf(a1.x, a1.y), fmaxf(b1.x, b1.y));
    o.w = fmaxf(fmaxf(a1.z, a1.w), fmaxf(b1.z, b1.w));
    *(float4*)(out + ((size_t)c * Ho + y) * Wo + 4 * x4) = o;
}

__global__ __launch_bounds__(BS) void peaks_kernel(
    const float* __restrict__ hm, float* __restrict__ out,
    int NC, int H, int W, float thresh)
{
    int idx = blockIdx.x * BS + threadIdx.x;
    int total = NC * H * W;
    if (idx >= total) return;
    int x = idx % W;
    int t = idx / W;
    int y = t % H;
    int c = t / H;
    float r = 0.f;
    if (x >= 1 && x < W - 1 && y >= 1 && y < H - 1) {
        const float* base = hm + (size_t)c * H * W;
        float cv = base[y * W + x];
        if (cv > thresh &&
            cv >= base[(y - 1) * W + x] &&
            cv >= base[(y + 1) * W + x] &&
            cv >= base[y * W + (x - 1)] &&
            cv >= base[y * W + (x + 1)])
            r = 1.f;
    }
    out[idx] = r;
}

static inline int nblk(long n) { return (int)((n + BS - 1) / BS); }

extern "C" void kernel_launch(void* const* d_in, const int* in_sizes, int n_in,
                              void* d_out, int out_size, void* d_ws, size_t ws_size,
                              hipStream_t stream)
{
    const float* x     = (const float*)d_in[0];
    const float* w_d1  = (const float*)d_in[1];  const float* b_d1  = (const float*)d_in[2];
    const float* w_d2  = (const float*)d_in[3];  const float* b_d2  = (const float*)d_in[4];
    const float* w_bn  = (const float*)d_in[5];  const float* b_bn  = (const float*)d_in[6];
    const float* w_u1  = (const float*)d_in[7];  const float* b_u1  = (const float*)d_in[8];
    const float* w_u2  = (const float*)d_in[9];  const float* b_u2  = (const float*)d_in[10];
    const float* w_seg = (const float*)d_in[11]; const float* b_seg = (const float*)d_in[12];
    const float* w_p1  = (const float*)d_in[13]; const float* b_p1  = (const float*)d_in[14];
    const float* w_p2  = (const float*)d_in[15]; const float* b_p2  = (const float*)d_in[16];
    const float* w_hm  = (const float*)d_in[17]; const float* b_hm  = (const float*)d_in[18];
    const float* w_paf = (const float*)d_in[19]; const float* b_paf = (const float*)d_in[20];

    const int N = 8, H = 384, W = 384;
    const int H2 = 192, W2 = 192, H4 = 96, W4 = 96;

    float* ws = (float*)d_ws;
    // Workspace extent = 56,623,104 floats = 216 MiB (R2 lifetime map).
    float* u1  = ws;                   // 8*64*192*192 = 18874368
    float* d1  = ws + 18874368;        // 8*32*384*384 = 37748736
    float* d2  = ws + 18874368;        // 8*64*192*192 = 18874368
    float* bn  = ws + 37748736;        // 8*128*96*96  = 9437184
    float* pd1 = ws;                   // 8*32*192*192 = 9437184
    float* pd2 = ws + 47185920;        // 8*64*96*96   = 4718592
    float* p1  = ws;                   // 8*64*192*192 = 18874368
    float* p2  = ws + 18874368;        // 8*128*96*96  = 9437184

    float* out_seg   = (float*)d_out;                 // 1179648
    float* out_hm    = out_seg + 1179648;             // 1253376
    float* out_paf   = out_hm + 1253376;              // 2359296
    float* out_peaks = out_paf + 2359296;             // 1253376
    // packed weights in the peaks region [4792320, 6045696), all consumed
    // before step 13 overwrites them. 16B-aligned.
    _Float16* bp_u1  = (_Float16*)(out_seg + 4792320); // 110592 fl
    _Float16* bp_u2  = (_Float16*)(out_seg + 4902912); // 27648 fl
    _Float16* bp_d2  = (_Float16*)(out_seg + 4930560); // 18432 fl
    _Float16* bp_bn  = (_Float16*)(out_seg + 4948992); // 73728 fl
    _Float16* bp_p2  = (_Float16*)(out_seg + 5022720); // 73728 fl
    _Float16* bp_hm  = (_Float16*)(out_seg + 5096448); // 4096 fl
    _Float16* bp_paf = (_Float16*)(out_seg + 5100544); // 4096 fl -> ends 5104640

    // 0. pack weights
    packw_gen_kernel<<<nblk(13824), BS, 0, stream>>>(w_u1, bp_u1, 192, 64);
    packw_gen_kernel<<<nblk(3456),  BS, 0, stream>>>(w_u2, bp_u2, 96, 32);
    packw_gen_kernel<<<nblk(2304),  BS, 0, stream>>>(w_d2, bp_d2, 32, 64);
    packw_gen_kernel<<<nblk(9216),  BS, 0, stream>>>(w_bn, bp_bn, 64, 128);
    packw_gen_kernel<<<nblk(9216),  BS, 0, stream>>>(w_p2, bp_p2, 64, 128);
    packw_1x1_kernel<<<nblk(512),   BS, 0, stream>>>(w_hm, bp_hm, 128, 2, 17);
    packw_1x1_kernel<<<nblk(512),   BS, 0, stream>>>(w_paf, bp_paf, 128, 2, 32);
    // 1. d1 = relu(conv3x3(x; 3->32)) @384
    {
        dim3 g(nblk((long)N * H * (W / 8)), 32 / 8);
        conv3x3_x8_kernel<1, 8><<<g, BS, 0, stream>>>(
            x, 3, nullptr, 0, w_d1, b_d1, d1, N, H, W, 32, 1);
    }
    // 2. pd1 = maxpool(d1) @192
    maxpool2_kernel<<<nblk((long)N * 32 * H2 * (W2 / 4)), BS, 0, stream>>>(d1, pd1, N * 32, H, W);
    // 3. d2 = relu(conv3x3(pd1; 32->64)) @192  [MFMA]
    conv3x3_mfma_kernel<1, 4, 192, 192><<<8 * 96 * 6, BS, 0, stream>>>(
        pd1, bp_d2, b_d2, d2);
    // 4. pd2 = maxpool(d2) @96
    maxpool2_kernel<<<nblk((long)N * 64 * H4 * (W4 / 4)), BS, 0, stream>>>(d2, pd2, N * 64, H2, W2);
    // 5. bn = relu(conv3x3(pd2; 64->128)) @96  [MFMA]
    conv3x3_mfma_kernel<2, 8, 96, 96><<<8 * 48 * 3, BS, 0, stream>>>(
        pd2, bp_bn, b_bn, bn);
    // 6. u1 = relu(conv3x3(concat(up2(bn), d2); 192->64)) @192  [MFMA 4-row]
    u1_mfma_kernel<<<8 * 48 * 3, BS, 0, stream>>>(bn, d2, bp_u1, b_u1, u1);
    // 7. d1' = relu(conv3x3(x; 3->32)) @384  (recompute)
    {
        dim3 g(nblk((long)N * H * (W / 8)), 32 / 8);
        conv3x3_x8_kernel<1, 8><<<g, BS, 0, stream>>>(
            x, 3, nullptr, 0, w_d1, b_d1, d1, N, H, W, 32, 1);
    }
    // 8. seg via fused MFMA u2+seg @384  [MFMA 4-row]
    u2seg_mfma_kernel<<<8 * 96 * 6, BS, 0, stream>>>(
        u1, d1, bp_u2, b_u2, w_seg, b_seg, out_seg);
    // 9. p1 = relu(conv3x3_s2(concat(x, seg); 4->64)) @384->192  [vector]
    {
        dim3 g(nblk((long)N * H2 * (W2 / 4)), 64 / 8);
        conv3x3_s2_co_kernel<8><<<g, BS, 0, stream>>>(
            x, 3, out_seg, 1, w_p1, b_p1, p1, N, H, W, 64, 1);
    }
    // 10. p2 = relu(conv3x3_s2(p1; 64->128)) @192->96  [MFMA s2]
    conv3x3s2_mfma_kernel<2, 8, 192><<<8 * 48 * 3, BS, 0, stream>>>(
        p1, bp_p2, b_p2, p2);
    // 11. hm = conv1x1(p2; 128->17) @96  [MFMA 1x1]
    conv1x1_mfma_kernel<4, 2><<<8 * 144, BS, 0, stream>>>(
        p2, bp_hm, b_hm, out_hm, 17, H4 * W4);
    // 12. paf = conv1x1(p2; 128->32) @96  [MFMA 1x1]
    conv1x1_mfma_kernel<4, 2><<<8 * 144, BS, 0, stream>>>(
        p2, bp_paf, b_paf, out_paf, 32, H4 * W4);
    // 13. peaks @96  (overwrites packed-weight region - already consumed)
    peaks_kernel<<<nblk((long)N * 17 * H4 * W4), BS, 0, stream>>>(
        out_hm, out_peaks, N * 17, H4, W4, 0.1f);
}